// Round 5
// baseline (134.677 us; speedup 1.0000x reference)
//
#include <hip/hip_runtime.h>
#include <math.h>

// Problem constants (fixed by setup_inputs)
constexpr int B_ = 2, T_ = 2048, C_ = 512, H_ = 8, D_ = 64;
constexpr int QKVG_ = 3 * H_ * D_ + H_;   // 1544
constexpr float GATE_BIAS_ = 6.906768f;
constexpr int NPAD1_ = 1664;              // 13 * 128 (gemm1 padded N)
constexpr int SC_ = 8;                    // s-tiles per attn chunk

typedef __attribute__((ext_vector_type(8))) short short8;
typedef __attribute__((ext_vector_type(4))) float f32x4;

__device__ __forceinline__ unsigned short f2b(float f) {
    unsigned int u = __float_as_uint(f);
    unsigned int r = (u + 0x7fffu + ((u >> 16) & 1u)) >> 16;   // RNE
    return (unsigned short)r;
}
__device__ __forceinline__ short8 pack8(float4 a, float4 b) {
    short8 r;
    r[0] = (short)f2b(a.x); r[1] = (short)f2b(a.y);
    r[2] = (short)f2b(a.z); r[3] = (short)f2b(a.w);
    r[4] = (short)f2b(b.x); r[5] = (short)f2b(b.y);
    r[6] = (short)f2b(b.z); r[7] = (short)f2b(b.w);
    return r;
}

// ---------------------------------------------------------------------------
// cvt_bf16: fp32 -> bf16, 8 elements/thread
// ---------------------------------------------------------------------------
__global__ __launch_bounds__(256) void cvt_bf16(
    const float* __restrict__ in, unsigned short* __restrict__ outp, int n8)
{
    const int i = blockIdx.x * 256 + threadIdx.x;
    if (i < n8) {
        float4 f0 = *(const float4*)(in + (size_t)i * 8);
        float4 f1 = *(const float4*)(in + (size_t)i * 8 + 4);
        *(short8*)(outp + (size_t)i * 8) = pack8(f0, f1);
    }
}

// ---------------------------------------------------------------------------
// packT: W[K][N] fp32 row-major -> Bt[Npad][K] bf16 (transposed, zero-padded)
// ---------------------------------------------------------------------------
__global__ __launch_bounds__(256) void packT(
    const float* __restrict__ W, unsigned short* __restrict__ Bt,
    int K, int N)
{
    __shared__ float Ws[64][65];
    const int tid = threadIdx.x;
    const int nt = blockIdx.x * 64;
    const int kt = blockIdx.y * 64;

    {
        const int r = tid >> 2;
        const int c0 = (tid & 3) * 16;
#pragma unroll
        for (int j = 0; j < 16; ++j) {
            const int n = nt + c0 + j;
            Ws[r][c0 + j] = (n < N) ? W[(size_t)(kt + r) * N + n] : 0.f;
        }
    }
    __syncthreads();
    {
        const int d = tid >> 2;
        const int kc = (tid & 3) * 16;
        short8 o0, o1;
#pragma unroll
        for (int j = 0; j < 8; ++j) o0[j] = (short)f2b(Ws[kc + j][d]);
#pragma unroll
        for (int j = 0; j < 8; ++j) o1[j] = (short)f2b(Ws[kc + 8 + j][d]);
        unsigned short* op = Bt + (size_t)(nt + d) * K + kt + kc;
        *(short8*)(op + 0) = o0;
        *(short8*)(op + 8) = o1;
    }
}

// ---------------------------------------------------------------------------
// gemm_bf16: C[M,N] f32 = A[M,K]bf16 @ Bt[Npad,K]bf16^T  (unchanged)
// ---------------------------------------------------------------------------
__global__ __launch_bounds__(256) void gemm_bf16(
    const unsigned short* __restrict__ A, const unsigned short* __restrict__ Bt,
    float* __restrict__ C, int M, int N, int K)
{
    __shared__ __align__(16) char AsB[128 * 128];
    __shared__ __align__(16) char BsB[128 * 128];

    const int tid = threadIdx.x;
    const int wave = tid >> 6, lane = tid & 63;
    const int l15 = lane & 15, lhi = lane >> 4;
    const int wr = wave >> 1, wc = wave & 1;
    const int bm = blockIdx.y * 128, bn = blockIdx.x * 128;

    f32x4 acc[4][4];
#pragma unroll
    for (int i = 0; i < 4; ++i)
#pragma unroll
        for (int j = 0; j < 4; ++j) acc[i][j] = (f32x4){0.f, 0.f, 0.f, 0.f};

    const unsigned short* Arow = A + (size_t)bm * K;
    const unsigned short* Brow = Bt + (size_t)bn * K;
    const int sw = (l15 & 7) << 4;

    for (int k0 = 0; k0 < K; k0 += 64) {
        __syncthreads();
#pragma unroll
        for (int p = 0; p < 4; ++p) {
            const int idx = p * 256 + tid;
            const int row = idx >> 3;
            const int kc = (idx & 7) * 8;
            const int ldso = row * 128 + ((kc * 2) ^ ((row & 7) << 4));
            *(short8*)(AsB + ldso) = *(const short8*)(Arow + (size_t)row * K + k0 + kc);
            *(short8*)(BsB + ldso) = *(const short8*)(Brow + (size_t)row * K + k0 + kc);
        }
        __syncthreads();

        short8 af[4][2];
#pragma unroll
        for (int mi = 0; mi < 4; ++mi) {
            const int row = wr * 64 + mi * 16 + l15;
#pragma unroll
            for (int kk = 0; kk < 2; ++kk)
                af[mi][kk] = *(const short8*)(AsB + row * 128 + ((kk * 64 + lhi * 16) ^ sw));
        }
#pragma unroll
        for (int ni = 0; ni < 4; ++ni) {
            const int row = wc * 64 + ni * 16 + l15;
            short8 bf0 = *(const short8*)(BsB + row * 128 + ((lhi * 16) ^ sw));
            short8 bf1 = *(const short8*)(BsB + row * 128 + ((64 + lhi * 16) ^ sw));
#pragma unroll
            for (int mi = 0; mi < 4; ++mi) {
                acc[mi][ni] = __builtin_amdgcn_mfma_f32_16x16x32_bf16(af[mi][0], bf0, acc[mi][ni], 0, 0, 0);
                acc[mi][ni] = __builtin_amdgcn_mfma_f32_16x16x32_bf16(af[mi][1], bf1, acc[mi][ni], 0, 0, 0);
            }
        }
    }

#pragma unroll
    for (int mi = 0; mi < 4; ++mi) {
        const int gm = bm + wr * 64 + mi * 16 + lhi * 4;
#pragma unroll
        for (int r = 0; r < 4; ++r) {
            float* crow = C + (size_t)(gm + r) * N;
#pragma unroll
            for (int ni = 0; ni < 4; ++ni) {
                const int gn = bn + wc * 64 + ni * 16 + l15;
                if (gn < N) crow[gn] = acc[mi][ni][r];
            }
        }
    }
}

// ---------------------------------------------------------------------------
// prep: RoPE q,k in-place + log-sigmoid gate -> Lg
// ---------------------------------------------------------------------------
__global__ __launch_bounds__(256) void prep_kernel(
    float* __restrict__ qkvg, float* __restrict__ Lg)
{
    const int gid = blockIdx.x * 256 + threadIdx.x;
    const int i = gid & 31;
    const int h = (gid >> 5) & 7;
    const int t = (gid >> 8) & 2047;
    const int b = gid >> 19;

    const float div = 6.2831853071795864f * exp2f((float)i * (-11.0f / 32.0f));
    const float ang = (float)t * div;
    const float sn = sinf(ang);
    const float cs = cosf(ang);

    float* qp = qkvg + (size_t)(b * T_ + t) * QKVG_ + h * 64 + 2 * i;
    float x1 = qp[0], x2 = qp[1];
    qp[0] = x1 * cs - x2 * sn;
    qp[1] = x2 * cs + x1 * sn;
    float* kp = qp + 512;
    x1 = kp[0]; x2 = kp[1];
    kp[0] = x1 * cs - x2 * sn;
    kp[1] = x2 * cs + x1 * sn;

    if (i == 0) {
        const float z = qkvg[(size_t)(b * T_ + t) * QKVG_ + 1536 + h] + GATE_BIAS_;
        const float lg = (z > 0.f) ? -log1pf(expf(-z)) : (z - log1pf(expf(z)));
        Lg[(size_t)(b * H_ + h) * T_ + t] = lg;
    }
}

// ---------------------------------------------------------------------------
// cumsum over t per (b,h)
// ---------------------------------------------------------------------------
__global__ __launch_bounds__(64) void cumsum_kernel(float* __restrict__ Lg)
{
    const int bh = blockIdx.x;
    const int lane = threadIdx.x;
    float* p = Lg + (size_t)bh * T_;
    float carry = 0.f;
    for (int c0 = 0; c0 < T_; c0 += 64) {
        float v = p[c0 + lane];
#pragma unroll
        for (int off = 1; off < 64; off <<= 1) {
            float n = __shfl_up(v, off, 64);
            if (lane >= off) v += n;
        }
        v += carry;
        p[c0 + lane] = v;
        carry = __shfl(v, 63, 64);
    }
}

// ---------------------------------------------------------------------------
// vt_pack: V (fp32, strided inside qkvg) -> Vtb[bh][d][t] bf16 (transposed)
// ---------------------------------------------------------------------------
__global__ __launch_bounds__(256) void vt_pack(
    const float* __restrict__ qkvg, unsigned short* __restrict__ Vtb)
{
    __shared__ float Vs[64][68];
    const int tid = threadIdx.x;
    const int stile = blockIdx.x;
    const int bh = blockIdx.y;
    const int b = bh >> 3, h = bh & 7;

    {
        const int r = tid >> 2, c = tid & 3;
        const float* vp = qkvg + (size_t)(b * T_ + stile * 64 + r) * QKVG_ + 1024 + h * 64 + c * 16;
        *(float4*)&Vs[r][c * 16 + 0]  = *(const float4*)(vp + 0);
        *(float4*)&Vs[r][c * 16 + 4]  = *(const float4*)(vp + 4);
        *(float4*)&Vs[r][c * 16 + 8]  = *(const float4*)(vp + 8);
        *(float4*)&Vs[r][c * 16 + 12] = *(const float4*)(vp + 12);
    }
    __syncthreads();
    {
        const int d = tid >> 2, cc = tid & 3;
        short8 o0, o1;
#pragma unroll
        for (int j = 0; j < 8; ++j) o0[j] = (short)f2b(Vs[cc * 16 + j][d]);
#pragma unroll
        for (int j = 0; j < 8; ++j) o1[j] = (short)f2b(Vs[cc * 16 + 8 + j][d]);
        unsigned short* op = Vtb + (size_t)(bh * 64 + d) * T_ + stile * 64 + cc * 16;
        *(short8*)(op + 0) = o0;
        *(short8*)(op + 8) = o1;
    }
}

// ---------------------------------------------------------------------------
// attn_mfma (split-s): grid (bt=32, sc=4, bh=16). Chunk sc handles s-tiles
// [8sc, min(8sc+7, bt)]; partial accY/den atomicAdd'd into Yacc (=d_out) /
// Dacc. Blocks with 8sc > bt exit. Same MFMA pipeline as R4 otherwise.
// ---------------------------------------------------------------------------
__global__ __launch_bounds__(256) void attn_mfma(
    const float* __restrict__ qkvg, const float* __restrict__ L,
    const unsigned short* __restrict__ Vtb,
    float* __restrict__ Yacc, float* __restrict__ Dacc)
{
    __shared__ __align__(16) char smem[24832];
    char* KsB = smem;                 // 8 KB  [s][d] bf16 swizzled
    char* VtB = smem + 8192;          // 8 KB  [d][s] bf16 swizzled
    char* PsB = smem + 16384;         // 8 KB  4 waves x [16][64] bf16 swizzled
    float* LsBuf = (float*)(smem + 24576);  // 64 floats

    const int bt = blockIdx.x;
    const int sc = blockIdx.y;
    const int bh = blockIdx.z;
    if (sc * SC_ > bt) return;
    const int st0 = sc * SC_;
    const int st1 = min(st0 + SC_ - 1, bt);

    const int tid = threadIdx.x;
    const int wave = tid >> 6;
    const int lane = tid & 63;
    const int l15 = lane & 15;
    const int lhi = lane >> 4;
    const int b = bh >> 3, h = bh & 7;
    const int t0 = bt * 64;

    const float* Lrow = L + (size_t)bh * T_;

    // Q fragments (A-frag: row = l15, k = kk*32 + lhi*8 + j)
    const int qrow = t0 + wave * 16 + l15;
    const float* qp = qkvg + (size_t)(b * T_ + qrow) * QKVG_ + h * 64 + lhi * 8;
    short8 qf[2];
#pragma unroll
    for (int kk = 0; kk < 2; ++kk) {
        float4 f0 = *(const float4*)(qp + kk * 32);
        float4 f1 = *(const float4*)(qp + kk * 32 + 4);
        qf[kk] = pack8(f0, f1);
    }

    float eLt[4];
#pragma unroll
    for (int r = 0; r < 4; ++r)
        eLt[r] = __expf(Lrow[t0 + wave * 16 + lhi * 4 + r]) * (1.0f / 64.0f);

    f32x4 accY[4];
#pragma unroll
    for (int n = 0; n < 4; ++n) accY[n] = (f32x4){0.f, 0.f, 0.f, 0.f};
    float den[4] = {0.f, 0.f, 0.f, 0.f};

    const int kchunk = lhi * 16;

    for (int st = st0; st <= st1; ++st) {
        __syncthreads();
        {
            const int s = tid >> 2, cq = tid & 3;
            const float* kp = qkvg + (size_t)(b * T_ + st * 64 + s) * QKVG_ + 512 + h * 64 + cq * 16;
            float4 k0 = *(const float4*)(kp + 0);
            float4 k1 = *(const float4*)(kp + 4);
            float4 k2 = *(const float4*)(kp + 8);
            float4 k3 = *(const float4*)(kp + 12);
            const int sw = (s & 7) << 4;
            *(short8*)(KsB + s * 128 + ((cq * 32) ^ sw))      = pack8(k0, k1);
            *(short8*)(KsB + s * 128 + ((cq * 32 + 16) ^ sw)) = pack8(k2, k3);
            const int d = s;
            const unsigned short* vp = Vtb + (size_t)(bh * 64 + d) * T_ + st * 64 + cq * 16;
            short8 v0 = *(const short8*)(vp + 0);
            short8 v1 = *(const short8*)(vp + 8);
            *(short8*)(VtB + d * 128 + ((cq * 32) ^ sw))      = v0;
            *(short8*)(VtB + d * 128 + ((cq * 32 + 16) ^ sw)) = v1;
            if (tid < 64) LsBuf[tid] = Lrow[st * 64 + tid];
        }
        __syncthreads();

        f32x4 accS[4];
#pragma unroll
        for (int n = 0; n < 4; ++n) accS[n] = (f32x4){0.f, 0.f, 0.f, 0.f};
        const int rsw = (l15 & 7) << 4;
#pragma unroll
        for (int n = 0; n < 4; ++n) {
#pragma unroll
            for (int kk = 0; kk < 2; ++kk) {
                short8 bf = *(const short8*)(KsB + (n * 16 + l15) * 128 + ((kk * 64 + kchunk) ^ rsw));
                accS[n] = __builtin_amdgcn_mfma_f32_16x16x32_bf16(qf[kk], bf, accS[n], 0, 0, 0);
            }
        }

        float eLsi[4];
#pragma unroll
        for (int n = 0; n < 4; ++n)
            eLsi[n] = __expf(-LsBuf[n * 16 + l15]);
        const bool last = (st == bt);
        char* PsW = PsB + wave * 2048;
#pragma unroll
        for (int n = 0; n < 4; ++n) {
#pragma unroll
            for (int r = 0; r < 4; ++r) {
                const float a = accS[n][r];
                float p = a * a * eLt[r] * eLsi[n];
                if (last) {
                    const int scol = n * 16 + l15;
                    const int trow = lhi * 4 + r;
                    p = (scol <= wave * 16 + trow) ? p : 0.f;
                }
                den[r] += p;
                const int prow = lhi * 4 + r;
                const int pcol = n * 16 + l15;
                *(unsigned short*)(PsW + prow * 128 + ((2 * pcol) ^ ((prow & 7) << 4))) = f2b(p);
            }
        }

        short8 pa[2];
#pragma unroll
        for (int kk = 0; kk < 2; ++kk)
            pa[kk] = *(const short8*)(PsW + l15 * 128 + ((kk * 64 + kchunk) ^ rsw));
#pragma unroll
        for (int n = 0; n < 4; ++n) {
#pragma unroll
            for (int kk = 0; kk < 2; ++kk) {
                short8 vb = *(const short8*)(VtB + (n * 16 + l15) * 128 + ((kk * 64 + kchunk) ^ rsw));
                accY[n] = __builtin_amdgcn_mfma_f32_16x16x32_bf16(pa[kk], vb, accY[n], 0, 0, 0);
            }
        }
    }

    // reduce den across the 16 col-lanes
#pragma unroll
    for (int r = 0; r < 4; ++r) {
        den[r] += __shfl_xor(den[r], 1, 64);
        den[r] += __shfl_xor(den[r], 2, 64);
        den[r] += __shfl_xor(den[r], 4, 64);
        den[r] += __shfl_xor(den[r], 8, 64);
    }

    // atomic-accumulate partials
#pragma unroll
    for (int r = 0; r < 4; ++r) {
        const int t = t0 + wave * 16 + lhi * 4 + r;
        if (l15 == 0)
            atomicAdd(&Dacc[(size_t)bh * T_ + t], den[r]);
        float* yo = Yacc + (size_t)(b * T_ + t) * (H_ * D_) + h * 64 + l15;
#pragma unroll
        for (int n = 0; n < 4; ++n)
            atomicAdd(&yo[n * 16], accY[n][r]);
    }
}

// ---------------------------------------------------------------------------
// normalize: ybb[b,t,h,d] = bf16(Yacc / max(den, 1e-6))
// ---------------------------------------------------------------------------
__global__ __launch_bounds__(256) void normalize_kernel(
    const float* __restrict__ Yacc, const float* __restrict__ Dacc,
    unsigned short* __restrict__ ybb)
{
    const int gid = blockIdx.x * 256 + threadIdx.x;   // 262144 threads, 8 f each
    const size_t base = (size_t)gid * 8;
    const int row = (int)(base >> 9);                 // b*T + t
    const int col = (int)(base & 511);
    const int b = row >> 11, t = row & 2047, h = col >> 6;
    const float d = Dacc[(size_t)(b * H_ + h) * T_ + t];
    const float inv = 1.0f / fmaxf(d, 1e-6f);
    float4 f0 = *(const float4*)(Yacc + base);
    float4 f1 = *(const float4*)(Yacc + base + 4);
    f0.x *= inv; f0.y *= inv; f0.z *= inv; f0.w *= inv;
    f1.x *= inv; f1.y *= inv; f1.z *= inv; f1.w *= inv;
    *(short8*)(ybb + base) = pack8(f0, f1);
}

// ---------------------------------------------------------------------------
extern "C" void kernel_launch(void* const* d_in, const int* in_sizes, int n_in,
                              void* d_out, int out_size, void* d_ws, size_t ws_size,
                              hipStream_t stream)
{
    const float* x      = (const float*)d_in[0];
    const float* w_attn = (const float*)d_in[1];
    const float* w_proj = (const float*)d_in[2];
    float* out = (float*)d_out;

    // workspace layout (~36.2 MB):
    // qkvg f32 | Lg f32 | Dacc f32 | Vtb bf16 | Bt1 bf16 | Bt2 bf16 | xb/ybb
    float* qkvg = (float*)d_ws;
    float* Lg   = qkvg + (size_t)B_ * T_ * QKVG_;            // 6,322,176 f
    float* Dacc = Lg + (size_t)B_ * H_ * T_;                 // +32,768 f
    unsigned short* Vtb = (unsigned short*)(Dacc + (size_t)B_ * H_ * T_);
    unsigned short* Bt1 = Vtb + (size_t)B_ * H_ * D_ * T_;   // +2,097,152
    unsigned short* Bt2 = Bt1 + (size_t)NPAD1_ * C_;         // +851,968
    unsigned short* xb  = Bt2 + (size_t)C_ * C_;             // +262,144
    unsigned short* ybb = xb;  // union: xb dead after gemm1

    float* Yacc = out;         // reuse d_out as fp32 Y accumulator

    const int M = B_ * T_;     // 4096

    // 0) packs
    cvt_bf16<<<(M * C_ / 8 + 255) / 256, 256, 0, stream>>>(x, xb, M * C_ / 8);
    packT<<<dim3(NPAD1_ / 64, C_ / 64), 256, 0, stream>>>(w_attn, Bt1, C_, QKVG_);
    packT<<<dim3(C_ / 64, (H_ * D_) / 64), 256, 0, stream>>>(w_proj, Bt2, H_ * D_, C_);

    // 1) qkvg = x @ w_attn   (MFMA bf16)
    gemm_bf16<<<dim3(NPAD1_ / 128, M / 128), 256, 0, stream>>>(
        xb, Bt1, qkvg, M, QKVG_, C_);

    // 2) RoPE(q,k) + log-sigmoid gate
    prep_kernel<<<(B_ * T_ * H_ * 32) / 256, 256, 0, stream>>>(qkvg, Lg);

    // 3) cumsum over t per (b,h)
    cumsum_kernel<<<B_ * H_, 64, 0, stream>>>(Lg);

    // 3b) pack V^T to bf16 [bh][d][t]
    vt_pack<<<dim3(T_ / 64, B_ * H_), 256, 0, stream>>>(qkvg, Vtb);

    // 4) zero accumulators, then split-s attention (atomic partial sums)
    hipMemsetAsync(Yacc, 0, (size_t)M * C_ * sizeof(float), stream);
    hipMemsetAsync(Dacc, 0, (size_t)B_ * H_ * T_ * sizeof(float), stream);
    attn_mfma<<<dim3(T_ / 64, (T_ / 64 + SC_ - 1) / SC_, B_ * H_), 256, 0, stream>>>(
        qkvg, Lg, Vtb, Yacc, Dacc);

    // 4b) normalize -> ybb (bf16)
    normalize_kernel<<<(M * C_ / 8) / 256, 256, 0, stream>>>(Yacc, Dacc, ybb);

    // 5) out = ybb @ w_proj  (MFMA bf16; overwrites Yacc/d_out)
    gemm_bf16<<<dim3(C_ / 128, M / 128), 256, 0, stream>>>(
        ybb, Bt2, out, M, C_, H_ * D_);
}

// Round 6
// 115.906 us; speedup vs baseline: 1.1620x; 1.1620x over previous
//
#include <hip/hip_runtime.h>
#include <math.h>

// Problem constants (fixed by setup_inputs)
constexpr int B_ = 2, T_ = 2048, C_ = 512, H_ = 8, D_ = 64;
constexpr int QKVG_ = 3 * H_ * D_ + H_;   // 1544
constexpr float GATE_BIAS_ = 6.906768f;
constexpr int NPAD1_ = 1664;              // 13 * 128 (gemm1 padded N)
constexpr int SC_ = 8;                    // s-tiles per attn chunk
constexpr int NBLK_ = 1280;               // total useful attn blocks (16 bh x 80)

typedef __attribute__((ext_vector_type(8))) short short8;
typedef __attribute__((ext_vector_type(4))) float f32x4;

__device__ __forceinline__ unsigned short f2b(float f) {
    unsigned int u = __float_as_uint(f);
    unsigned int r = (u + 0x7fffu + ((u >> 16) & 1u)) >> 16;   // RNE
    return (unsigned short)r;
}
__device__ __forceinline__ short8 pack8(float4 a, float4 b) {
    short8 r;
    r[0] = (short)f2b(a.x); r[1] = (short)f2b(a.y);
    r[2] = (short)f2b(a.z); r[3] = (short)f2b(a.w);
    r[4] = (short)f2b(b.x); r[5] = (short)f2b(b.y);
    r[6] = (short)f2b(b.z); r[7] = (short)f2b(b.w);
    return r;
}

// ---------------------------------------------------------------------------
// cvt_bf16: fp32 -> bf16, 8 elements/thread
// ---------------------------------------------------------------------------
__global__ __launch_bounds__(256) void cvt_bf16(
    const float* __restrict__ in, unsigned short* __restrict__ outp, int n8)
{
    const int i = blockIdx.x * 256 + threadIdx.x;
    if (i < n8) {
        float4 f0 = *(const float4*)(in + (size_t)i * 8);
        float4 f1 = *(const float4*)(in + (size_t)i * 8 + 4);
        *(short8*)(outp + (size_t)i * 8) = pack8(f0, f1);
    }
}

// ---------------------------------------------------------------------------
// packT: W[K][N] fp32 row-major -> Bt[Npad][K] bf16 (transposed, zero-padded)
// ---------------------------------------------------------------------------
__global__ __launch_bounds__(256) void packT(
    const float* __restrict__ W, unsigned short* __restrict__ Bt,
    int K, int N)
{
    __shared__ float Ws[64][65];
    const int tid = threadIdx.x;
    const int nt = blockIdx.x * 64;
    const int kt = blockIdx.y * 64;

    {
        const int r = tid >> 2;
        const int c0 = (tid & 3) * 16;
#pragma unroll
        for (int j = 0; j < 16; ++j) {
            const int n = nt + c0 + j;
            Ws[r][c0 + j] = (n < N) ? W[(size_t)(kt + r) * N + n] : 0.f;
        }
    }
    __syncthreads();
    {
        const int d = tid >> 2;
        const int kc = (tid & 3) * 16;
        short8 o0, o1;
#pragma unroll
        for (int j = 0; j < 8; ++j) o0[j] = (short)f2b(Ws[kc + j][d]);
#pragma unroll
        for (int j = 0; j < 8; ++j) o1[j] = (short)f2b(Ws[kc + 8 + j][d]);
        unsigned short* op = Bt + (size_t)(nt + d) * K + kt + kc;
        *(short8*)(op + 0) = o0;
        *(short8*)(op + 8) = o1;
    }
}

// ---------------------------------------------------------------------------
// gemm_bf16: C[M,N] f32 = A[M,K]bf16 @ Bt[Npad,K]bf16^T  (unchanged)
// ---------------------------------------------------------------------------
__global__ __launch_bounds__(256) void gemm_bf16(
    const unsigned short* __restrict__ A, const unsigned short* __restrict__ Bt,
    float* __restrict__ C, int M, int N, int K)
{
    __shared__ __align__(16) char AsB[128 * 128];
    __shared__ __align__(16) char BsB[128 * 128];

    const int tid = threadIdx.x;
    const int wave = tid >> 6, lane = tid & 63;
    const int l15 = lane & 15, lhi = lane >> 4;
    const int wr = wave >> 1, wc = wave & 1;
    const int bm = blockIdx.y * 128, bn = blockIdx.x * 128;

    f32x4 acc[4][4];
#pragma unroll
    for (int i = 0; i < 4; ++i)
#pragma unroll
        for (int j = 0; j < 4; ++j) acc[i][j] = (f32x4){0.f, 0.f, 0.f, 0.f};

    const unsigned short* Arow = A + (size_t)bm * K;
    const unsigned short* Brow = Bt + (size_t)bn * K;
    const int sw = (l15 & 7) << 4;

    for (int k0 = 0; k0 < K; k0 += 64) {
        __syncthreads();
#pragma unroll
        for (int p = 0; p < 4; ++p) {
            const int idx = p * 256 + tid;
            const int row = idx >> 3;
            const int kc = (idx & 7) * 8;
            const int ldso = row * 128 + ((kc * 2) ^ ((row & 7) << 4));
            *(short8*)(AsB + ldso) = *(const short8*)(Arow + (size_t)row * K + k0 + kc);
            *(short8*)(BsB + ldso) = *(const short8*)(Brow + (size_t)row * K + k0 + kc);
        }
        __syncthreads();

        short8 af[4][2];
#pragma unroll
        for (int mi = 0; mi < 4; ++mi) {
            const int row = wr * 64 + mi * 16 + l15;
#pragma unroll
            for (int kk = 0; kk < 2; ++kk)
                af[mi][kk] = *(const short8*)(AsB + row * 128 + ((kk * 64 + lhi * 16) ^ sw));
        }
#pragma unroll
        for (int ni = 0; ni < 4; ++ni) {
            const int row = wc * 64 + ni * 16 + l15;
            short8 bf0 = *(const short8*)(BsB + row * 128 + ((lhi * 16) ^ sw));
            short8 bf1 = *(const short8*)(BsB + row * 128 + ((64 + lhi * 16) ^ sw));
#pragma unroll
            for (int mi = 0; mi < 4; ++mi) {
                acc[mi][ni] = __builtin_amdgcn_mfma_f32_16x16x32_bf16(af[mi][0], bf0, acc[mi][ni], 0, 0, 0);
                acc[mi][ni] = __builtin_amdgcn_mfma_f32_16x16x32_bf16(af[mi][1], bf1, acc[mi][ni], 0, 0, 0);
            }
        }
    }

#pragma unroll
    for (int mi = 0; mi < 4; ++mi) {
        const int gm = bm + wr * 64 + mi * 16 + lhi * 4;
#pragma unroll
        for (int r = 0; r < 4; ++r) {
            float* crow = C + (size_t)(gm + r) * N;
#pragma unroll
            for (int ni = 0; ni < 4; ++ni) {
                const int gn = bn + wc * 64 + ni * 16 + l15;
                if (gn < N) crow[gn] = acc[mi][ni][r];
            }
        }
    }
}

// ---------------------------------------------------------------------------
// prep: RoPE q,k in-place + log-sigmoid gate -> Lg
// ---------------------------------------------------------------------------
__global__ __launch_bounds__(256) void prep_kernel(
    float* __restrict__ qkvg, float* __restrict__ Lg)
{
    const int gid = blockIdx.x * 256 + threadIdx.x;
    const int i = gid & 31;
    const int h = (gid >> 5) & 7;
    const int t = (gid >> 8) & 2047;
    const int b = gid >> 19;

    const float div = 6.2831853071795864f * exp2f((float)i * (-11.0f / 32.0f));
    const float ang = (float)t * div;
    const float sn = sinf(ang);
    const float cs = cosf(ang);

    float* qp = qkvg + (size_t)(b * T_ + t) * QKVG_ + h * 64 + 2 * i;
    float x1 = qp[0], x2 = qp[1];
    qp[0] = x1 * cs - x2 * sn;
    qp[1] = x2 * cs + x1 * sn;
    float* kp = qp + 512;
    x1 = kp[0]; x2 = kp[1];
    kp[0] = x1 * cs - x2 * sn;
    kp[1] = x2 * cs + x1 * sn;

    if (i == 0) {
        const float z = qkvg[(size_t)(b * T_ + t) * QKVG_ + 1536 + h] + GATE_BIAS_;
        const float lg = (z > 0.f) ? -log1pf(expf(-z)) : (z - log1pf(expf(z)));
        Lg[(size_t)(b * H_ + h) * T_ + t] = lg;
    }
}

// ---------------------------------------------------------------------------
// cumsum over t per (b,h)
// ---------------------------------------------------------------------------
__global__ __launch_bounds__(64) void cumsum_kernel(float* __restrict__ Lg)
{
    const int bh = blockIdx.x;
    const int lane = threadIdx.x;
    float* p = Lg + (size_t)bh * T_;
    float carry = 0.f;
    for (int c0 = 0; c0 < T_; c0 += 64) {
        float v = p[c0 + lane];
#pragma unroll
        for (int off = 1; off < 64; off <<= 1) {
            float n = __shfl_up(v, off, 64);
            if (lane >= off) v += n;
        }
        v += carry;
        p[c0 + lane] = v;
        carry = __shfl(v, 63, 64);
    }
}

// ---------------------------------------------------------------------------
// kv_pack: K (RoPE'd fp32 in qkvg) -> Ksb[bh][t][d] bf16, scaled e^(-L/2);
//          V (fp32 in qkvg)       -> Vtb[bh][d][t] bf16 (transposed)
// grid (T/64, 16bh), 256 threads
// ---------------------------------------------------------------------------
__global__ __launch_bounds__(256) void kv_pack(
    const float* __restrict__ qkvg, const float* __restrict__ Lg,
    unsigned short* __restrict__ Ksb, unsigned short* __restrict__ Vtb)
{
    __shared__ float Vs[64][68];
    const int tid = threadIdx.x;
    const int stile = blockIdx.x;
    const int bh = blockIdx.y;
    const int b = bh >> 3, h = bh & 7;
    const int r = tid >> 2, c = tid & 3;
    const int t = stile * 64 + r;

    // K: scale by e^(-L/2), pack bf16 contiguous
    {
        const float eK = __expf(-0.5f * Lg[(size_t)bh * T_ + t]);
        const float* kp = qkvg + (size_t)(b * T_ + t) * QKVG_ + 512 + h * 64 + c * 16;
        float4 k0 = *(const float4*)(kp + 0);
        float4 k1 = *(const float4*)(kp + 4);
        float4 k2 = *(const float4*)(kp + 8);
        float4 k3 = *(const float4*)(kp + 12);
        k0.x *= eK; k0.y *= eK; k0.z *= eK; k0.w *= eK;
        k1.x *= eK; k1.y *= eK; k1.z *= eK; k1.w *= eK;
        k2.x *= eK; k2.y *= eK; k2.z *= eK; k2.w *= eK;
        k3.x *= eK; k3.y *= eK; k3.z *= eK; k3.w *= eK;
        unsigned short* op = Ksb + ((size_t)bh * T_ + t) * 64 + c * 16;
        *(short8*)(op + 0) = pack8(k0, k1);
        *(short8*)(op + 8) = pack8(k2, k3);
    }
    // V: transpose via LDS
    {
        const float* vp = qkvg + (size_t)(b * T_ + t) * QKVG_ + 1024 + h * 64 + c * 16;
        *(float4*)&Vs[r][c * 16 + 0]  = *(const float4*)(vp + 0);
        *(float4*)&Vs[r][c * 16 + 4]  = *(const float4*)(vp + 4);
        *(float4*)&Vs[r][c * 16 + 8]  = *(const float4*)(vp + 8);
        *(float4*)&Vs[r][c * 16 + 12] = *(const float4*)(vp + 12);
    }
    __syncthreads();
    {
        const int d = tid >> 2, cc = tid & 3;
        short8 o0, o1;
#pragma unroll
        for (int j = 0; j < 8; ++j) o0[j] = (short)f2b(Vs[cc * 16 + j][d]);
#pragma unroll
        for (int j = 0; j < 8; ++j) o1[j] = (short)f2b(Vs[cc * 16 + 8 + j][d]);
        unsigned short* op = Vtb + ((size_t)bh * 64 + d) * T_ + stile * 64 + cc * 16;
        *(short8*)(op + 0) = o0;
        *(short8*)(op + 8) = o1;
    }
}

// ---------------------------------------------------------------------------
// attn_mfma: gate-prescaled scores p = (q'.k')^2; no per-tile exp/gating.
// Compact XCD-pinned grid: wg&7 = xcd, bh in {xcd, 8+xcd}; 80 chunks/bh.
// Per 64-wide KV tile: QK^T (8 mfma) -> square+mask -> P LDS bf16 swizzled
// -> PV (8 mfma). Partials atomicAdd'd to Yacc/Dacc.
// ---------------------------------------------------------------------------
__global__ __launch_bounds__(256) void attn_mfma(
    const float* __restrict__ qkvg, const float* __restrict__ Lg,
    const unsigned short* __restrict__ Ksb, const unsigned short* __restrict__ Vtb,
    float* __restrict__ Yacc, float* __restrict__ Dacc)
{
    __shared__ __align__(16) char smem[24576];
    char* KsB = smem;                 // 8 KB [s][d] bf16 swizzled
    char* VtB = smem + 8192;          // 8 KB [d][s] bf16 swizzled
    char* PsB = smem + 16384;         // 8 KB 4 waves x [16][64] bf16 swizzled

    // ---- decode (bh, bt, sc) from XCD-pinned compact index ----
    const int wg = blockIdx.x;
    const int xcd = wg & 7;
    const int slot = wg >> 3;              // 0..159
    const int bh = (slot < 80) ? xcd : 8 + xcd;
    const int rem = (slot < 80) ? slot : slot - 80;
    const int rr = 79 - rem;               // big-bt chunks first
    int bt, sc;
    if (rr < 8)       { bt = rr; sc = 0; }
    else if (rr < 24) { const int q = rr - 8;  bt = 8 + (q >> 1);  sc = q & 1; }
    else if (rr < 48) { const int q = rr - 24; bt = 16 + q / 3;    sc = q % 3; }
    else              { const int q = rr - 48; bt = 24 + (q >> 2); sc = q & 3; }
    const int st0 = sc * SC_;
    const int st1 = min(st0 + SC_ - 1, bt);

    const int tid = threadIdx.x;
    const int wave = tid >> 6;
    const int lane = tid & 63;
    const int l15 = lane & 15;
    const int lhi = lane >> 4;
    const int b = bh >> 3, h = bh & 7;
    const int t0 = bt * 64;

    // ---- Q fragments: fp32 (RoPE'd) scaled by e^(L/2)/8, packed bf16 ----
    const int qrow = t0 + wave * 16 + l15;
    const float eQ = __expf(0.5f * Lg[(size_t)bh * T_ + qrow]) * 0.125f;
    const float* qp = qkvg + (size_t)(b * T_ + qrow) * QKVG_ + h * 64 + lhi * 8;
    short8 qf[2];
#pragma unroll
    for (int kk = 0; kk < 2; ++kk) {
        float4 f0 = *(const float4*)(qp + kk * 32);
        float4 f1 = *(const float4*)(qp + kk * 32 + 4);
        f0.x *= eQ; f0.y *= eQ; f0.z *= eQ; f0.w *= eQ;
        f1.x *= eQ; f1.y *= eQ; f1.z *= eQ; f1.w *= eQ;
        qf[kk] = pack8(f0, f1);
    }

    f32x4 accY[4];
#pragma unroll
    for (int n = 0; n < 4; ++n) accY[n] = (f32x4){0.f, 0.f, 0.f, 0.f};
    float den[4] = {0.f, 0.f, 0.f, 0.f};

    const int kchunk = lhi * 16;
    const int rsw = (l15 & 7) << 4;
    const int srow = tid >> 2;
    const int c2 = (tid & 3) * 2;
    const int swr = (srow & 7) << 4;

    for (int st = st0; st <= st1; ++st) {
        __syncthreads();
        // ---- stage K,V tiles from packed bf16 (coalesced, no conversion) ----
        {
            const unsigned short* kp = Ksb + ((size_t)bh * T_ + st * 64 + srow) * 64 + c2 * 8;
            short8 k0 = *(const short8*)kp;
            short8 k1 = *(const short8*)(kp + 8);
            *(short8*)(KsB + srow * 128 + ((c2 * 16) ^ swr))      = k0;
            *(short8*)(KsB + srow * 128 + ((c2 * 16 + 16) ^ swr)) = k1;
            const unsigned short* vp = Vtb + ((size_t)bh * 64 + srow) * T_ + st * 64 + c2 * 8;
            short8 v0 = *(const short8*)vp;
            short8 v1 = *(const short8*)(vp + 8);
            *(short8*)(VtB + srow * 128 + ((c2 * 16) ^ swr))      = v0;
            *(short8*)(VtB + srow * 128 + ((c2 * 16 + 16) ^ swr)) = v1;
        }
        __syncthreads();

        // ---- QK^T ----
        f32x4 accS[4];
#pragma unroll
        for (int n = 0; n < 4; ++n) accS[n] = (f32x4){0.f, 0.f, 0.f, 0.f};
#pragma unroll
        for (int n = 0; n < 4; ++n) {
#pragma unroll
            for (int kk = 0; kk < 2; ++kk) {
                short8 bf = *(const short8*)(KsB + (n * 16 + l15) * 128 + ((kk * 64 + kchunk) ^ rsw));
                accS[n] = __builtin_amdgcn_mfma_f32_16x16x32_bf16(qf[kk], bf, accS[n], 0, 0, 0);
            }
        }

        // ---- square + causal mask; write P (bf16) to LDS ----
        const bool last = (st == bt);
        char* PsW = PsB + wave * 2048;
#pragma unroll
        for (int n = 0; n < 4; ++n) {
#pragma unroll
            for (int r = 0; r < 4; ++r) {
                const float a = accS[n][r];
                float p = a * a;
                if (last)
                    p = ((n * 16 + l15) <= wave * 16 + lhi * 4 + r) ? p : 0.f;
                den[r] += p;
                const int prow = lhi * 4 + r;
                *(unsigned short*)(PsW + prow * 128 + ((2 * (n * 16 + l15)) ^ ((prow & 7) << 4))) = f2b(p);
            }
        }

        // ---- PV ----
        short8 pa[2];
#pragma unroll
        for (int kk = 0; kk < 2; ++kk)
            pa[kk] = *(const short8*)(PsW + l15 * 128 + ((kk * 64 + kchunk) ^ rsw));
#pragma unroll
        for (int n = 0; n < 4; ++n) {
#pragma unroll
            for (int kk = 0; kk < 2; ++kk) {
                short8 vb = *(const short8*)(VtB + (n * 16 + l15) * 128 + ((kk * 64 + kchunk) ^ rsw));
                accY[n] = __builtin_amdgcn_mfma_f32_16x16x32_bf16(pa[kk], vb, accY[n], 0, 0, 0);
            }
        }
    }

    // ---- reduce den across the 16 col-lanes ----
#pragma unroll
    for (int r = 0; r < 4; ++r) {
        den[r] += __shfl_xor(den[r], 1, 64);
        den[r] += __shfl_xor(den[r], 2, 64);
        den[r] += __shfl_xor(den[r], 4, 64);
        den[r] += __shfl_xor(den[r], 8, 64);
    }

    // ---- atomic-accumulate partials ----
#pragma unroll
    for (int r = 0; r < 4; ++r) {
        const int t = t0 + wave * 16 + lhi * 4 + r;
        if (l15 == 0)
            atomicAdd(&Dacc[(size_t)bh * T_ + t], den[r]);
        float* yo = Yacc + (size_t)(b * T_ + t) * (H_ * D_) + h * 64 + l15;
#pragma unroll
        for (int n = 0; n < 4; ++n)
            atomicAdd(&yo[n * 16], accY[n][r]);
    }
}

// ---------------------------------------------------------------------------
// normalize: ybb[b,t,h,d] = bf16(Yacc / max(den, 1e-6))
// ---------------------------------------------------------------------------
__global__ __launch_bounds__(256) void normalize_kernel(
    const float* __restrict__ Yacc, const float* __restrict__ Dacc,
    unsigned short* __restrict__ ybb)
{
    const int gid = blockIdx.x * 256 + threadIdx.x;
    const size_t base = (size_t)gid * 8;
    const int row = (int)(base >> 9);
    const int col = (int)(base & 511);
    const int b = row >> 11, t = row & 2047, h = col >> 6;
    const float d = Dacc[(size_t)(b * H_ + h) * T_ + t];
    const float inv = 1.0f / fmaxf(d, 1e-6f);
    float4 f0 = *(const float4*)(Yacc + base);
    float4 f1 = *(const float4*)(Yacc + base + 4);
    f0.x *= inv; f0.y *= inv; f0.z *= inv; f0.w *= inv;
    f1.x *= inv; f1.y *= inv; f1.z *= inv; f1.w *= inv;
    *(short8*)(ybb + base) = pack8(f0, f1);
}

// ---------------------------------------------------------------------------
extern "C" void kernel_launch(void* const* d_in, const int* in_sizes, int n_in,
                              void* d_out, int out_size, void* d_ws, size_t ws_size,
                              hipStream_t stream)
{
    const float* x      = (const float*)d_in[0];
    const float* w_attn = (const float*)d_in[1];
    const float* w_proj = (const float*)d_in[2];
    float* out = (float*)d_out;

    // workspace layout (36.2 MB, same proven budget as R4/R5):
    // qkvg f32 | Lg | Dacc | Vtb | Bt1 | Bt2 | A
    // region A (4MB) is reused: xb (gemm1 input) -> Ksb (attn) -> ybb (gemm2 in)
    float* qkvg = (float*)d_ws;
    float* Lg   = qkvg + (size_t)B_ * T_ * QKVG_;            // 6,322,176 f
    float* Dacc = Lg + (size_t)B_ * H_ * T_;                 // +32,768 f
    unsigned short* Vtb = (unsigned short*)(Dacc + (size_t)B_ * H_ * T_);
    unsigned short* Bt1 = Vtb + (size_t)B_ * H_ * D_ * T_;   // +2,097,152
    unsigned short* Bt2 = Bt1 + (size_t)NPAD1_ * C_;         // +851,968
    unsigned short* xb  = Bt2 + (size_t)C_ * C_;             // +262,144
    unsigned short* Ksb = xb;   // alias: xb dead after gemm1
    unsigned short* ybb = xb;   // alias: Ksb dead after attn

    float* Yacc = out;          // reuse d_out as fp32 Y accumulator

    const int M = B_ * T_;      // 4096

    // 0) packs
    cvt_bf16<<<(M * C_ / 8 + 255) / 256, 256, 0, stream>>>(x, xb, M * C_ / 8);
    packT<<<dim3(NPAD1_ / 64, C_ / 64), 256, 0, stream>>>(w_attn, Bt1, C_, QKVG_);
    packT<<<dim3(C_ / 64, (H_ * D_) / 64), 256, 0, stream>>>(w_proj, Bt2, H_ * D_, C_);

    // 1) qkvg = x @ w_attn   (MFMA bf16)
    gemm_bf16<<<dim3(NPAD1_ / 128, M / 128), 256, 0, stream>>>(
        xb, Bt1, qkvg, M, QKVG_, C_);

    // 2) RoPE(q,k) in place + log-sigmoid gate
    prep_kernel<<<(B_ * T_ * H_ * 32) / 256, 256, 0, stream>>>(qkvg, Lg);

    // 3) cumsum over t per (b,h)
    cumsum_kernel<<<B_ * H_, 64, 0, stream>>>(Lg);

    // 3b) pack K (gate-prescaled) + V^T to bf16
    kv_pack<<<dim3(T_ / 64, B_ * H_), 256, 0, stream>>>(qkvg, Lg, Ksb, Vtb);

    // 4) zero accumulators, then split-s attention (atomic partial sums)
    hipMemsetAsync(Yacc, 0, (size_t)M * C_ * sizeof(float), stream);
    hipMemsetAsync(Dacc, 0, (size_t)B_ * H_ * T_ * sizeof(float), stream);
    attn_mfma<<<NBLK_, 256, 0, stream>>>(qkvg, Lg, Ksb, Vtb, Yacc, Dacc);

    // 4b) normalize -> ybb (bf16)
    normalize_kernel<<<(M * C_ / 8) / 256, 256, 0, stream>>>(Yacc, Dacc, ybb);

    // 5) out = ybb @ w_proj  (MFMA bf16; overwrites Yacc/d_out)
    gemm_bf16<<<dim3(C_ / 128, M / 128), 256, 0, stream>>>(
        ybb, Bt2, out, M, C_, H_ * D_);
}

// Round 7
// 115.101 us; speedup vs baseline: 1.1701x; 1.0070x over previous
//
#include <hip/hip_runtime.h>
#include <math.h>

// Problem constants (fixed by setup_inputs)
constexpr int B_ = 2, T_ = 2048, C_ = 512, H_ = 8, D_ = 64;
constexpr int QKVG_ = 3 * H_ * D_ + H_;   // 1544
constexpr float GATE_BIAS_ = 6.906768f;
constexpr int NPAD1_ = 1664;              // 13 * 128 (gemm1 padded N)
constexpr int SC_ = 8;                    // s-tiles per attn chunk
constexpr int NBLK_ = 1280;               // total useful attn blocks (16 bh x 80)

typedef __attribute__((ext_vector_type(8))) short short8;
typedef __attribute__((ext_vector_type(4))) float f32x4;

__device__ __forceinline__ unsigned short f2b(float f) {
    unsigned int u = __float_as_uint(f);
    unsigned int r = (u + 0x7fffu + ((u >> 16) & 1u)) >> 16;   // RNE
    return (unsigned short)r;
}
__device__ __forceinline__ short8 pack8(float4 a, float4 b) {
    short8 r;
    r[0] = (short)f2b(a.x); r[1] = (short)f2b(a.y);
    r[2] = (short)f2b(a.z); r[3] = (short)f2b(a.w);
    r[4] = (short)f2b(b.x); r[5] = (short)f2b(b.y);
    r[6] = (short)f2b(b.z); r[7] = (short)f2b(b.w);
    return r;
}

// ---------------------------------------------------------------------------
// zero_acc: vectorized zero of Yacc (2,097,152 f) + Dacc (32,768 f)
// 2080 blocks x 256 threads x float4  (replaces slow rocclr fillBuffer)
// ---------------------------------------------------------------------------
__global__ __launch_bounds__(256) void zero_acc(
    float* __restrict__ Yacc, float* __restrict__ Dacc)
{
    const int gid = blockIdx.x * 256 + threadIdx.x;
    const float4 z = make_float4(0.f, 0.f, 0.f, 0.f);
    if (gid < 524288) ((float4*)Yacc)[gid] = z;
    if (gid < 8192)   ((float4*)Dacc)[gid] = z;
}

// ---------------------------------------------------------------------------
// cvt_bf16: fp32 -> bf16, 8 elements/thread
// ---------------------------------------------------------------------------
__global__ __launch_bounds__(256) void cvt_bf16(
    const float* __restrict__ in, unsigned short* __restrict__ outp, int n8)
{
    const int i = blockIdx.x * 256 + threadIdx.x;
    if (i < n8) {
        float4 f0 = *(const float4*)(in + (size_t)i * 8);
        float4 f1 = *(const float4*)(in + (size_t)i * 8 + 4);
        *(short8*)(outp + (size_t)i * 8) = pack8(f0, f1);
    }
}

// ---------------------------------------------------------------------------
// packT: W[K][N] fp32 row-major -> Bt[Npad][K] bf16 (transposed, zero-padded)
// ---------------------------------------------------------------------------
__global__ __launch_bounds__(256) void packT(
    const float* __restrict__ W, unsigned short* __restrict__ Bt,
    int K, int N)
{
    __shared__ float Ws[64][65];
    const int tid = threadIdx.x;
    const int nt = blockIdx.x * 64;
    const int kt = blockIdx.y * 64;

    {
        const int r = tid >> 2;
        const int c0 = (tid & 3) * 16;
#pragma unroll
        for (int j = 0; j < 16; ++j) {
            const int n = nt + c0 + j;
            Ws[r][c0 + j] = (n < N) ? W[(size_t)(kt + r) * N + n] : 0.f;
        }
    }
    __syncthreads();
    {
        const int d = tid >> 2;
        const int kc = (tid & 3) * 16;
        short8 o0, o1;
#pragma unroll
        for (int j = 0; j < 8; ++j) o0[j] = (short)f2b(Ws[kc + j][d]);
#pragma unroll
        for (int j = 0; j < 8; ++j) o1[j] = (short)f2b(Ws[kc + 8 + j][d]);
        unsigned short* op = Bt + (size_t)(nt + d) * K + kt + kc;
        *(short8*)(op + 0) = o0;
        *(short8*)(op + 8) = o1;
    }
}

// ---------------------------------------------------------------------------
// gemm_bf16: C[M,N] f32 = A[M,K]bf16 @ Bt[Npad,K]bf16^T  (unchanged)
// ---------------------------------------------------------------------------
__global__ __launch_bounds__(256) void gemm_bf16(
    const unsigned short* __restrict__ A, const unsigned short* __restrict__ Bt,
    float* __restrict__ C, int M, int N, int K)
{
    __shared__ __align__(16) char AsB[128 * 128];
    __shared__ __align__(16) char BsB[128 * 128];

    const int tid = threadIdx.x;
    const int wave = tid >> 6, lane = tid & 63;
    const int l15 = lane & 15, lhi = lane >> 4;
    const int wr = wave >> 1, wc = wave & 1;
    const int bm = blockIdx.y * 128, bn = blockIdx.x * 128;

    f32x4 acc[4][4];
#pragma unroll
    for (int i = 0; i < 4; ++i)
#pragma unroll
        for (int j = 0; j < 4; ++j) acc[i][j] = (f32x4){0.f, 0.f, 0.f, 0.f};

    const unsigned short* Arow = A + (size_t)bm * K;
    const unsigned short* Brow = Bt + (size_t)bn * K;
    const int sw = (l15 & 7) << 4;

    for (int k0 = 0; k0 < K; k0 += 64) {
        __syncthreads();
#pragma unroll
        for (int p = 0; p < 4; ++p) {
            const int idx = p * 256 + tid;
            const int row = idx >> 3;
            const int kc = (idx & 7) * 8;
            const int ldso = row * 128 + ((kc * 2) ^ ((row & 7) << 4));
            *(short8*)(AsB + ldso) = *(const short8*)(Arow + (size_t)row * K + k0 + kc);
            *(short8*)(BsB + ldso) = *(const short8*)(Brow + (size_t)row * K + k0 + kc);
        }
        __syncthreads();

        short8 af[4][2];
#pragma unroll
        for (int mi = 0; mi < 4; ++mi) {
            const int row = wr * 64 + mi * 16 + l15;
#pragma unroll
            for (int kk = 0; kk < 2; ++kk)
                af[mi][kk] = *(const short8*)(AsB + row * 128 + ((kk * 64 + lhi * 16) ^ sw));
        }
#pragma unroll
        for (int ni = 0; ni < 4; ++ni) {
            const int row = wc * 64 + ni * 16 + l15;
            short8 bf0 = *(const short8*)(BsB + row * 128 + ((lhi * 16) ^ sw));
            short8 bf1 = *(const short8*)(BsB + row * 128 + ((64 + lhi * 16) ^ sw));
#pragma unroll
            for (int mi = 0; mi < 4; ++mi) {
                acc[mi][ni] = __builtin_amdgcn_mfma_f32_16x16x32_bf16(af[mi][0], bf0, acc[mi][ni], 0, 0, 0);
                acc[mi][ni] = __builtin_amdgcn_mfma_f32_16x16x32_bf16(af[mi][1], bf1, acc[mi][ni], 0, 0, 0);
            }
        }
    }

#pragma unroll
    for (int mi = 0; mi < 4; ++mi) {
        const int gm = bm + wr * 64 + mi * 16 + lhi * 4;
#pragma unroll
        for (int r = 0; r < 4; ++r) {
            float* crow = C + (size_t)(gm + r) * N;
#pragma unroll
            for (int ni = 0; ni < 4; ++ni) {
                const int gn = bn + wc * 64 + ni * 16 + l15;
                if (gn < N) crow[gn] = acc[mi][ni][r];
            }
        }
    }
}

// ---------------------------------------------------------------------------
// prep: RoPE q,k in-place + log-sigmoid gate -> Lg
// ---------------------------------------------------------------------------
__global__ __launch_bounds__(256) void prep_kernel(
    float* __restrict__ qkvg, float* __restrict__ Lg)
{
    const int gid = blockIdx.x * 256 + threadIdx.x;
    const int i = gid & 31;
    const int h = (gid >> 5) & 7;
    const int t = (gid >> 8) & 2047;
    const int b = gid >> 19;

    const float div = 6.2831853071795864f * exp2f((float)i * (-11.0f / 32.0f));
    const float ang = (float)t * div;
    const float sn = sinf(ang);
    const float cs = cosf(ang);

    float* qp = qkvg + (size_t)(b * T_ + t) * QKVG_ + h * 64 + 2 * i;
    float x1 = qp[0], x2 = qp[1];
    qp[0] = x1 * cs - x2 * sn;
    qp[1] = x2 * cs + x1 * sn;
    float* kp = qp + 512;
    x1 = kp[0]; x2 = kp[1];
    kp[0] = x1 * cs - x2 * sn;
    kp[1] = x2 * cs + x1 * sn;

    if (i == 0) {
        const float z = qkvg[(size_t)(b * T_ + t) * QKVG_ + 1536 + h] + GATE_BIAS_;
        const float lg = (z > 0.f) ? -log1pf(expf(-z)) : (z - log1pf(expf(z)));
        Lg[(size_t)(b * H_ + h) * T_ + t] = lg;
    }
}

// ---------------------------------------------------------------------------
// cumsum over t per (b,h)
// ---------------------------------------------------------------------------
__global__ __launch_bounds__(64) void cumsum_kernel(float* __restrict__ Lg)
{
    const int bh = blockIdx.x;
    const int lane = threadIdx.x;
    float* p = Lg + (size_t)bh * T_;
    float carry = 0.f;
    for (int c0 = 0; c0 < T_; c0 += 64) {
        float v = p[c0 + lane];
#pragma unroll
        for (int off = 1; off < 64; off <<= 1) {
            float n = __shfl_up(v, off, 64);
            if (lane >= off) v += n;
        }
        v += carry;
        p[c0 + lane] = v;
        carry = __shfl(v, 63, 64);
    }
}

// ---------------------------------------------------------------------------
// kv_pack: K (RoPE'd fp32 in qkvg) -> Ksb[bh][t][d] bf16, scaled e^(-L/2);
//          V (fp32 in qkvg)       -> Vtb[bh][d][t] bf16 (transposed)
// ---------------------------------------------------------------------------
__global__ __launch_bounds__(256) void kv_pack(
    const float* __restrict__ qkvg, const float* __restrict__ Lg,
    unsigned short* __restrict__ Ksb, unsigned short* __restrict__ Vtb)
{
    __shared__ float Vs[64][68];
    const int tid = threadIdx.x;
    const int stile = blockIdx.x;
    const int bh = blockIdx.y;
    const int b = bh >> 3, h = bh & 7;
    const int r = tid >> 2, c = tid & 3;
    const int t = stile * 64 + r;

    {
        const float eK = __expf(-0.5f * Lg[(size_t)bh * T_ + t]);
        const float* kp = qkvg + (size_t)(b * T_ + t) * QKVG_ + 512 + h * 64 + c * 16;
        float4 k0 = *(const float4*)(kp + 0);
        float4 k1 = *(const float4*)(kp + 4);
        float4 k2 = *(const float4*)(kp + 8);
        float4 k3 = *(const float4*)(kp + 12);
        k0.x *= eK; k0.y *= eK; k0.z *= eK; k0.w *= eK;
        k1.x *= eK; k1.y *= eK; k1.z *= eK; k1.w *= eK;
        k2.x *= eK; k2.y *= eK; k2.z *= eK; k2.w *= eK;
        k3.x *= eK; k3.y *= eK; k3.z *= eK; k3.w *= eK;
        unsigned short* op = Ksb + ((size_t)bh * T_ + t) * 64 + c * 16;
        *(short8*)(op + 0) = pack8(k0, k1);
        *(short8*)(op + 8) = pack8(k2, k3);
    }
    {
        const float* vp = qkvg + (size_t)(b * T_ + t) * QKVG_ + 1024 + h * 64 + c * 16;
        *(float4*)&Vs[r][c * 16 + 0]  = *(const float4*)(vp + 0);
        *(float4*)&Vs[r][c * 16 + 4]  = *(const float4*)(vp + 4);
        *(float4*)&Vs[r][c * 16 + 8]  = *(const float4*)(vp + 8);
        *(float4*)&Vs[r][c * 16 + 12] = *(const float4*)(vp + 12);
    }
    __syncthreads();
    {
        const int d = tid >> 2, cc = tid & 3;
        short8 o0, o1;
#pragma unroll
        for (int j = 0; j < 8; ++j) o0[j] = (short)f2b(Vs[cc * 16 + j][d]);
#pragma unroll
        for (int j = 0; j < 8; ++j) o1[j] = (short)f2b(Vs[cc * 16 + 8 + j][d]);
        unsigned short* op = Vtb + ((size_t)bh * 64 + d) * T_ + stile * 64 + cc * 16;
        *(short8*)(op + 0) = o0;
        *(short8*)(op + 8) = o1;
    }
}

// ---------------------------------------------------------------------------
// attn_mfma: gate-prescaled scores p = (q'.k')^2; XCD-pinned compact grid.
// ---------------------------------------------------------------------------
__global__ __launch_bounds__(256) void attn_mfma(
    const float* __restrict__ qkvg, const float* __restrict__ Lg,
    const unsigned short* __restrict__ Ksb, const unsigned short* __restrict__ Vtb,
    float* __restrict__ Yacc, float* __restrict__ Dacc)
{
    __shared__ __align__(16) char smem[24576];
    char* KsB = smem;                 // 8 KB [s][d] bf16 swizzled
    char* VtB = smem + 8192;          // 8 KB [d][s] bf16 swizzled
    char* PsB = smem + 16384;         // 8 KB 4 waves x [16][64] bf16 swizzled

    const int wg = blockIdx.x;
    const int xcd = wg & 7;
    const int slot = wg >> 3;              // 0..159
    const int bh = (slot < 80) ? xcd : 8 + xcd;
    const int rem = (slot < 80) ? slot : slot - 80;
    const int rr = 79 - rem;               // big-bt chunks first
    int bt, sc;
    if (rr < 8)       { bt = rr; sc = 0; }
    else if (rr < 24) { const int q = rr - 8;  bt = 8 + (q >> 1);  sc = q & 1; }
    else if (rr < 48) { const int q = rr - 24; bt = 16 + q / 3;    sc = q % 3; }
    else              { const int q = rr - 48; bt = 24 + (q >> 2); sc = q & 3; }
    const int st0 = sc * SC_;
    const int st1 = min(st0 + SC_ - 1, bt);

    const int tid = threadIdx.x;
    const int wave = tid >> 6;
    const int lane = tid & 63;
    const int l15 = lane & 15;
    const int lhi = lane >> 4;
    const int b = bh >> 3, h = bh & 7;
    const int t0 = bt * 64;

    const int qrow = t0 + wave * 16 + l15;
    const float eQ = __expf(0.5f * Lg[(size_t)bh * T_ + qrow]) * 0.125f;
    const float* qp = qkvg + (size_t)(b * T_ + qrow) * QKVG_ + h * 64 + lhi * 8;
    short8 qf[2];
#pragma unroll
    for (int kk = 0; kk < 2; ++kk) {
        float4 f0 = *(const float4*)(qp + kk * 32);
        float4 f1 = *(const float4*)(qp + kk * 32 + 4);
        f0.x *= eQ; f0.y *= eQ; f0.z *= eQ; f0.w *= eQ;
        f1.x *= eQ; f1.y *= eQ; f1.z *= eQ; f1.w *= eQ;
        qf[kk] = pack8(f0, f1);
    }

    f32x4 accY[4];
#pragma unroll
    for (int n = 0; n < 4; ++n) accY[n] = (f32x4){0.f, 0.f, 0.f, 0.f};
    float den[4] = {0.f, 0.f, 0.f, 0.f};

    const int kchunk = lhi * 16;
    const int rsw = (l15 & 7) << 4;
    const int srow = tid >> 2;
    const int c2 = (tid & 3) * 2;
    const int swr = (srow & 7) << 4;

    for (int st = st0; st <= st1; ++st) {
        __syncthreads();
        {
            const unsigned short* kp = Ksb + ((size_t)bh * T_ + st * 64 + srow) * 64 + c2 * 8;
            short8 k0 = *(const short8*)kp;
            short8 k1 = *(const short8*)(kp + 8);
            *(short8*)(KsB + srow * 128 + ((c2 * 16) ^ swr))      = k0;
            *(short8*)(KsB + srow * 128 + ((c2 * 16 + 16) ^ swr)) = k1;
            const unsigned short* vp = Vtb + ((size_t)bh * 64 + srow) * T_ + st * 64 + c2 * 8;
            short8 v0 = *(const short8*)vp;
            short8 v1 = *(const short8*)(vp + 8);
            *(short8*)(VtB + srow * 128 + ((c2 * 16) ^ swr))      = v0;
            *(short8*)(VtB + srow * 128 + ((c2 * 16 + 16) ^ swr)) = v1;
        }
        __syncthreads();

        f32x4 accS[4];
#pragma unroll
        for (int n = 0; n < 4; ++n) accS[n] = (f32x4){0.f, 0.f, 0.f, 0.f};
#pragma unroll
        for (int n = 0; n < 4; ++n) {
#pragma unroll
            for (int kk = 0; kk < 2; ++kk) {
                short8 bf = *(const short8*)(KsB + (n * 16 + l15) * 128 + ((kk * 64 + kchunk) ^ rsw));
                accS[n] = __builtin_amdgcn_mfma_f32_16x16x32_bf16(qf[kk], bf, accS[n], 0, 0, 0);
            }
        }

        const bool last = (st == bt);
        char* PsW = PsB + wave * 2048;
#pragma unroll
        for (int n = 0; n < 4; ++n) {
#pragma unroll
            for (int r = 0; r < 4; ++r) {
                const float a = accS[n][r];
                float p = a * a;
                if (last)
                    p = ((n * 16 + l15) <= wave * 16 + lhi * 4 + r) ? p : 0.f;
                den[r] += p;
                const int prow = lhi * 4 + r;
                *(unsigned short*)(PsW + prow * 128 + ((2 * (n * 16 + l15)) ^ ((prow & 7) << 4))) = f2b(p);
            }
        }

        short8 pa[2];
#pragma unroll
        for (int kk = 0; kk < 2; ++kk)
            pa[kk] = *(const short8*)(PsW + l15 * 128 + ((kk * 64 + kchunk) ^ rsw));
#pragma unroll
        for (int n = 0; n < 4; ++n) {
#pragma unroll
            for (int kk = 0; kk < 2; ++kk) {
                short8 vb = *(const short8*)(VtB + (n * 16 + l15) * 128 + ((kk * 64 + kchunk) ^ rsw));
                accY[n] = __builtin_amdgcn_mfma_f32_16x16x32_bf16(pa[kk], vb, accY[n], 0, 0, 0);
            }
        }
    }

#pragma unroll
    for (int r = 0; r < 4; ++r) {
        den[r] += __shfl_xor(den[r], 1, 64);
        den[r] += __shfl_xor(den[r], 2, 64);
        den[r] += __shfl_xor(den[r], 4, 64);
        den[r] += __shfl_xor(den[r], 8, 64);
    }

#pragma unroll
    for (int r = 0; r < 4; ++r) {
        const int t = t0 + wave * 16 + lhi * 4 + r;
        if (l15 == 0)
            atomicAdd(&Dacc[(size_t)bh * T_ + t], den[r]);
        float* yo = Yacc + (size_t)(b * T_ + t) * (H_ * D_) + h * 64 + l15;
#pragma unroll
        for (int n = 0; n < 4; ++n)
            atomicAdd(&yo[n * 16], accY[n][r]);
    }
}

// ---------------------------------------------------------------------------
// normalize: ybb[b,t,h,d] = bf16(Yacc / max(den, 1e-6))
// ---------------------------------------------------------------------------
__global__ __launch_bounds__(256) void normalize_kernel(
    const float* __restrict__ Yacc, const float* __restrict__ Dacc,
    unsigned short* __restrict__ ybb)
{
    const int gid = blockIdx.x * 256 + threadIdx.x;
    const size_t base = (size_t)gid * 8;
    const int row = (int)(base >> 9);
    const int col = (int)(base & 511);
    const int b = row >> 11, t = row & 2047, h = col >> 6;
    const float d = Dacc[(size_t)(b * H_ + h) * T_ + t];
    const float inv = 1.0f / fmaxf(d, 1e-6f);
    float4 f0 = *(const float4*)(Yacc + base);
    float4 f1 = *(const float4*)(Yacc + base + 4);
    f0.x *= inv; f0.y *= inv; f0.z *= inv; f0.w *= inv;
    f1.x *= inv; f1.y *= inv; f1.z *= inv; f1.w *= inv;
    *(short8*)(ybb + base) = pack8(f0, f1);
}

// ---------------------------------------------------------------------------
extern "C" void kernel_launch(void* const* d_in, const int* in_sizes, int n_in,
                              void* d_out, int out_size, void* d_ws, size_t ws_size,
                              hipStream_t stream)
{
    const float* x      = (const float*)d_in[0];
    const float* w_attn = (const float*)d_in[1];
    const float* w_proj = (const float*)d_in[2];
    float* out = (float*)d_out;

    // workspace layout (36.2 MB):
    // qkvg f32 | Lg | Dacc | Vtb | Bt1 | Bt2 | A (xb -> Ksb -> ybb aliased)
    float* qkvg = (float*)d_ws;
    float* Lg   = qkvg + (size_t)B_ * T_ * QKVG_;
    float* Dacc = Lg + (size_t)B_ * H_ * T_;
    unsigned short* Vtb = (unsigned short*)(Dacc + (size_t)B_ * H_ * T_);
    unsigned short* Bt1 = Vtb + (size_t)B_ * H_ * D_ * T_;
    unsigned short* Bt2 = Bt1 + (size_t)NPAD1_ * C_;
    unsigned short* xb  = Bt2 + (size_t)C_ * C_;
    unsigned short* Ksb = xb;   // alias: xb dead after gemm1
    unsigned short* ybb = xb;   // alias: Ksb dead after attn

    float* Yacc = out;          // reuse d_out as fp32 Y accumulator

    const int M = B_ * T_;      // 4096

    // 0) packs
    cvt_bf16<<<(M * C_ / 8 + 255) / 256, 256, 0, stream>>>(x, xb, M * C_ / 8);
    packT<<<dim3(NPAD1_ / 64, C_ / 64), 256, 0, stream>>>(w_attn, Bt1, C_, QKVG_);
    packT<<<dim3(C_ / 64, (H_ * D_) / 64), 256, 0, stream>>>(w_proj, Bt2, H_ * D_, C_);

    // 1) qkvg = x @ w_attn   (MFMA bf16)
    gemm_bf16<<<dim3(NPAD1_ / 128, M / 128), 256, 0, stream>>>(
        xb, Bt1, qkvg, M, QKVG_, C_);

    // 2) RoPE(q,k) in place + log-sigmoid gate
    prep_kernel<<<(B_ * T_ * H_ * 32) / 256, 256, 0, stream>>>(qkvg, Lg);

    // 3) cumsum over t per (b,h)
    cumsum_kernel<<<B_ * H_, 64, 0, stream>>>(Lg);

    // 3b) pack K (gate-prescaled) + V^T to bf16
    kv_pack<<<dim3(T_ / 64, B_ * H_), 256, 0, stream>>>(qkvg, Lg, Ksb, Vtb);

    // 4) fast zero of accumulators, then split-s attention (atomics)
    zero_acc<<<2080, 256, 0, stream>>>(Yacc, Dacc);
    attn_mfma<<<NBLK_, 256, 0, stream>>>(qkvg, Lg, Ksb, Vtb, Yacc, Dacc);

    // 4b) normalize -> ybb (bf16)
    normalize_kernel<<<(M * C_ / 8) / 256, 256, 0, stream>>>(Yacc, Dacc, ybb);

    // 5) out = ybb @ w_proj  (MFMA bf16; overwrites Yacc/d_out)
    gemm_bf16<<<dim3(C_ / 128, M / 128), 256, 0, stream>>>(
        ybb, Bt2, out, M, C_, H_ * D_);
}

// Round 8
// 99.024 us; speedup vs baseline: 1.3600x; 1.1624x over previous
//
#include <hip/hip_runtime.h>
#include <math.h>

// Problem constants (fixed by setup_inputs)
constexpr int B_ = 2, T_ = 2048, C_ = 512, H_ = 8, D_ = 64;
constexpr int QKVG_ = 3 * H_ * D_ + H_;   // 1544
constexpr float GATE_BIAS_ = 6.906768f;
constexpr int NPAD1_ = 1664;              // 13 * 128 (gemm1 padded N)
constexpr int SC_ = 8;                    // s-tiles per attn chunk
constexpr int NBLK_ = 1280;               // total useful attn blocks (16 bh x 80)
constexpr int MC_ = 4096 * 512;           // M*C = 2,097,152
constexpr int BHT_ = B_ * H_ * T_;        // 32,768

typedef __attribute__((ext_vector_type(8))) short short8;
typedef __attribute__((ext_vector_type(4))) float f32x4;

__device__ __forceinline__ unsigned short f2b(float f) {
    unsigned int u = __float_as_uint(f);
    unsigned int r = (u + 0x7fffu + ((u >> 16) & 1u)) >> 16;   // RNE
    return (unsigned short)r;
}
__device__ __forceinline__ short8 pack8(float4 a, float4 b) {
    short8 r;
    r[0] = (short)f2b(a.x); r[1] = (short)f2b(a.y);
    r[2] = (short)f2b(a.z); r[3] = (short)f2b(a.w);
    r[4] = (short)f2b(b.x); r[5] = (short)f2b(b.y);
    r[6] = (short)f2b(b.z); r[7] = (short)f2b(b.w);
    return r;
}

// ---------------------------------------------------------------------------
// pack_inputs: merged cvt_bf16(x) + packT(w_attn->Bt1) + packT(w_proj->Bt2)
// blocks: [0,1024) cvt | [1024,1232) Bt1 (26x8) | [1232,1296) Bt2 (8x8)
// ---------------------------------------------------------------------------
__device__ __forceinline__ void packT_body(
    const float* __restrict__ W, unsigned short* __restrict__ Bt,
    int K, int N, int nt, int kt, int tid, float (*Ws)[65])
{
    {
        const int r = tid >> 2;
        const int c0 = (tid & 3) * 16;
#pragma unroll
        for (int j = 0; j < 16; ++j) {
            const int n = nt + c0 + j;
            Ws[r][c0 + j] = (n < N) ? W[(size_t)(kt + r) * N + n] : 0.f;
        }
    }
    __syncthreads();
    {
        const int d = tid >> 2;
        const int kc = (tid & 3) * 16;
        short8 o0, o1;
#pragma unroll
        for (int j = 0; j < 8; ++j) o0[j] = (short)f2b(Ws[kc + j][d]);
#pragma unroll
        for (int j = 0; j < 8; ++j) o1[j] = (short)f2b(Ws[kc + 8 + j][d]);
        unsigned short* op = Bt + (size_t)(nt + d) * K + kt + kc;
        *(short8*)(op + 0) = o0;
        *(short8*)(op + 8) = o1;
    }
}

__global__ __launch_bounds__(256) void pack_inputs(
    const float* __restrict__ x, const float* __restrict__ w_attn,
    const float* __restrict__ w_proj, unsigned short* __restrict__ xb,
    unsigned short* __restrict__ Bt1, unsigned short* __restrict__ Bt2)
{
    __shared__ float Ws[64][65];
    const int bid = blockIdx.x;
    const int tid = threadIdx.x;
    if (bid < 1024) {
        const int i = bid * 256 + tid;     // exactly MC_/8 threads
        float4 f0 = *(const float4*)(x + (size_t)i * 8);
        float4 f1 = *(const float4*)(x + (size_t)i * 8 + 4);
        *(short8*)(xb + (size_t)i * 8) = pack8(f0, f1);
    } else if (bid < 1232) {
        const int q = bid - 1024;
        packT_body(w_attn, Bt1, C_, QKVG_, (q % 26) * 64, (q / 26) * 64, tid, Ws);
    } else {
        const int q = bid - 1232;
        packT_body(w_proj, Bt2, H_ * D_, C_, (q & 7) * 64, (q >> 3) * 64, tid, Ws);
    }
}

// ---------------------------------------------------------------------------
// gemm_bf16: C[M,N] f32 = A[M,K]bf16 @ Bt[Npad,K]bf16^T  (unchanged)
// ---------------------------------------------------------------------------
__global__ __launch_bounds__(256) void gemm_bf16(
    const unsigned short* __restrict__ A, const unsigned short* __restrict__ Bt,
    float* __restrict__ C, int M, int N, int K)
{
    __shared__ __align__(16) char AsB[128 * 128];
    __shared__ __align__(16) char BsB[128 * 128];

    const int tid = threadIdx.x;
    const int wave = tid >> 6, lane = tid & 63;
    const int l15 = lane & 15, lhi = lane >> 4;
    const int wr = wave >> 1, wc = wave & 1;
    const int bm = blockIdx.y * 128, bn = blockIdx.x * 128;

    f32x4 acc[4][4];
#pragma unroll
    for (int i = 0; i < 4; ++i)
#pragma unroll
        for (int j = 0; j < 4; ++j) acc[i][j] = (f32x4){0.f, 0.f, 0.f, 0.f};

    const unsigned short* Arow = A + (size_t)bm * K;
    const unsigned short* Brow = Bt + (size_t)bn * K;
    const int sw = (l15 & 7) << 4;

    for (int k0 = 0; k0 < K; k0 += 64) {
        __syncthreads();
#pragma unroll
        for (int p = 0; p < 4; ++p) {
            const int idx = p * 256 + tid;
            const int row = idx >> 3;
            const int kc = (idx & 7) * 8;
            const int ldso = row * 128 + ((kc * 2) ^ ((row & 7) << 4));
            *(short8*)(AsB + ldso) = *(const short8*)(Arow + (size_t)row * K + k0 + kc);
            *(short8*)(BsB + ldso) = *(const short8*)(Brow + (size_t)row * K + k0 + kc);
        }
        __syncthreads();

        short8 af[4][2];
#pragma unroll
        for (int mi = 0; mi < 4; ++mi) {
            const int row = wr * 64 + mi * 16 + l15;
#pragma unroll
            for (int kk = 0; kk < 2; ++kk)
                af[mi][kk] = *(const short8*)(AsB + row * 128 + ((kk * 64 + lhi * 16) ^ sw));
        }
#pragma unroll
        for (int ni = 0; ni < 4; ++ni) {
            const int row = wc * 64 + ni * 16 + l15;
            short8 bf0 = *(const short8*)(BsB + row * 128 + ((lhi * 16) ^ sw));
            short8 bf1 = *(const short8*)(BsB + row * 128 + ((64 + lhi * 16) ^ sw));
#pragma unroll
            for (int mi = 0; mi < 4; ++mi) {
                acc[mi][ni] = __builtin_amdgcn_mfma_f32_16x16x32_bf16(af[mi][0], bf0, acc[mi][ni], 0, 0, 0);
                acc[mi][ni] = __builtin_amdgcn_mfma_f32_16x16x32_bf16(af[mi][1], bf1, acc[mi][ni], 0, 0, 0);
            }
        }
    }

#pragma unroll
    for (int mi = 0; mi < 4; ++mi) {
        const int gm = bm + wr * 64 + mi * 16 + lhi * 4;
#pragma unroll
        for (int r = 0; r < 4; ++r) {
            float* crow = C + (size_t)(gm + r) * N;
#pragma unroll
            for (int ni = 0; ni < 4; ++ni) {
                const int gn = bn + wc * 64 + ni * 16 + l15;
                if (gn < N) crow[gn] = acc[mi][ni][r];
            }
        }
    }
}

// ---------------------------------------------------------------------------
// prep: RoPE q,k in-place + log-sigmoid gate -> Lg
// ---------------------------------------------------------------------------
__global__ __launch_bounds__(256) void prep_kernel(
    float* __restrict__ qkvg, float* __restrict__ Lg)
{
    const int gid = blockIdx.x * 256 + threadIdx.x;
    const int i = gid & 31;
    const int h = (gid >> 5) & 7;
    const int t = (gid >> 8) & 2047;
    const int b = gid >> 19;

    const float div = 6.2831853071795864f * exp2f((float)i * (-11.0f / 32.0f));
    const float ang = (float)t * div;
    const float sn = sinf(ang);
    const float cs = cosf(ang);

    float* qp = qkvg + (size_t)(b * T_ + t) * QKVG_ + h * 64 + 2 * i;
    float x1 = qp[0], x2 = qp[1];
    qp[0] = x1 * cs - x2 * sn;
    qp[1] = x2 * cs + x1 * sn;
    float* kp = qp + 512;
    x1 = kp[0]; x2 = kp[1];
    kp[0] = x1 * cs - x2 * sn;
    kp[1] = x2 * cs + x1 * sn;

    if (i == 0) {
        const float z = qkvg[(size_t)(b * T_ + t) * QKVG_ + 1536 + h] + GATE_BIAS_;
        const float lg = (z > 0.f) ? -log1pf(expf(-z)) : (z - log1pf(expf(z)));
        Lg[(size_t)(b * H_ + h) * T_ + t] = lg;
    }
}

// ---------------------------------------------------------------------------
// cumsum over t per (b,h)
// ---------------------------------------------------------------------------
__global__ __launch_bounds__(64) void cumsum_kernel(float* __restrict__ Lg)
{
    const int bh = blockIdx.x;
    const int lane = threadIdx.x;
    float* p = Lg + (size_t)bh * T_;
    float carry = 0.f;
    for (int c0 = 0; c0 < T_; c0 += 64) {
        float v = p[c0 + lane];
#pragma unroll
        for (int off = 1; off < 64; off <<= 1) {
            float n = __shfl_up(v, off, 64);
            if (lane >= off) v += n;
        }
        v += carry;
        p[c0 + lane] = v;
        carry = __shfl(v, 63, 64);
    }
}

// ---------------------------------------------------------------------------
// kv_pack: K (RoPE'd fp32 in qkvg) -> Ksb[bh][t][d] bf16, scaled e^(-L/2);
//          V (fp32 in qkvg)       -> Vtb[bh][d][t] bf16 (transposed)
// ---------------------------------------------------------------------------
__global__ __launch_bounds__(256) void kv_pack(
    const float* __restrict__ qkvg, const float* __restrict__ Lg,
    unsigned short* __restrict__ Ksb, unsigned short* __restrict__ Vtb)
{
    __shared__ float Vs[64][68];
    const int tid = threadIdx.x;
    const int stile = blockIdx.x;
    const int bh = blockIdx.y;
    const int b = bh >> 3, h = bh & 7;
    const int r = tid >> 2, c = tid & 3;
    const int t = stile * 64 + r;

    {
        const float eK = __expf(-0.5f * Lg[(size_t)bh * T_ + t]);
        const float* kp = qkvg + (size_t)(b * T_ + t) * QKVG_ + 512 + h * 64 + c * 16;
        float4 k0 = *(const float4*)(kp + 0);
        float4 k1 = *(const float4*)(kp + 4);
        float4 k2 = *(const float4*)(kp + 8);
        float4 k3 = *(const float4*)(kp + 12);
        k0.x *= eK; k0.y *= eK; k0.z *= eK; k0.w *= eK;
        k1.x *= eK; k1.y *= eK; k1.z *= eK; k1.w *= eK;
        k2.x *= eK; k2.y *= eK; k2.z *= eK; k2.w *= eK;
        k3.x *= eK; k3.y *= eK; k3.z *= eK; k3.w *= eK;
        unsigned short* op = Ksb + ((size_t)bh * T_ + t) * 64 + c * 16;
        *(short8*)(op + 0) = pack8(k0, k1);
        *(short8*)(op + 8) = pack8(k2, k3);
    }
    {
        const float* vp = qkvg + (size_t)(b * T_ + t) * QKVG_ + 1024 + h * 64 + c * 16;
        *(float4*)&Vs[r][c * 16 + 0]  = *(const float4*)(vp + 0);
        *(float4*)&Vs[r][c * 16 + 4]  = *(const float4*)(vp + 4);
        *(float4*)&Vs[r][c * 16 + 8]  = *(const float4*)(vp + 8);
        *(float4*)&Vs[r][c * 16 + 12] = *(const float4*)(vp + 12);
    }
    __syncthreads();
    {
        const int d = tid >> 2, cc = tid & 3;
        short8 o0, o1;
#pragma unroll
        for (int j = 0; j < 8; ++j) o0[j] = (short)f2b(Vs[cc * 16 + j][d]);
#pragma unroll
        for (int j = 0; j < 8; ++j) o1[j] = (short)f2b(Vs[cc * 16 + 8 + j][d]);
        unsigned short* op = Vtb + ((size_t)bh * 64 + d) * T_ + stile * 64 + cc * 16;
        *(short8*)(op + 0) = o0;
        *(short8*)(op + 8) = o1;
    }
}

// ---------------------------------------------------------------------------
// attn_mfma: gate-prescaled scores p = (q'.k')^2; XCD-pinned compact grid.
// Non-atomic split-s: block (bt,sc) stores its 64x64 Y tile into slice sc
// (slice 0 = d_out, slices 1-3 in Yp) and den into Dpart[sc]. No zero-init:
// normalize sums exactly nsc = bt/8+1 slices.
// ---------------------------------------------------------------------------
__global__ __launch_bounds__(256) void attn_mfma(
    const float* __restrict__ qkvg, const float* __restrict__ Lg,
    const unsigned short* __restrict__ Ksb, const unsigned short* __restrict__ Vtb,
    float* __restrict__ Y0, float* __restrict__ Yp, float* __restrict__ Dpart)
{
    __shared__ __align__(16) char smem[24576];
    char* KsB = smem;                 // 8 KB [s][d] bf16 swizzled
    char* VtB = smem + 8192;          // 8 KB [d][s] bf16 swizzled
    char* PsB = smem + 16384;         // 8 KB 4 waves x [16][64] bf16 swizzled

    const int wg = blockIdx.x;
    const int xcd = wg & 7;
    const int slot = wg >> 3;              // 0..159
    const int bh = (slot < 80) ? xcd : 8 + xcd;
    const int rem = (slot < 80) ? slot : slot - 80;
    const int rr = 79 - rem;               // big-bt chunks first
    int bt, sc;
    if (rr < 8)       { bt = rr; sc = 0; }
    else if (rr < 24) { const int q = rr - 8;  bt = 8 + (q >> 1);  sc = q & 1; }
    else if (rr < 48) { const int q = rr - 24; bt = 16 + q / 3;    sc = q % 3; }
    else              { const int q = rr - 48; bt = 24 + (q >> 2); sc = q & 3; }
    const int st0 = sc * SC_;
    const int st1 = min(st0 + SC_ - 1, bt);

    const int tid = threadIdx.x;
    const int wave = tid >> 6;
    const int lane = tid & 63;
    const int l15 = lane & 15;
    const int lhi = lane >> 4;
    const int b = bh >> 3, h = bh & 7;
    const int t0 = bt * 64;

    const int qrow = t0 + wave * 16 + l15;
    const float eQ = __expf(0.5f * Lg[(size_t)bh * T_ + qrow]) * 0.125f;
    const float* qp = qkvg + (size_t)(b * T_ + qrow) * QKVG_ + h * 64 + lhi * 8;
    short8 qf[2];
#pragma unroll
    for (int kk = 0; kk < 2; ++kk) {
        float4 f0 = *(const float4*)(qp + kk * 32);
        float4 f1 = *(const float4*)(qp + kk * 32 + 4);
        f0.x *= eQ; f0.y *= eQ; f0.z *= eQ; f0.w *= eQ;
        f1.x *= eQ; f1.y *= eQ; f1.z *= eQ; f1.w *= eQ;
        qf[kk] = pack8(f0, f1);
    }

    f32x4 accY[4];
#pragma unroll
    for (int n = 0; n < 4; ++n) accY[n] = (f32x4){0.f, 0.f, 0.f, 0.f};
    float den[4] = {0.f, 0.f, 0.f, 0.f};

    const int kchunk = lhi * 16;
    const int rsw = (l15 & 7) << 4;
    const int srow = tid >> 2;
    const int c2 = (tid & 3) * 2;
    const int swr = (srow & 7) << 4;

    for (int st = st0; st <= st1; ++st) {
        __syncthreads();
        {
            const unsigned short* kp = Ksb + ((size_t)bh * T_ + st * 64 + srow) * 64 + c2 * 8;
            short8 k0 = *(const short8*)kp;
            short8 k1 = *(const short8*)(kp + 8);
            *(short8*)(KsB + srow * 128 + ((c2 * 16) ^ swr))      = k0;
            *(short8*)(KsB + srow * 128 + ((c2 * 16 + 16) ^ swr)) = k1;
            const unsigned short* vp = Vtb + ((size_t)bh * 64 + srow) * T_ + st * 64 + c2 * 8;
            short8 v0 = *(const short8*)vp;
            short8 v1 = *(const short8*)(vp + 8);
            *(short8*)(VtB + srow * 128 + ((c2 * 16) ^ swr))      = v0;
            *(short8*)(VtB + srow * 128 + ((c2 * 16 + 16) ^ swr)) = v1;
        }
        __syncthreads();

        f32x4 accS[4];
#pragma unroll
        for (int n = 0; n < 4; ++n) accS[n] = (f32x4){0.f, 0.f, 0.f, 0.f};
#pragma unroll
        for (int n = 0; n < 4; ++n) {
#pragma unroll
            for (int kk = 0; kk < 2; ++kk) {
                short8 bf = *(const short8*)(KsB + (n * 16 + l15) * 128 + ((kk * 64 + kchunk) ^ rsw));
                accS[n] = __builtin_amdgcn_mfma_f32_16x16x32_bf16(qf[kk], bf, accS[n], 0, 0, 0);
            }
        }

        const bool last = (st == bt);
        char* PsW = PsB + wave * 2048;
#pragma unroll
        for (int n = 0; n < 4; ++n) {
#pragma unroll
            for (int r = 0; r < 4; ++r) {
                const float a = accS[n][r];
                float p = a * a;
                if (last)
                    p = ((n * 16 + l15) <= wave * 16 + lhi * 4 + r) ? p : 0.f;
                den[r] += p;
                const int prow = lhi * 4 + r;
                *(unsigned short*)(PsW + prow * 128 + ((2 * (n * 16 + l15)) ^ ((prow & 7) << 4))) = f2b(p);
            }
        }

        short8 pa[2];
#pragma unroll
        for (int kk = 0; kk < 2; ++kk)
            pa[kk] = *(const short8*)(PsW + l15 * 128 + ((kk * 64 + kchunk) ^ rsw));
#pragma unroll
        for (int n = 0; n < 4; ++n) {
#pragma unroll
            for (int kk = 0; kk < 2; ++kk) {
                short8 vb = *(const short8*)(VtB + (n * 16 + l15) * 128 + ((kk * 64 + kchunk) ^ rsw));
                accY[n] = __builtin_amdgcn_mfma_f32_16x16x32_bf16(pa[kk], vb, accY[n], 0, 0, 0);
            }
        }
    }

#pragma unroll
    for (int r = 0; r < 4; ++r) {
        den[r] += __shfl_xor(den[r], 1, 64);
        den[r] += __shfl_xor(den[r], 2, 64);
        den[r] += __shfl_xor(den[r], 4, 64);
        den[r] += __shfl_xor(den[r], 8, 64);
    }

    // plain stores into slice sc (no atomics, no zero-init needed)
    float* Ybase = (sc == 0) ? Y0 : (Yp + (size_t)(sc - 1) * MC_);
    float* Dbase = Dpart + (size_t)sc * BHT_;
#pragma unroll
    for (int r = 0; r < 4; ++r) {
        const int t = t0 + wave * 16 + lhi * 4 + r;
        if (l15 == 0)
            Dbase[(size_t)bh * T_ + t] = den[r];
        float* yo = Ybase + (size_t)(b * T_ + t) * (H_ * D_) + h * 64 + l15;
#pragma unroll
        for (int n = 0; n < 4; ++n)
            yo[n * 16] = accY[n][r];
    }
}

// ---------------------------------------------------------------------------
// normalize: ybb = bf16( (sum of nsc Y slices) / max(sum of nsc den, 1e-6) )
// nsc = bt/8 + 1 slices exist for row-tile bt = t/64.
// ---------------------------------------------------------------------------
__global__ __launch_bounds__(256) void normalize_kernel(
    const float* __restrict__ Y0, const float* __restrict__ Yp,
    const float* __restrict__ Dpart, unsigned short* __restrict__ ybb)
{
    const int gid = blockIdx.x * 256 + threadIdx.x;
    const size_t base = (size_t)gid * 8;
    const int row = (int)(base >> 9);
    const int col = (int)(base & 511);
    const int b = row >> 11, t = row & 2047, h = col >> 6;
    const int bh = b * H_ + h;
    const int nsc = ((t >> 6) >> 3) + 1;      // bt/8 + 1

    float d = Dpart[(size_t)bh * T_ + t];
    float4 f0 = *(const float4*)(Y0 + base);
    float4 f1 = *(const float4*)(Y0 + base + 4);
    for (int s = 1; s < nsc; ++s) {
        d += Dpart[(size_t)s * BHT_ + (size_t)bh * T_ + t];
        const float* yp = Yp + (size_t)(s - 1) * MC_ + base;
        float4 g0 = *(const float4*)(yp);
        float4 g1 = *(const float4*)(yp + 4);
        f0.x += g0.x; f0.y += g0.y; f0.z += g0.z; f0.w += g0.w;
        f1.x += g1.x; f1.y += g1.y; f1.z += g1.z; f1.w += g1.w;
    }
    const float inv = 1.0f / fmaxf(d, 1e-6f);
    f0.x *= inv; f0.y *= inv; f0.z *= inv; f0.w *= inv;
    f1.x *= inv; f1.y *= inv; f1.z *= inv; f1.w *= inv;
    *(short8*)(ybb + base) = pack8(f0, f1);
}

// ---------------------------------------------------------------------------
extern "C" void kernel_launch(void* const* d_in, const int* in_sizes, int n_in,
                              void* d_out, int out_size, void* d_ws, size_t ws_size,
                              hipStream_t stream)
{
    const float* x      = (const float*)d_in[0];
    const float* w_attn = (const float*)d_in[1];
    const float* w_proj = (const float*)d_in[2];
    float* out = (float*)d_out;

    // workspace (~60.5 MB of ~256 MB):
    // qkvg f32 | Lg | Dpart[4] | Vtb | Bt1 | Bt2 | A (xb->Ksb->ybb) | Yp[3]
    float* qkvg = (float*)d_ws;
    float* Lg    = qkvg + (size_t)B_ * T_ * QKVG_;           // 6,322,176 f
    float* Dpart = Lg + BHT_;                                // 4*32768 f
    unsigned short* Vtb = (unsigned short*)(Dpart + 4 * BHT_);
    unsigned short* Bt1 = Vtb + (size_t)B_ * H_ * D_ * T_;   // +2,097,152 us
    unsigned short* Bt2 = Bt1 + (size_t)NPAD1_ * C_;         // +851,968 us
    unsigned short* xb  = Bt2 + (size_t)C_ * C_;             // +262,144 us
    unsigned short* Ksb = xb;   // alias: xb dead after gemm1
    unsigned short* ybb = xb;   // alias: Ksb dead after attn
    float* Yp = (float*)(xb + (size_t)MC_);                  // 3 * 8 MB slices

    const int M = B_ * T_;      // 4096

    // 0) merged packs: x->bf16, w_attn->Bt1, w_proj->Bt2
    pack_inputs<<<1296, 256, 0, stream>>>(x, w_attn, w_proj, xb, Bt1, Bt2);

    // 1) qkvg = x @ w_attn   (MFMA bf16)
    gemm_bf16<<<dim3(NPAD1_ / 128, M / 128), 256, 0, stream>>>(
        xb, Bt1, qkvg, M, QKVG_, C_);

    // 2) RoPE(q,k) in place + log-sigmoid gate
    prep_kernel<<<(B_ * T_ * H_ * 32) / 256, 256, 0, stream>>>(qkvg, Lg);

    // 3) cumsum over t per (b,h)
    cumsum_kernel<<<B_ * H_, 64, 0, stream>>>(Lg);

    // 3b) pack K (gate-prescaled) + V^T to bf16
    kv_pack<<<dim3(T_ / 64, B_ * H_), 256, 0, stream>>>(qkvg, Lg, Ksb, Vtb);

    // 4) split-s attention, non-atomic partial slices
    attn_mfma<<<NBLK_, 256, 0, stream>>>(qkvg, Lg, Ksb, Vtb, out, Yp, Dpart);

    // 4b) normalize + slice-sum -> ybb (bf16)
    normalize_kernel<<<(MC_ / 8) / 256, 256, 0, stream>>>(out, Yp, Dpart, ybb);

    // 5) out = ybb @ w_proj  (MFMA bf16; overwrites d_out)
    gemm_bf16<<<dim3(C_ / 128, M / 128), 256, 0, stream>>>(
        ybb, Bt2, out, M, C_, H_ * D_);
}

// Round 9
// 90.050 us; speedup vs baseline: 1.4956x; 1.0997x over previous
//
#include <hip/hip_runtime.h>
#include <math.h>

// Problem constants (fixed by setup_inputs)
constexpr int B_ = 2, T_ = 2048, C_ = 512, H_ = 8, D_ = 64;
constexpr int QKVG_ = 3 * H_ * D_ + H_;   // 1544
constexpr float GATE_BIAS_ = 6.906768f;
constexpr int NPAD1_ = 1664;              // 13 * 128 (gemm1 padded N)
constexpr int SC_ = 8;                    // s-tiles per attn chunk
constexpr int NBLK_ = 1280;               // total useful attn blocks (16 bh x 80)
constexpr int MC_ = 4096 * 512;           // M*C = 2,097,152
constexpr int BHT_ = B_ * H_ * T_;        // 32,768

typedef __attribute__((ext_vector_type(8))) short short8;
typedef __attribute__((ext_vector_type(4))) float f32x4;

__device__ __forceinline__ unsigned short f2b(float f) {
    unsigned int u = __float_as_uint(f);
    unsigned int r = (u + 0x7fffu + ((u >> 16) & 1u)) >> 16;   // RNE
    return (unsigned short)r;
}
__device__ __forceinline__ short8 pack8(float4 a, float4 b) {
    short8 r;
    r[0] = (short)f2b(a.x); r[1] = (short)f2b(a.y);
    r[2] = (short)f2b(a.z); r[3] = (short)f2b(a.w);
    r[4] = (short)f2b(b.x); r[5] = (short)f2b(b.y);
    r[6] = (short)f2b(b.z); r[7] = (short)f2b(b.w);
    return r;
}

// ---------------------------------------------------------------------------
// pack_inputs: merged cvt_bf16(x) + packT(w_attn->Bt1) + packT(w_proj->Bt2)
// ---------------------------------------------------------------------------
__device__ __forceinline__ void packT_body(
    const float* __restrict__ W, unsigned short* __restrict__ Bt,
    int K, int N, int nt, int kt, int tid, float (*Ws)[65])
{
    {
        const int r = tid >> 2;
        const int c0 = (tid & 3) * 16;
#pragma unroll
        for (int j = 0; j < 16; ++j) {
            const int n = nt + c0 + j;
            Ws[r][c0 + j] = (n < N) ? W[(size_t)(kt + r) * N + n] : 0.f;
        }
    }
    __syncthreads();
    {
        const int d = tid >> 2;
        const int kc = (tid & 3) * 16;
        short8 o0, o1;
#pragma unroll
        for (int j = 0; j < 8; ++j) o0[j] = (short)f2b(Ws[kc + j][d]);
#pragma unroll
        for (int j = 0; j < 8; ++j) o1[j] = (short)f2b(Ws[kc + 8 + j][d]);
        unsigned short* op = Bt + (size_t)(nt + d) * K + kt + kc;
        *(short8*)(op + 0) = o0;
        *(short8*)(op + 8) = o1;
    }
}

__global__ __launch_bounds__(256) void pack_inputs(
    const float* __restrict__ x, const float* __restrict__ w_attn,
    const float* __restrict__ w_proj, unsigned short* __restrict__ xb,
    unsigned short* __restrict__ Bt1, unsigned short* __restrict__ Bt2)
{
    __shared__ float Ws[64][65];
    const int bid = blockIdx.x;
    const int tid = threadIdx.x;
    if (bid < 1024) {
        const int i = bid * 256 + tid;
        float4 f0 = *(const float4*)(x + (size_t)i * 8);
        float4 f1 = *(const float4*)(x + (size_t)i * 8 + 4);
        *(short8*)(xb + (size_t)i * 8) = pack8(f0, f1);
    } else if (bid < 1232) {
        const int q = bid - 1024;
        packT_body(w_attn, Bt1, C_, QKVG_, (q % 26) * 64, (q / 26) * 64, tid, Ws);
    } else {
        const int q = bid - 1232;
        packT_body(w_proj, Bt2, H_ * D_, C_, (q & 7) * 64, (q >> 3) * 64, tid, Ws);
    }
}

// ---------------------------------------------------------------------------
// gemm_bf16: C[M,N] f32 = A[M,K]bf16 @ Bt[Npad,K]bf16^T  (unchanged)
// ---------------------------------------------------------------------------
__global__ __launch_bounds__(256) void gemm_bf16(
    const unsigned short* __restrict__ A, const unsigned short* __restrict__ Bt,
    float* __restrict__ C, int M, int N, int K)
{
    __shared__ __align__(16) char AsB[128 * 128];
    __shared__ __align__(16) char BsB[128 * 128];

    const int tid = threadIdx.x;
    const int wave = tid >> 6, lane = tid & 63;
    const int l15 = lane & 15, lhi = lane >> 4;
    const int wr = wave >> 1, wc = wave & 1;
    const int bm = blockIdx.y * 128, bn = blockIdx.x * 128;

    f32x4 acc[4][4];
#pragma unroll
    for (int i = 0; i < 4; ++i)
#pragma unroll
        for (int j = 0; j < 4; ++j) acc[i][j] = (f32x4){0.f, 0.f, 0.f, 0.f};

    const unsigned short* Arow = A + (size_t)bm * K;
    const unsigned short* Brow = Bt + (size_t)bn * K;
    const int sw = (l15 & 7) << 4;

    for (int k0 = 0; k0 < K; k0 += 64) {
        __syncthreads();
#pragma unroll
        for (int p = 0; p < 4; ++p) {
            const int idx = p * 256 + tid;
            const int row = idx >> 3;
            const int kc = (idx & 7) * 8;
            const int ldso = row * 128 + ((kc * 2) ^ ((row & 7) << 4));
            *(short8*)(AsB + ldso) = *(const short8*)(Arow + (size_t)row * K + k0 + kc);
            *(short8*)(BsB + ldso) = *(const short8*)(Brow + (size_t)row * K + k0 + kc);
        }
        __syncthreads();

        short8 af[4][2];
#pragma unroll
        for (int mi = 0; mi < 4; ++mi) {
            const int row = wr * 64 + mi * 16 + l15;
#pragma unroll
            for (int kk = 0; kk < 2; ++kk)
                af[mi][kk] = *(const short8*)(AsB + row * 128 + ((kk * 64 + lhi * 16) ^ sw));
        }
#pragma unroll
        for (int ni = 0; ni < 4; ++ni) {
            const int row = wc * 64 + ni * 16 + l15;
            short8 bf0 = *(const short8*)(BsB + row * 128 + ((lhi * 16) ^ sw));
            short8 bf1 = *(const short8*)(BsB + row * 128 + ((64 + lhi * 16) ^ sw));
#pragma unroll
            for (int mi = 0; mi < 4; ++mi) {
                acc[mi][ni] = __builtin_amdgcn_mfma_f32_16x16x32_bf16(af[mi][0], bf0, acc[mi][ni], 0, 0, 0);
                acc[mi][ni] = __builtin_amdgcn_mfma_f32_16x16x32_bf16(af[mi][1], bf1, acc[mi][ni], 0, 0, 0);
            }
        }
    }

#pragma unroll
    for (int mi = 0; mi < 4; ++mi) {
        const int gm = bm + wr * 64 + mi * 16 + lhi * 4;
#pragma unroll
        for (int r = 0; r < 4; ++r) {
            float* crow = C + (size_t)(gm + r) * N;
#pragma unroll
            for (int ni = 0; ni < 4; ++ni) {
                const int gn = bn + wc * 64 + ni * 16 + l15;
                if (gn < N) crow[gn] = acc[mi][ni][r];
            }
        }
    }
}

// ---------------------------------------------------------------------------
// gate_cumsum: one block per (b,h). Reads gate col from qkvg, log-sigmoid,
// block-wide inclusive scan (8 elems/thread, wave scan, cross-wave offsets),
// writes Lg[bh][t]. Replaces prep's gate pass + 64-thread serial cumsum.
// ---------------------------------------------------------------------------
__global__ __launch_bounds__(256) void gate_cumsum(
    const float* __restrict__ qkvg, float* __restrict__ Lg)
{
    __shared__ float wsum[4];
    const int bh = blockIdx.x;
    const int b = bh >> 3, h = bh & 7;
    const int tid = threadIdx.x;
    const int lane = tid & 63, wv = tid >> 6;

    const float* gp = qkvg + (size_t)(b * T_ + tid * 8) * QKVG_ + 1536 + h;
    float v[8];
    float s = 0.f;
#pragma unroll
    for (int j = 0; j < 8; ++j) {
        const float z = gp[(size_t)j * QKVG_] + GATE_BIAS_;
        const float lg = (z > 0.f) ? -log1pf(expf(-z)) : (z - log1pf(expf(z)));
        s += lg;
        v[j] = s;
    }
    // inclusive wave scan of per-thread totals
    float ssum = s;
#pragma unroll
    for (int off = 1; off < 64; off <<= 1) {
        float n = __shfl_up(ssum, off, 64);
        if (lane >= off) ssum += n;
    }
    if (lane == 63) wsum[wv] = ssum;
    __syncthreads();
    float base = ssum - s;                   // exclusive prefix within wave
#pragma unroll
    for (int w = 0; w < 3; ++w)
        base += (w < wv) ? wsum[w] : 0.f;

    float* op = Lg + (size_t)bh * T_ + tid * 8;
#pragma unroll
    for (int j = 0; j < 8; ++j) op[j] = v[j] + base;
}

// ---------------------------------------------------------------------------
// qkv_pack: fused RoPE + gate-prescale + bf16 pack.
//   Q -> Qsb[bh][t][d] = bf16( rope(q) * e^(+L/2) / 8 )
//   K -> Ksb[bh][t][d] = bf16( rope(k) * e^(-L/2) )
//   V -> Vtb[bh][d][t] = bf16( v )            (transposed via LDS)
// RoPE pairs (2i,2i+1) are adjacent within each thread's 16-dim chunk.
// ---------------------------------------------------------------------------
__global__ __launch_bounds__(256) void qkv_pack(
    const float* __restrict__ qkvg, const float* __restrict__ Lg,
    unsigned short* __restrict__ Qsb, unsigned short* __restrict__ Ksb,
    unsigned short* __restrict__ Vtb)
{
    __shared__ float Vs[64][68];
    const int tid = threadIdx.x;
    const int stile = blockIdx.x;
    const int bh = blockIdx.y;
    const int b = bh >> 3, h = bh & 7;
    const int r = tid >> 2, c = tid & 3;
    const int t = stile * 64 + r;

    // sin/cos for this thread's 8 pairs (i = c*8 + j)
    float sn[8], cs[8];
#pragma unroll
    for (int j = 0; j < 8; ++j) {
        const int i = c * 8 + j;
        const float div = 6.2831853071795864f * exp2f((float)i * (-11.0f / 32.0f));
        const float ang = (float)t * div;
        sn[j] = sinf(ang);
        cs[j] = cosf(ang);
    }

    const float Lt = Lg[(size_t)bh * T_ + t];
    const float eQ = __expf(0.5f * Lt) * 0.125f;
    const float eK = __expf(-0.5f * Lt);
    const float* basep = qkvg + (size_t)(b * T_ + t) * QKVG_ + h * 64 + c * 16;

    // Q
    {
        float q[16];
        *(float4*)&q[0]  = *(const float4*)(basep + 0);
        *(float4*)&q[4]  = *(const float4*)(basep + 4);
        *(float4*)&q[8]  = *(const float4*)(basep + 8);
        *(float4*)&q[12] = *(const float4*)(basep + 12);
#pragma unroll
        for (int j = 0; j < 8; ++j) {
            const float x1 = q[2 * j], x2 = q[2 * j + 1];
            q[2 * j]     = (x1 * cs[j] - x2 * sn[j]) * eQ;
            q[2 * j + 1] = (x2 * cs[j] + x1 * sn[j]) * eQ;
        }
        unsigned short* op = Qsb + ((size_t)bh * T_ + t) * 64 + c * 16;
        *(short8*)(op + 0) = pack8(*(float4*)&q[0], *(float4*)&q[4]);
        *(short8*)(op + 8) = pack8(*(float4*)&q[8], *(float4*)&q[12]);
    }
    // K
    {
        float k[16];
        *(float4*)&k[0]  = *(const float4*)(basep + 512);
        *(float4*)&k[4]  = *(const float4*)(basep + 516);
        *(float4*)&k[8]  = *(const float4*)(basep + 520);
        *(float4*)&k[12] = *(const float4*)(basep + 524);
#pragma unroll
        for (int j = 0; j < 8; ++j) {
            const float x1 = k[2 * j], x2 = k[2 * j + 1];
            k[2 * j]     = (x1 * cs[j] - x2 * sn[j]) * eK;
            k[2 * j + 1] = (x2 * cs[j] + x1 * sn[j]) * eK;
        }
        unsigned short* op = Ksb + ((size_t)bh * T_ + t) * 64 + c * 16;
        *(short8*)(op + 0) = pack8(*(float4*)&k[0], *(float4*)&k[4]);
        *(short8*)(op + 8) = pack8(*(float4*)&k[8], *(float4*)&k[12]);
    }
    // V (transpose via LDS)
    {
        *(float4*)&Vs[r][c * 16 + 0]  = *(const float4*)(basep + 1024);
        *(float4*)&Vs[r][c * 16 + 4]  = *(const float4*)(basep + 1028);
        *(float4*)&Vs[r][c * 16 + 8]  = *(const float4*)(basep + 1032);
        *(float4*)&Vs[r][c * 16 + 12] = *(const float4*)(basep + 1036);
    }
    __syncthreads();
    {
        const int d = tid >> 2, cc = tid & 3;
        short8 o0, o1;
#pragma unroll
        for (int j = 0; j < 8; ++j) o0[j] = (short)f2b(Vs[cc * 16 + j][d]);
#pragma unroll
        for (int j = 0; j < 8; ++j) o1[j] = (short)f2b(Vs[cc * 16 + 8 + j][d]);
        unsigned short* op = Vtb + ((size_t)bh * 64 + d) * T_ + stile * 64 + cc * 16;
        *(short8*)(op + 0) = o0;
        *(short8*)(op + 8) = o1;
    }
}

// ---------------------------------------------------------------------------
// attn_mfma: scores p = (q'.k')^2 (gates prefolded); XCD-pinned compact grid.
// Non-atomic split-s partial slices (slice 0 = d_out).
// ---------------------------------------------------------------------------
__global__ __launch_bounds__(256) void attn_mfma(
    const unsigned short* __restrict__ Qsb, const unsigned short* __restrict__ Ksb,
    const unsigned short* __restrict__ Vtb,
    float* __restrict__ Y0, float* __restrict__ Yp, float* __restrict__ Dpart)
{
    __shared__ __align__(16) char smem[24576];
    char* KsB = smem;                 // 8 KB [s][d] bf16 swizzled
    char* VtB = smem + 8192;          // 8 KB [d][s] bf16 swizzled
    char* PsB = smem + 16384;         // 8 KB 4 waves x [16][64] bf16 swizzled

    const int wg = blockIdx.x;
    const int xcd = wg & 7;
    const int slot = wg >> 3;              // 0..159
    const int bh = (slot < 80) ? xcd : 8 + xcd;
    const int rem = (slot < 80) ? slot : slot - 80;
    const int rr = 79 - rem;               // big-bt chunks first
    int bt, sc;
    if (rr < 8)       { bt = rr; sc = 0; }
    else if (rr < 24) { const int q = rr - 8;  bt = 8 + (q >> 1);  sc = q & 1; }
    else if (rr < 48) { const int q = rr - 24; bt = 16 + q / 3;    sc = q % 3; }
    else              { const int q = rr - 48; bt = 24 + (q >> 2); sc = q & 3; }
    const int st0 = sc * SC_;
    const int st1 = min(st0 + SC_ - 1, bt);

    const int tid = threadIdx.x;
    const int wave = tid >> 6;
    const int lane = tid & 63;
    const int l15 = lane & 15;
    const int lhi = lane >> 4;
    const int b = bh >> 3, h = bh & 7;
    const int t0 = bt * 64;

    // Q fragments from prescaled bf16 (A-frag: row=l15, k=kk*32+lhi*8+j)
    const int qrow = t0 + wave * 16 + l15;
    const unsigned short* qpp = Qsb + ((size_t)bh * T_ + qrow) * 64 + lhi * 8;
    short8 qf[2];
    qf[0] = *(const short8*)(qpp);
    qf[1] = *(const short8*)(qpp + 32);

    f32x4 accY[4];
#pragma unroll
    for (int n = 0; n < 4; ++n) accY[n] = (f32x4){0.f, 0.f, 0.f, 0.f};
    float den[4] = {0.f, 0.f, 0.f, 0.f};

    const int kchunk = lhi * 16;
    const int rsw = (l15 & 7) << 4;
    const int srow = tid >> 2;
    const int c2 = (tid & 3) * 2;
    const int swr = (srow & 7) << 4;

    for (int st = st0; st <= st1; ++st) {
        __syncthreads();
        {
            const unsigned short* kp = Ksb + ((size_t)bh * T_ + st * 64 + srow) * 64 + c2 * 8;
            short8 k0 = *(const short8*)kp;
            short8 k1 = *(const short8*)(kp + 8);
            *(short8*)(KsB + srow * 128 + ((c2 * 16) ^ swr))      = k0;
            *(short8*)(KsB + srow * 128 + ((c2 * 16 + 16) ^ swr)) = k1;
            const unsigned short* vp = Vtb + ((size_t)bh * 64 + srow) * T_ + st * 64 + c2 * 8;
            short8 v0 = *(const short8*)vp;
            short8 v1 = *(const short8*)(vp + 8);
            *(short8*)(VtB + srow * 128 + ((c2 * 16) ^ swr))      = v0;
            *(short8*)(VtB + srow * 128 + ((c2 * 16 + 16) ^ swr)) = v1;
        }
        __syncthreads();

        f32x4 accS[4];
#pragma unroll
        for (int n = 0; n < 4; ++n) accS[n] = (f32x4){0.f, 0.f, 0.f, 0.f};
#pragma unroll
        for (int n = 0; n < 4; ++n) {
#pragma unroll
            for (int kk = 0; kk < 2; ++kk) {
                short8 bf = *(const short8*)(KsB + (n * 16 + l15) * 128 + ((kk * 64 + kchunk) ^ rsw));
                accS[n] = __builtin_amdgcn_mfma_f32_16x16x32_bf16(qf[kk], bf, accS[n], 0, 0, 0);
            }
        }

        const bool last = (st == bt);
        char* PsW = PsB + wave * 2048;
#pragma unroll
        for (int n = 0; n < 4; ++n) {
#pragma unroll
            for (int r = 0; r < 4; ++r) {
                const float a = accS[n][r];
                float p = a * a;
                if (last)
                    p = ((n * 16 + l15) <= wave * 16 + lhi * 4 + r) ? p : 0.f;
                den[r] += p;
                const int prow = lhi * 4 + r;
                *(unsigned short*)(PsW + prow * 128 + ((2 * (n * 16 + l15)) ^ ((prow & 7) << 4))) = f2b(p);
            }
        }

        short8 pa[2];
#pragma unroll
        for (int kk = 0; kk < 2; ++kk)
            pa[kk] = *(const short8*)(PsW + l15 * 128 + ((kk * 64 + kchunk) ^ rsw));
#pragma unroll
        for (int n = 0; n < 4; ++n) {
#pragma unroll
            for (int kk = 0; kk < 2; ++kk) {
                short8 vb = *(const short8*)(VtB + (n * 16 + l15) * 128 + ((kk * 64 + kchunk) ^ rsw));
                accY[n] = __builtin_amdgcn_mfma_f32_16x16x32_bf16(pa[kk], vb, accY[n], 0, 0, 0);
            }
        }
    }

#pragma unroll
    for (int r = 0; r < 4; ++r) {
        den[r] += __shfl_xor(den[r], 1, 64);
        den[r] += __shfl_xor(den[r], 2, 64);
        den[r] += __shfl_xor(den[r], 4, 64);
        den[r] += __shfl_xor(den[r], 8, 64);
    }

    float* Ybase = (sc == 0) ? Y0 : (Yp + (size_t)(sc - 1) * MC_);
    float* Dbase = Dpart + (size_t)sc * BHT_;
#pragma unroll
    for (int r = 0; r < 4; ++r) {
        const int t = t0 + wave * 16 + lhi * 4 + r;
        if (l15 == 0)
            Dbase[(size_t)bh * T_ + t] = den[r];
        float* yo = Ybase + (size_t)(b * T_ + t) * (H_ * D_) + h * 64 + l15;
#pragma unroll
        for (int n = 0; n < 4; ++n)
            yo[n * 16] = accY[n][r];
    }
}

// ---------------------------------------------------------------------------
// normalize: ybb = bf16( (sum of nsc Y slices) / max(sum of nsc den, 1e-6) )
// ---------------------------------------------------------------------------
__global__ __launch_bounds__(256) void normalize_kernel(
    const float* __restrict__ Y0, const float* __restrict__ Yp,
    const float* __restrict__ Dpart, unsigned short* __restrict__ ybb)
{
    const int gid = blockIdx.x * 256 + threadIdx.x;
    const size_t base = (size_t)gid * 8;
    const int row = (int)(base >> 9);
    const int col = (int)(base & 511);
    const int b = row >> 11, t = row & 2047, h = col >> 6;
    const int bh = b * H_ + h;
    const int nsc = ((t >> 6) >> 3) + 1;      // bt/8 + 1

    float d = Dpart[(size_t)bh * T_ + t];
    float4 f0 = *(const float4*)(Y0 + base);
    float4 f1 = *(const float4*)(Y0 + base + 4);
    for (int s = 1; s < nsc; ++s) {
        d += Dpart[(size_t)s * BHT_ + (size_t)bh * T_ + t];
        const float* yp = Yp + (size_t)(s - 1) * MC_ + base;
        float4 g0 = *(const float4*)(yp);
        float4 g1 = *(const float4*)(yp + 4);
        f0.x += g0.x; f0.y += g0.y; f0.z += g0.z; f0.w += g0.w;
        f1.x += g1.x; f1.y += g1.y; f1.z += g1.z; f1.w += g1.w;
    }
    const float inv = 1.0f / fmaxf(d, 1e-6f);
    f0.x *= inv; f0.y *= inv; f0.z *= inv; f0.w *= inv;
    f1.x *= inv; f1.y *= inv; f1.z *= inv; f1.w *= inv;
    *(short8*)(ybb + base) = pack8(f0, f1);
}

// ---------------------------------------------------------------------------
extern "C" void kernel_launch(void* const* d_in, const int* in_sizes, int n_in,
                              void* d_out, int out_size, void* d_ws, size_t ws_size,
                              hipStream_t stream)
{
    const float* x      = (const float*)d_in[0];
    const float* w_attn = (const float*)d_in[1];
    const float* w_proj = (const float*)d_in[2];
    float* out = (float*)d_out;

    // workspace (~66 MB of ~256 MB):
    // qkvg f32 | Lg | Dpart[4] | Vtb | Bt1 | Bt2 | A (xb->Ksb->ybb) | Yp[3] | Qsb
    float* qkvg = (float*)d_ws;
    float* Lg    = qkvg + (size_t)B_ * T_ * QKVG_;           // 6,322,176 f
    float* Dpart = Lg + BHT_;                                // 4*32768 f
    unsigned short* Vtb = (unsigned short*)(Dpart + 4 * BHT_);
    unsigned short* Bt1 = Vtb + (size_t)B_ * H_ * D_ * T_;   // +2,097,152 us
    unsigned short* Bt2 = Bt1 + (size_t)NPAD1_ * C_;         // +851,968 us
    unsigned short* xb  = Bt2 + (size_t)C_ * C_;             // +262,144 us
    unsigned short* Ksb = xb;   // alias: xb dead after gemm1
    unsigned short* ybb = xb;   // alias: Ksb dead after attn
    float* Yp = (float*)(xb + (size_t)MC_);                  // 3 * 8 MB slices
    unsigned short* Qsb = (unsigned short*)(Yp + 3 * (size_t)MC_);  // 4 MB

    const int M = B_ * T_;      // 4096

    // 0) merged packs: x->bf16, w_attn->Bt1, w_proj->Bt2
    pack_inputs<<<1296, 256, 0, stream>>>(x, w_attn, w_proj, xb, Bt1, Bt2);

    // 1) qkvg = x @ w_attn   (MFMA bf16)
    gemm_bf16<<<dim3(NPAD1_ / 128, M / 128), 256, 0, stream>>>(
        xb, Bt1, qkvg, M, QKVG_, C_);

    // 2) gate log-sigmoid + block-scan cumsum -> Lg
    gate_cumsum<<<B_ * H_, 256, 0, stream>>>(qkvg, Lg);

    // 3) fused RoPE + prescale + pack Q,K,V -> Qsb, Ksb, Vtb
    qkv_pack<<<dim3(T_ / 64, B_ * H_), 256, 0, stream>>>(qkvg, Lg, Qsb, Ksb, Vtb);

    // 4) split-s attention, non-atomic partial slices
    attn_mfma<<<NBLK_, 256, 0, stream>>>(Qsb, Ksb, Vtb, out, Yp, Dpart);

    // 4b) normalize + slice-sum -> ybb (bf16)
    normalize_kernel<<<(MC_ / 8) / 256, 256, 0, stream>>>(out, Yp, Dpart, ybb);

    // 5) out = ybb @ w_proj  (MFMA bf16; overwrites d_out)
    gemm_bf16<<<dim3(C_ / 128, M / 128), 256, 0, stream>>>(
        ybb, Bt2, out, M, C_, H_ * D_);
}

// Round 11
// 89.600 us; speedup vs baseline: 1.5031x; 1.0050x over previous
//
#include <hip/hip_runtime.h>
#include <math.h>

// Problem constants (fixed by setup_inputs)
constexpr int B_ = 2, T_ = 2048, C_ = 512, H_ = 8, D_ = 64;
constexpr int QKVG_ = 3 * H_ * D_ + H_;   // 1544
constexpr float GATE_BIAS_ = 6.906768f;
constexpr int NPAD1_ = 1664;              // 13 * 128 (gemm1 padded N)
constexpr int SC_ = 8;                    // s-tiles per attn chunk
constexpr int NBLK_ = 1280;               // total useful attn blocks (16 bh x 80)
constexpr int MC_ = 4096 * 512;           // M*C = 2,097,152
constexpr int BHT_ = B_ * H_ * T_;        // 32,768

typedef __attribute__((ext_vector_type(8))) short short8;
typedef __attribute__((ext_vector_type(4))) float f32x4;

__device__ __forceinline__ unsigned short f2b(float f) {
    unsigned int u = __float_as_uint(f);
    unsigned int r = (u + 0x7fffu + ((u >> 16) & 1u)) >> 16;   // RNE
    return (unsigned short)r;
}
__device__ __forceinline__ short8 pack8(float4 a, float4 b) {
    short8 r;
    r[0] = (short)f2b(a.x); r[1] = (short)f2b(a.y);
    r[2] = (short)f2b(a.z); r[3] = (short)f2b(a.w);
    r[4] = (short)f2b(b.x); r[5] = (short)f2b(b.y);
    r[6] = (short)f2b(b.z); r[7] = (short)f2b(b.w);
    return r;
}

// async global->LDS, 16 B/lane. LDS dest = wave-uniform base + lane*16.
__device__ __forceinline__ void gl2lds16(const unsigned short* g, void* lds_base) {
    __builtin_amdgcn_global_load_lds(
        (const __attribute__((address_space(1))) unsigned int*)g,
        (__attribute__((address_space(3))) unsigned int*)lds_base, 16, 0, 0);
}

// ---------------------------------------------------------------------------
// pack_inputs: cvt x->xb (PRE-SWIZZLED) + packT w_attn/w_proj (PRE-SWIZZLED)
// Pre-swizzle: original 16B-chunk c stored at position c^(row&7) within each
// aligned 8-chunk group. Staging loads position (lane&7) LINEARLY; LDS then
// holds chunk (lane&7)^(row&7) at position (lane&7) == swizzled layout.
// ---------------------------------------------------------------------------
__device__ __forceinline__ void packT_body(
    const float* __restrict__ W, unsigned short* __restrict__ Bt,
    int K, int N, int nt, int kt, int tid, float (*Ws)[65])
{
    {
        const int r = tid >> 2;
        const int c0 = (tid & 3) * 16;
#pragma unroll
        for (int j = 0; j < 16; ++j) {
            const int n = nt + c0 + j;
            Ws[r][c0 + j] = (n < N) ? W[(size_t)(kt + r) * N + n] : 0.f;
        }
    }
    __syncthreads();
    {
        const int d = tid >> 2;             // N-row within tile
        const int cc = tid & 3;             // chunk pair (2cc, 2cc+1)
        const int kc = cc * 16;
        short8 o0, o1;
#pragma unroll
        for (int j = 0; j < 8; ++j) o0[j] = (short)f2b(Ws[kc + j][d]);
#pragma unroll
        for (int j = 0; j < 8; ++j) o1[j] = (short)f2b(Ws[kc + 8 + j][d]);
        const int row = nt + d;
        unsigned short* op = Bt + (size_t)row * K + kt;
        *(short8*)(op + ((2 * cc) ^ (row & 7)) * 8)     = o0;
        *(short8*)(op + ((2 * cc + 1) ^ (row & 7)) * 8) = o1;
    }
}

__global__ __launch_bounds__(256) void pack_inputs(
    const float* __restrict__ x, const float* __restrict__ w_attn,
    const float* __restrict__ w_proj, unsigned short* __restrict__ xb,
    unsigned short* __restrict__ Bt1, unsigned short* __restrict__ Bt2)
{
    __shared__ float Ws[64][65];
    const int bid = blockIdx.x;
    const int tid = threadIdx.x;
    if (bid < 1024) {
        const int i = bid * 256 + tid;      // one 16B chunk (8 elems)
        float4 f0 = *(const float4*)(x + (size_t)i * 8);
        float4 f1 = *(const float4*)(x + (size_t)i * 8 + 4);
        const int row = i >> 6;             // K=512 -> 64 chunks/row
        const int ic = i & 63;
        const int swc = (ic & ~7) | ((ic & 7) ^ (row & 7));
        *(short8*)(xb + (size_t)row * 512 + swc * 8) = pack8(f0, f1);
    } else if (bid < 1232) {
        const int q = bid - 1024;
        packT_body(w_attn, Bt1, C_, QKVG_, (q % 26) * 64, (q / 26) * 64, tid, Ws);
    } else {
        const int q = bid - 1232;
        packT_body(w_proj, Bt2, H_ * D_, C_, (q & 7) * 64, (q >> 3) * 64, tid, Ws);
    }
}

// ---------------------------------------------------------------------------
// gemm_bf16: C[M,N] f32 = A[M,K]bf16 @ Bt[Npad,K]bf16^T
// A/Bt PRE-SWIZZLED; staging = global_load_lds dwordx4, LINEAR source offset
// (lane&7) -- the data is already permuted in memory (fix of R10 bug).
// ---------------------------------------------------------------------------
__global__ __launch_bounds__(256) void gemm_bf16(
    const unsigned short* __restrict__ A, const unsigned short* __restrict__ Bt,
    float* __restrict__ C, int M, int N, int K)
{
    __shared__ __align__(16) char AsB[128 * 128];
    __shared__ __align__(16) char BsB[128 * 128];

    const int tid = threadIdx.x;
    const int wave = tid >> 6, lane = tid & 63;
    const int l15 = lane & 15, lhi = lane >> 4;
    const int wr = wave >> 1, wc = wave & 1;
    const int bm = blockIdx.y * 128, bn = blockIdx.x * 128;

    f32x4 acc[4][4];
#pragma unroll
    for (int i = 0; i < 4; ++i)
#pragma unroll
        for (int j = 0; j < 4; ++j) acc[i][j] = (f32x4){0.f, 0.f, 0.f, 0.f};

    const unsigned short* Arow = A + (size_t)bm * K;
    const unsigned short* Brow = Bt + (size_t)bn * K;
    const int sw = (l15 & 7) << 4;

    const int srow = tid >> 3;              // staging row (+32 per p)
    const int schunk = tid & 7;             // linear chunk position

    for (int k0 = 0; k0 < K; k0 += 64) {
        __syncthreads();
#pragma unroll
        for (int p = 0; p < 4; ++p) {
            const int row = p * 32 + srow;
            const size_t goff = (size_t)row * K + k0 + schunk * 8;
            gl2lds16(Arow + goff, AsB + p * 4096 + wave * 1024);
            gl2lds16(Brow + goff, BsB + p * 4096 + wave * 1024);
        }
        __syncthreads();

        short8 af[4][2];
#pragma unroll
        for (int mi = 0; mi < 4; ++mi) {
            const int row = wr * 64 + mi * 16 + l15;
#pragma unroll
            for (int kk = 0; kk < 2; ++kk)
                af[mi][kk] = *(const short8*)(AsB + row * 128 + ((kk * 64 + lhi * 16) ^ sw));
        }
#pragma unroll
        for (int ni = 0; ni < 4; ++ni) {
            const int row = wc * 64 + ni * 16 + l15;
            short8 bf0 = *(const short8*)(BsB + row * 128 + ((lhi * 16) ^ sw));
            short8 bf1 = *(const short8*)(BsB + row * 128 + ((64 + lhi * 16) ^ sw));
#pragma unroll
            for (int mi = 0; mi < 4; ++mi) {
                acc[mi][ni] = __builtin_amdgcn_mfma_f32_16x16x32_bf16(af[mi][0], bf0, acc[mi][ni], 0, 0, 0);
                acc[mi][ni] = __builtin_amdgcn_mfma_f32_16x16x32_bf16(af[mi][1], bf1, acc[mi][ni], 0, 0, 0);
            }
        }
    }

#pragma unroll
    for (int mi = 0; mi < 4; ++mi) {
        const int gm = bm + wr * 64 + mi * 16 + lhi * 4;
#pragma unroll
        for (int r = 0; r < 4; ++r) {
            float* crow = C + (size_t)(gm + r) * N;
#pragma unroll
            for (int ni = 0; ni < 4; ++ni) {
                const int gn = bn + wc * 64 + ni * 16 + l15;
                if (gn < N) crow[gn] = acc[mi][ni][r];
            }
        }
    }
}

// ---------------------------------------------------------------------------
// gate_cumsum: one block per (b,h): log-sigmoid + block-wide inclusive scan
// ---------------------------------------------------------------------------
__global__ __launch_bounds__(256) void gate_cumsum(
    const float* __restrict__ qkvg, float* __restrict__ Lg)
{
    __shared__ float wsum[4];
    const int bh = blockIdx.x;
    const int b = bh >> 3, h = bh & 7;
    const int tid = threadIdx.x;
    const int lane = tid & 63, wv = tid >> 6;

    const float* gp = qkvg + (size_t)(b * T_ + tid * 8) * QKVG_ + 1536 + h;
    float v[8];
    float s = 0.f;
#pragma unroll
    for (int j = 0; j < 8; ++j) {
        const float z = gp[(size_t)j * QKVG_] + GATE_BIAS_;
        const float lg = (z > 0.f) ? -log1pf(expf(-z)) : (z - log1pf(expf(z)));
        s += lg;
        v[j] = s;
    }
    float ssum = s;
#pragma unroll
    for (int off = 1; off < 64; off <<= 1) {
        float n = __shfl_up(ssum, off, 64);
        if (lane >= off) ssum += n;
    }
    if (lane == 63) wsum[wv] = ssum;
    __syncthreads();
    float base = ssum - s;
#pragma unroll
    for (int w = 0; w < 3; ++w)
        base += (w < wv) ? wsum[w] : 0.f;

    float* op = Lg + (size_t)bh * T_ + tid * 8;
#pragma unroll
    for (int j = 0; j < 8; ++j) op[j] = v[j] + base;
}

// ---------------------------------------------------------------------------
// qkv_pack: fused RoPE + gate-prescale + bf16 pack.
//   Qsb linear; Ksb/Vtb PRE-SWIZZLED (chunk c -> c^(row&7) within 128B rows)
// ---------------------------------------------------------------------------
__global__ __launch_bounds__(256) void qkv_pack(
    const float* __restrict__ qkvg, const float* __restrict__ Lg,
    unsigned short* __restrict__ Qsb, unsigned short* __restrict__ Ksb,
    unsigned short* __restrict__ Vtb)
{
    __shared__ float Vs[64][68];
    const int tid = threadIdx.x;
    const int stile = blockIdx.x;
    const int bh = blockIdx.y;
    const int b = bh >> 3, h = bh & 7;
    const int r = tid >> 2, c = tid & 3;
    const int t = stile * 64 + r;

    float sn[8], cs[8];
#pragma unroll
    for (int j = 0; j < 8; ++j) {
        const int i = c * 8 + j;
        const float div = 6.2831853071795864f * exp2f((float)i * (-11.0f / 32.0f));
        const float ang = (float)t * div;
        sn[j] = sinf(ang);
        cs[j] = cosf(ang);
    }

    const float Lt = Lg[(size_t)bh * T_ + t];
    const float eQ = __expf(0.5f * Lt) * 0.125f;
    const float eK = __expf(-0.5f * Lt);
    const float* basep = qkvg + (size_t)(b * T_ + t) * QKVG_ + h * 64 + c * 16;

    // Q (linear)
    {
        float q[16];
        *(float4*)&q[0]  = *(const float4*)(basep + 0);
        *(float4*)&q[4]  = *(const float4*)(basep + 4);
        *(float4*)&q[8]  = *(const float4*)(basep + 8);
        *(float4*)&q[12] = *(const float4*)(basep + 12);
#pragma unroll
        for (int j = 0; j < 8; ++j) {
            const float x1 = q[2 * j], x2 = q[2 * j + 1];
            q[2 * j]     = (x1 * cs[j] - x2 * sn[j]) * eQ;
            q[2 * j + 1] = (x2 * cs[j] + x1 * sn[j]) * eQ;
        }
        unsigned short* op = Qsb + ((size_t)bh * T_ + t) * 64 + c * 16;
        *(short8*)(op + 0) = pack8(*(float4*)&q[0], *(float4*)&q[4]);
        *(short8*)(op + 8) = pack8(*(float4*)&q[8], *(float4*)&q[12]);
    }
    // K (pre-swizzled by t&7)
    {
        float k[16];
        *(float4*)&k[0]  = *(const float4*)(basep + 512);
        *(float4*)&k[4]  = *(const float4*)(basep + 516);
        *(float4*)&k[8]  = *(const float4*)(basep + 520);
        *(float4*)&k[12] = *(const float4*)(basep + 524);
#pragma unroll
        for (int j = 0; j < 8; ++j) {
            const float x1 = k[2 * j], x2 = k[2 * j + 1];
            k[2 * j]     = (x1 * cs[j] - x2 * sn[j]) * eK;
            k[2 * j + 1] = (x2 * cs[j] + x1 * sn[j]) * eK;
        }
        unsigned short* op = Ksb + ((size_t)bh * T_ + t) * 64;
        *(short8*)(op + ((2 * c) ^ (t & 7)) * 8)     = pack8(*(float4*)&k[0], *(float4*)&k[4]);
        *(short8*)(op + ((2 * c + 1) ^ (t & 7)) * 8) = pack8(*(float4*)&k[8], *(float4*)&k[12]);
    }
    // V (transpose via LDS; pre-swizzled by d&7)
    {
        *(float4*)&Vs[r][c * 16 + 0]  = *(const float4*)(basep + 1024);
        *(float4*)&Vs[r][c * 16 + 4]  = *(const float4*)(basep + 1028);
        *(float4*)&Vs[r][c * 16 + 8]  = *(const float4*)(basep + 1032);
        *(float4*)&Vs[r][c * 16 + 12] = *(const float4*)(basep + 1036);
    }
    __syncthreads();
    {
        const int d = tid >> 2, cc = tid & 3;
        short8 o0, o1;
#pragma unroll
        for (int j = 0; j < 8; ++j) o0[j] = (short)f2b(Vs[cc * 16 + j][d]);
#pragma unroll
        for (int j = 0; j < 8; ++j) o1[j] = (short)f2b(Vs[cc * 16 + 8 + j][d]);
        unsigned short* op = Vtb + ((size_t)bh * 64 + d) * T_ + stile * 64;
        *(short8*)(op + ((2 * cc) ^ (d & 7)) * 8)     = o0;
        *(short8*)(op + ((2 * cc + 1) ^ (d & 7)) * 8) = o1;
    }
}

// ---------------------------------------------------------------------------
// attn_mfma: scores p = (q'.k')^2; XCD-pinned compact grid; K/V staged via
// global_load_lds from pre-swizzled Ksb/Vtb, LINEAR source offset (fix).
// ---------------------------------------------------------------------------
__global__ __launch_bounds__(256) void attn_mfma(
    const unsigned short* __restrict__ Qsb, const unsigned short* __restrict__ Ksb,
    const unsigned short* __restrict__ Vtb,
    float* __restrict__ Y0, float* __restrict__ Yp, float* __restrict__ Dpart)
{
    __shared__ __align__(16) char smem[24576];
    char* KsB = smem;                 // 8 KB [s][d] bf16 swizzled
    char* VtB = smem + 8192;          // 8 KB [d][s] bf16 swizzled
    char* PsB = smem + 16384;         // 8 KB 4 waves x [16][64] bf16 swizzled

    const int wg = blockIdx.x;
    const int xcd = wg & 7;
    const int slot = wg >> 3;              // 0..159
    const int bh = (slot < 80) ? xcd : 8 + xcd;
    const int rem = (slot < 80) ? slot : slot - 80;
    const int rr = 79 - rem;               // big-bt chunks first
    int bt, sc;
    if (rr < 8)       { bt = rr; sc = 0; }
    else if (rr < 24) { const int q = rr - 8;  bt = 8 + (q >> 1);  sc = q & 1; }
    else if (rr < 48) { const int q = rr - 24; bt = 16 + q / 3;    sc = q % 3; }
    else              { const int q = rr - 48; bt = 24 + (q >> 2); sc = q & 3; }
    const int st0 = sc * SC_;
    const int st1 = min(st0 + SC_ - 1, bt);

    const int tid = threadIdx.x;
    const int wave = tid >> 6;
    const int lane = tid & 63;
    const int l15 = lane & 15;
    const int lhi = lane >> 4;
    const int b = bh >> 3, h = bh & 7;
    const int t0 = bt * 64;

    const int qrow = t0 + wave * 16 + l15;
    const unsigned short* qpp = Qsb + ((size_t)bh * T_ + qrow) * 64 + lhi * 8;
    short8 qf[2];
    qf[0] = *(const short8*)(qpp);
    qf[1] = *(const short8*)(qpp + 32);

    f32x4 accY[4];
#pragma unroll
    for (int n = 0; n < 4; ++n) accY[n] = (f32x4){0.f, 0.f, 0.f, 0.f};
    float den[4] = {0.f, 0.f, 0.f, 0.f};

    const int kchunk = lhi * 16;
    const int rsw = (l15 & 7) << 4;
    const int srow = tid >> 3;            // staging row (+32 per p)
    const int schunk = tid & 7;           // linear chunk position

    for (int st = st0; st <= st1; ++st) {
        __syncthreads();
#pragma unroll
        for (int p = 0; p < 2; ++p) {
            const int row = p * 32 + srow;
            gl2lds16(Ksb + ((size_t)bh * T_ + st * 64 + row) * 64 + schunk * 8,
                     KsB + p * 4096 + wave * 1024);
            gl2lds16(Vtb + ((size_t)bh * 64 + row) * T_ + st * 64 + schunk * 8,
                     VtB + p * 4096 + wave * 1024);
        }
        __syncthreads();

        f32x4 accS[4];
#pragma unroll
        for (int n = 0; n < 4; ++n) accS[n] = (f32x4){0.f, 0.f, 0.f, 0.f};
#pragma unroll
        for (int n = 0; n < 4; ++n) {
#pragma unroll
            for (int kk = 0; kk < 2; ++kk) {
                short8 bf = *(const short8*)(KsB + (n * 16 + l15) * 128 + ((kk * 64 + kchunk) ^ rsw));
                accS[n] = __builtin_amdgcn_mfma_f32_16x16x32_bf16(qf[kk], bf, accS[n], 0, 0, 0);
            }
        }

        const bool last = (st == bt);
        char* PsW = PsB + wave * 2048;
#pragma unroll
        for (int n = 0; n < 4; ++n) {
#pragma unroll
            for (int r = 0; r < 4; ++r) {
                const float a = accS[n][r];
                float p = a * a;
                if (last)
                    p = ((n * 16 + l15) <= wave * 16 + lhi * 4 + r) ? p : 0.f;
                den[r] += p;
                const int prow = lhi * 4 + r;
                *(unsigned short*)(PsW + prow * 128 + ((2 * (n * 16 + l15)) ^ ((prow & 7) << 4))) = f2b(p);
            }
        }

        short8 pa[2];
#pragma unroll
        for (int kk = 0; kk < 2; ++kk)
            pa[kk] = *(const short8*)(PsW + l15 * 128 + ((kk * 64 + kchunk) ^ rsw));
#pragma unroll
        for (int n = 0; n < 4; ++n) {
#pragma unroll
            for (int kk = 0; kk < 2; ++kk) {
                short8 vb = *(const short8*)(VtB + (n * 16 + l15) * 128 + ((kk * 64 + kchunk) ^ rsw));
                accY[n] = __builtin_amdgcn_mfma_f32_16x16x32_bf16(pa[kk], vb, accY[n], 0, 0, 0);
            }
        }
    }

#pragma unroll
    for (int r = 0; r < 4; ++r) {
        den[r] += __shfl_xor(den[r], 1, 64);
        den[r] += __shfl_xor(den[r], 2, 64);
        den[r] += __shfl_xor(den[r], 4, 64);
        den[r] += __shfl_xor(den[r], 8, 64);
    }

    float* Ybase = (sc == 0) ? Y0 : (Yp + (size_t)(sc - 1) * MC_);
    float* Dbase = Dpart + (size_t)sc * BHT_;
#pragma unroll
    for (int r = 0; r < 4; ++r) {
        const int t = t0 + wave * 16 + lhi * 4 + r;
        if (l15 == 0)
            Dbase[(size_t)bh * T_ + t] = den[r];
        float* yo = Ybase + (size_t)(b * T_ + t) * (H_ * D_) + h * 64 + l15;
#pragma unroll
        for (int n = 0; n < 4; ++n)
            yo[n * 16] = accY[n][r];
    }
}

// ---------------------------------------------------------------------------
// normalize: ybb = bf16( (sum of nsc Y slices) / max(sum of nsc den, 1e-6) )
// ybb written PRE-SWIZZLED (it is gemm2's staged A operand).
// ---------------------------------------------------------------------------
__global__ __launch_bounds__(256) void normalize_kernel(
    const float* __restrict__ Y0, const float* __restrict__ Yp,
    const float* __restrict__ Dpart, unsigned short* __restrict__ ybb)
{
    const int gid = blockIdx.x * 256 + threadIdx.x;
    const size_t base = (size_t)gid * 8;
    const int row = (int)(base >> 9);
    const int col = (int)(base & 511);
    const int b = row >> 11, t = row & 2047, h = col >> 6;
    const int bh = b * H_ + h;
    const int nsc = ((t >> 6) >> 3) + 1;      // bt/8 + 1

    float d = Dpart[(size_t)bh * T_ + t];
    float4 f0 = *(const float4*)(Y0 + base);
    float4 f1 = *(const float4*)(Y0 + base + 4);
    for (int s = 1; s < nsc; ++s) {
        d += Dpart[(size_t)s * BHT_ + (size_t)bh * T_ + t];
        const float* yp = Yp + (size_t)(s - 1) * MC_ + base;
        float4 g0 = *(const float4*)(yp);
        float4 g1 = *(const float4*)(yp + 4);
        f0.x += g0.x; f0.y += g0.y; f0.z += g0.z; f0.w += g0.w;
        f1.x += g1.x; f1.y += g1.y; f1.z += g1.z; f1.w += g1.w;
    }
    const float inv = 1.0f / fmaxf(d, 1e-6f);
    f0.x *= inv; f0.y *= inv; f0.z *= inv; f0.w *= inv;
    f1.x *= inv; f1.y *= inv; f1.z *= inv; f1.w *= inv;

    const int ic = col >> 3;                  // chunk in row (0..63)
    const int swc = (ic & ~7) | ((ic & 7) ^ (row & 7));
    *(short8*)(ybb + (size_t)row * 512 + swc * 8) = pack8(f0, f1);
}

// ---------------------------------------------------------------------------
extern "C" void kernel_launch(void* const* d_in, const int* in_sizes, int n_in,
                              void* d_out, int out_size, void* d_ws, size_t ws_size,
                              hipStream_t stream)
{
    const float* x      = (const float*)d_in[0];
    const float* w_attn = (const float*)d_in[1];
    const float* w_proj = (const float*)d_in[2];
    float* out = (float*)d_out;

    // workspace (~66 MB of ~256 MB):
    // qkvg f32 | Lg | Dpart[4] | Vtb | Bt1 | Bt2 | A (xb->Ksb->ybb) | Yp[3] | Qsb
    float* qkvg = (float*)d_ws;
    float* Lg    = qkvg + (size_t)B_ * T_ * QKVG_;           // 6,322,176 f
    float* Dpart = Lg + BHT_;                                // 4*32768 f
    unsigned short* Vtb = (unsigned short*)(Dpart + 4 * BHT_);
    unsigned short* Bt1 = Vtb + (size_t)B_ * H_ * D_ * T_;   // +2,097,152 us
    unsigned short* Bt2 = Bt1 + (size_t)NPAD1_ * C_;         // +851,968 us
    unsigned short* xb  = Bt2 + (size_t)C_ * C_;             // +262,144 us
    unsigned short* Ksb = xb;   // alias: xb dead after gemm1
    unsigned short* ybb = xb;   // alias: Ksb dead after attn
    float* Yp = (float*)(xb + (size_t)MC_);                  // 3 * 8 MB slices
    unsigned short* Qsb = (unsigned short*)(Yp + 3 * (size_t)MC_);  // 4 MB

    const int M = B_ * T_;      // 4096

    // 0) merged packs (pre-swizzled): x->xb, w_attn->Bt1, w_proj->Bt2
    pack_inputs<<<1296, 256, 0, stream>>>(x, w_attn, w_proj, xb, Bt1, Bt2);

    // 1) qkvg = x @ w_attn   (MFMA bf16, global_load_lds staging)
    gemm_bf16<<<dim3(NPAD1_ / 128, M / 128), 256, 0, stream>>>(
        xb, Bt1, qkvg, M, QKVG_, C_);

    // 2) gate log-sigmoid + block-scan cumsum -> Lg
    gate_cumsum<<<B_ * H_, 256, 0, stream>>>(qkvg, Lg);

    // 3) fused RoPE + prescale + pack Q,K,V -> Qsb, Ksb(swz), Vtb(swz)
    qkv_pack<<<dim3(T_ / 64, B_ * H_), 256, 0, stream>>>(qkvg, Lg, Qsb, Ksb, Vtb);

    // 4) split-s attention, non-atomic partial slices
    attn_mfma<<<NBLK_, 256, 0, stream>>>(Qsb, Ksb, Vtb, out, Yp, Dpart);

    // 4b) normalize + slice-sum -> ybb (bf16, pre-swizzled)
    normalize_kernel<<<(MC_ / 8) / 256, 256, 0, stream>>>(out, Yp, Dpart, ybb);

    // 5) out = ybb @ w_proj  (MFMA bf16; overwrites d_out)
    gemm_bf16<<<dim3(C_ / 128, M / 128), 256, 0, stream>>>(
        ybb, Bt2, out, M, C_, H_ * D_);
}

// Round 12
// 84.236 us; speedup vs baseline: 1.5988x; 1.0637x over previous
//
#include <hip/hip_runtime.h>
#include <math.h>

// Problem constants (fixed by setup_inputs)
constexpr int B_ = 2, T_ = 2048, C_ = 512, H_ = 8, D_ = 64;
constexpr int QKVG_ = 3 * H_ * D_ + H_;   // 1544 (w_attn row stride)
constexpr float GATE_BIAS_ = 6.906768f;
constexpr int N1_ = 1536;                 // gemm1 N (Q,K,V only; gate separate)
constexpr int SC_ = 8;                    // s-tiles per attn chunk
constexpr int NBLK_ = 1280;               // attn blocks (16 bh x 80)
constexpr int MC_ = 4096 * 512;           // 2,097,152
constexpr int BHT_ = B_ * H_ * T_;        // 32,768

typedef __attribute__((ext_vector_type(8))) short short8;
typedef __attribute__((ext_vector_type(4))) float f32x4;

__device__ __forceinline__ unsigned short f2b(float f) {
    unsigned int u = __float_as_uint(f);
    unsigned int r = (u + 0x7fffu + ((u >> 16) & 1u)) >> 16;   // RNE
    return (unsigned short)r;
}
__device__ __forceinline__ short8 pack8(float4 a, float4 b) {
    short8 r;
    r[0] = (short)f2b(a.x); r[1] = (short)f2b(a.y);
    r[2] = (short)f2b(a.z); r[3] = (short)f2b(a.w);
    r[4] = (short)f2b(b.x); r[5] = (short)f2b(b.y);
    r[6] = (short)f2b(b.z); r[7] = (short)f2b(b.w);
    return r;
}

// async global->LDS, 16 B/lane
__device__ __forceinline__ void gl2lds16(const unsigned short* g, void* lds_base) {
    __builtin_amdgcn_global_load_lds(
        (const __attribute__((address_space(1))) unsigned int*)g,
        (__attribute__((address_space(3))) unsigned int*)lds_base, 16, 0, 0);
}

// ---------------------------------------------------------------------------
// pack_inputs: [0,1024) x->xb (pre-swz) | [1024,1216) w_attn->Bt1 (24x8) |
// [1216,1280) w_proj->Bt2 (8x8) | [1280,1288) sincos table | [1288,1416) gate GEMV
// ---------------------------------------------------------------------------
__device__ __forceinline__ void packT_body(
    const float* __restrict__ W, unsigned short* __restrict__ Bt,
    int K, int N, int ldW, int nt, int kt, int tid, float (*Ws)[65])
{
    {
        const int r = tid >> 2;
        const int c0 = (tid & 3) * 16;
#pragma unroll
        for (int j = 0; j < 16; ++j) {
            const int n = nt + c0 + j;
            Ws[r][c0 + j] = (n < N) ? W[(size_t)(kt + r) * ldW + n] : 0.f;
        }
    }
    __syncthreads();
    {
        const int d = tid >> 2;
        const int cc = tid & 3;
        const int kc = cc * 16;
        short8 o0, o1;
#pragma unroll
        for (int j = 0; j < 8; ++j) o0[j] = (short)f2b(Ws[kc + j][d]);
#pragma unroll
        for (int j = 0; j < 8; ++j) o1[j] = (short)f2b(Ws[kc + 8 + j][d]);
        const int row = nt + d;
        unsigned short* op = Bt + (size_t)row * K + kt;
        *(short8*)(op + ((2 * cc) ^ (row & 7)) * 8)     = o0;
        *(short8*)(op + ((2 * cc + 1) ^ (row & 7)) * 8) = o1;
    }
}

__global__ __launch_bounds__(256) void pack_inputs(
    const float* __restrict__ x, const float* __restrict__ w_attn,
    const float* __restrict__ w_proj, unsigned short* __restrict__ xb,
    unsigned short* __restrict__ Bt1, unsigned short* __restrict__ Bt2,
    float2* __restrict__ sincos, float* __restrict__ g)
{
    __shared__ float SM[64 * 65];
    float (*Ws)[65] = (float(*)[65])SM;
    const int bid = blockIdx.x;
    const int tid = threadIdx.x;
    if (bid < 1024) {
        const int i = bid * 256 + tid;
        float4 f0 = *(const float4*)(x + (size_t)i * 8);
        float4 f1 = *(const float4*)(x + (size_t)i * 8 + 4);
        const int row = i >> 6;
        const int ic = i & 63;
        const int swc = (ic & ~7) | ((ic & 7) ^ (row & 7));
        *(short8*)(xb + (size_t)row * 512 + swc * 8) = pack8(f0, f1);
    } else if (bid < 1216) {
        const int q = bid - 1024;
        packT_body(w_attn, Bt1, C_, N1_, QKVG_, (q % 24) * 64, (q / 24) * 64, tid, Ws);
    } else if (bid < 1280) {
        const int q = bid - 1216;
        packT_body(w_proj, Bt2, H_ * D_, C_, C_, (q & 7) * 64, (q >> 3) * 64, tid, Ws);
    } else if (bid < 1288) {
        const int t = (bid - 1280) * 256 + tid;
        float2* op = sincos + (size_t)t * 32;
#pragma unroll
        for (int i = 0; i < 32; ++i) {
            const float div = 6.2831853071795864f * exp2f((float)i * (-11.0f / 32.0f));
            const float ang = (float)t * div;
            op[i] = make_float2(cosf(ang), sinf(ang));
        }
    } else {
        // gate GEMV: g[bh][t] = x[m] . w_attn[:,1536+h]
        const int q = bid - 1288;
        float* LDSw = SM;                      // [512][8]
        {
            const int k = tid * 2;
#pragma unroll
            for (int kk = 0; kk < 2; ++kk) {
                const float* wp = w_attn + (size_t)(k + kk) * QKVG_ + 1536;
                float4 wa = *(const float4*)wp;
                float4 wb = *(const float4*)(wp + 4);
                float* dst = LDSw + (k + kk) * 8;
                *(float4*)dst = wa;
                *(float4*)(dst + 4) = wb;
            }
        }
        __syncthreads();
        const int m = q * 32 + (tid >> 3);
        const int h = tid & 7;
        const float* xrow = x + (size_t)m * C_;
        float s = 0.f;
#pragma unroll 4
        for (int k0 = 0; k0 < 512; k0 += 4) {
            float4 xv = *(const float4*)(xrow + k0);
            s += xv.x * LDSw[(k0 + 0) * 8 + h] + xv.y * LDSw[(k0 + 1) * 8 + h]
               + xv.z * LDSw[(k0 + 2) * 8 + h] + xv.w * LDSw[(k0 + 3) * 8 + h];
        }
        const int b = m >> 11, t = m & 2047;
        g[(size_t)(b * 8 + h) * T_ + t] = s;
    }
}

// ---------------------------------------------------------------------------
// gate_cumsum: one block per (b,h): log-sigmoid(g+bias) + block inclusive scan
// ---------------------------------------------------------------------------
__global__ __launch_bounds__(256) void gate_cumsum(
    const float* __restrict__ g, float* __restrict__ Lg)
{
    __shared__ float wsum[4];
    const int bh = blockIdx.x;
    const int tid = threadIdx.x;
    const int lane = tid & 63, wv = tid >> 6;

    const float* gp = g + (size_t)bh * T_ + tid * 8;
    float v[8];
    float s = 0.f;
#pragma unroll
    for (int j = 0; j < 8; ++j) {
        const float z = gp[j] + GATE_BIAS_;
        const float lg = (z > 0.f) ? -log1pf(expf(-z)) : (z - log1pf(expf(z)));
        s += lg;
        v[j] = s;
    }
    float ssum = s;
#pragma unroll
    for (int off = 1; off < 64; off <<= 1) {
        float n = __shfl_up(ssum, off, 64);
        if (lane >= off) ssum += n;
    }
    if (lane == 63) wsum[wv] = ssum;
    __syncthreads();
    float base = ssum - s;
#pragma unroll
    for (int w = 0; w < 3; ++w)
        base += (w < wv) ? wsum[w] : 0.f;

    float* op = Lg + (size_t)bh * T_ + tid * 8;
#pragma unroll
    for (int j = 0; j < 8; ++j) op[j] = v[j] + base;
}

// ---------------------------------------------------------------------------
// gemm_fused: qkv = xb @ Bt1^T (MFMA, N=1536) with fused epilogue:
//   Q cols -> Qsb (RoPE * e^{+L/2}/8, linear bf16)
//   K cols -> Ksb (RoPE * e^{-L/2}, pre-swizzled bf16)
//   V cols -> Vtb (transposed [bh][d][t], pre-swizzled bf16)
// Epilogue stages fp32 half-tiles (128x64) in LDS ([128][65] padded).
// ---------------------------------------------------------------------------
__global__ __launch_bounds__(256) void gemm_fused(
    const unsigned short* __restrict__ A, const unsigned short* __restrict__ Bt,
    const float* __restrict__ Lg, const float2* __restrict__ sincos,
    unsigned short* __restrict__ Qsb, unsigned short* __restrict__ Ksb,
    unsigned short* __restrict__ Vtb)
{
    __shared__ __align__(16) char smem[33280];   // staging 32KB | epi [128][65] f32
    char* AsB = smem;
    char* BsB = smem + 16384;
    float (*epi)[65] = (float(*)[65])smem;

    const int tid = threadIdx.x;
    const int wave = tid >> 6, lane = tid & 63;
    const int l15 = lane & 15, lhi = lane >> 4;
    const int wr = wave >> 1, wc = wave & 1;
    const int bm = blockIdx.y * 128, bn = blockIdx.x * 128;

    f32x4 acc[4][4];
#pragma unroll
    for (int i = 0; i < 4; ++i)
#pragma unroll
        for (int j = 0; j < 4; ++j) acc[i][j] = (f32x4){0.f, 0.f, 0.f, 0.f};

    const unsigned short* Arow = A + (size_t)bm * C_;
    const unsigned short* Brow = Bt + (size_t)bn * C_;
    const int sw = (l15 & 7) << 4;
    const int srow = tid >> 3;
    const int schunk = tid & 7;

    for (int k0 = 0; k0 < C_; k0 += 64) {
        __syncthreads();
#pragma unroll
        for (int p = 0; p < 4; ++p) {
            const int row = p * 32 + srow;
            const size_t goff = (size_t)row * C_ + k0 + schunk * 8;
            gl2lds16(Arow + goff, AsB + p * 4096 + wave * 1024);
            gl2lds16(Brow + goff, BsB + p * 4096 + wave * 1024);
        }
        __syncthreads();

        short8 af[4][2];
#pragma unroll
        for (int mi = 0; mi < 4; ++mi) {
            const int row = wr * 64 + mi * 16 + l15;
#pragma unroll
            for (int kk = 0; kk < 2; ++kk)
                af[mi][kk] = *(const short8*)(AsB + row * 128 + ((kk * 64 + lhi * 16) ^ sw));
        }
#pragma unroll
        for (int ni = 0; ni < 4; ++ni) {
            const int row = wc * 64 + ni * 16 + l15;
            short8 bf0 = *(const short8*)(BsB + row * 128 + ((lhi * 16) ^ sw));
            short8 bf1 = *(const short8*)(BsB + row * 128 + ((64 + lhi * 16) ^ sw));
#pragma unroll
            for (int mi = 0; mi < 4; ++mi) {
                acc[mi][ni] = __builtin_amdgcn_mfma_f32_16x16x32_bf16(af[mi][0], bf0, acc[mi][ni], 0, 0, 0);
                acc[mi][ni] = __builtin_amdgcn_mfma_f32_16x16x32_bf16(af[mi][1], bf1, acc[mi][ni], 0, 0, 0);
            }
        }
    }

    // -------- fused epilogue --------
    const int rid = bn >> 9;              // 0 Q, 1 K, 2 V
    const int b = bm >> 11;
    const int tloc0 = bm & 2047;

#pragma unroll
    for (int hc = 0; hc < 2; ++hc) {
        __syncthreads();
        if (wc == hc) {
#pragma unroll
            for (int mi = 0; mi < 4; ++mi)
#pragma unroll
                for (int ni = 0; ni < 4; ++ni)
#pragma unroll
                    for (int r = 0; r < 4; ++r)
                        epi[wr * 64 + mi * 16 + lhi * 4 + r][ni * 16 + l15] = acc[mi][ni][r];
        }
        __syncthreads();
        const int h = ((bn & 511) >> 6) + hc;
        const int bh = b * 8 + h;
        if (rid < 2) {
            // Q/K: thread = (row, 32-col half)
            const int row = tid >> 1;
            const int c0 = (tid & 1) * 32;
            const int t = tloc0 + row;
            const float Lt = Lg[(size_t)bh * T_ + t];
            const float scl = (rid == 0) ? (__expf(0.5f * Lt) * 0.125f)
                                         : __expf(-0.5f * Lt);
            float vb[32];
#pragma unroll
            for (int j = 0; j < 32; ++j) vb[j] = epi[row][c0 + j];
            const float2* sct = sincos + (size_t)t * 32 + (c0 >> 1);
#pragma unroll
            for (int p = 0; p < 16; ++p) {
                const float2 cssn = sct[p];
                const float x1 = vb[2 * p], x2 = vb[2 * p + 1];
                vb[2 * p]     = (x1 * cssn.x - x2 * cssn.y) * scl;
                vb[2 * p + 1] = (x2 * cssn.x + x1 * cssn.y) * scl;
            }
            unsigned short* op = ((rid == 0) ? Qsb : Ksb) + ((size_t)bh * T_ + t) * 64;
#pragma unroll
            for (int j = 0; j < 4; ++j) {
                short8 o = pack8(*(float4*)&vb[j * 8], *(float4*)&vb[j * 8 + 4]);
                const int chunk = (c0 >> 3) + j;
                const int pos = (rid == 0) ? chunk : (chunk ^ (t & 7));
                *(short8*)(op + pos * 8) = o;
            }
        } else {
            // V: thread = (d, 32-t group); transpose from epi columns
            const int d = tid >> 2;
            const int tq = tid & 3;
            unsigned short* op = Vtb + ((size_t)(bh * 64 + d)) * T_;
#pragma unroll
            for (int j = 0; j < 4; ++j) {
                const int tl = tq * 32 + j * 8;
                short8 o;
#pragma unroll
                for (int e = 0; e < 8; ++e)
                    o[e] = (short)f2b(epi[tl + e][d]);
                const int chunkidx = (tloc0 + tl) >> 3;
                const int pos = (chunkidx & ~7) | ((chunkidx & 7) ^ (d & 7));
                *(short8*)(op + pos * 8) = o;
            }
        }
    }
}

// ---------------------------------------------------------------------------
// gemm_bf16 (generic, for gemm2): C = A @ Bt^T, pre-swizzled operands
// ---------------------------------------------------------------------------
__global__ __launch_bounds__(256) void gemm_bf16(
    const unsigned short* __restrict__ A, const unsigned short* __restrict__ Bt,
    float* __restrict__ C, int M, int N, int K)
{
    __shared__ __align__(16) char AsB[128 * 128];
    __shared__ __align__(16) char BsB[128 * 128];

    const int tid = threadIdx.x;
    const int wave = tid >> 6, lane = tid & 63;
    const int l15 = lane & 15, lhi = lane >> 4;
    const int wr = wave >> 1, wc = wave & 1;
    const int bm = blockIdx.y * 128, bn = blockIdx.x * 128;

    f32x4 acc[4][4];
#pragma unroll
    for (int i = 0; i < 4; ++i)
#pragma unroll
        for (int j = 0; j < 4; ++j) acc[i][j] = (f32x4){0.f, 0.f, 0.f, 0.f};

    const unsigned short* Arow = A + (size_t)bm * K;
    const unsigned short* Brow = Bt + (size_t)bn * K;
    const int sw = (l15 & 7) << 4;
    const int srow = tid >> 3;
    const int schunk = tid & 7;

    for (int k0 = 0; k0 < K; k0 += 64) {
        __syncthreads();
#pragma unroll
        for (int p = 0; p < 4; ++p) {
            const int row = p * 32 + srow;
            const size_t goff = (size_t)row * K + k0 + schunk * 8;
            gl2lds16(Arow + goff, AsB + p * 4096 + wave * 1024);
            gl2lds16(Brow + goff, BsB + p * 4096 + wave * 1024);
        }
        __syncthreads();

        short8 af[4][2];
#pragma unroll
        for (int mi = 0; mi < 4; ++mi) {
            const int row = wr * 64 + mi * 16 + l15;
#pragma unroll
            for (int kk = 0; kk < 2; ++kk)
                af[mi][kk] = *(const short8*)(AsB + row * 128 + ((kk * 64 + lhi * 16) ^ sw));
        }
#pragma unroll
        for (int ni = 0; ni < 4; ++ni) {
            const int row = wc * 64 + ni * 16 + l15;
            short8 bf0 = *(const short8*)(BsB + row * 128 + ((lhi * 16) ^ sw));
            short8 bf1 = *(const short8*)(BsB + row * 128 + ((64 + lhi * 16) ^ sw));
#pragma unroll
            for (int mi = 0; mi < 4; ++mi) {
                acc[mi][ni] = __builtin_amdgcn_mfma_f32_16x16x32_bf16(af[mi][0], bf0, acc[mi][ni], 0, 0, 0);
                acc[mi][ni] = __builtin_amdgcn_mfma_f32_16x16x32_bf16(af[mi][1], bf1, acc[mi][ni], 0, 0, 0);
            }
        }
    }

#pragma unroll
    for (int mi = 0; mi < 4; ++mi) {
        const int gm = bm + wr * 64 + mi * 16 + lhi * 4;
#pragma unroll
        for (int r = 0; r < 4; ++r) {
            float* crow = C + (size_t)(gm + r) * N;
#pragma unroll
            for (int ni = 0; ni < 4; ++ni) {
                const int gn = bn + wc * 64 + ni * 16 + l15;
                if (gn < N) crow[gn] = acc[mi][ni][r];
            }
        }
    }
}

// ---------------------------------------------------------------------------
// attn_mfma: scores p = (q'.k')^2; XCD-pinned grid; gl2lds staging (linear src)
// ---------------------------------------------------------------------------
__global__ __launch_bounds__(256) void attn_mfma(
    const unsigned short* __restrict__ Qsb, const unsigned short* __restrict__ Ksb,
    const unsigned short* __restrict__ Vtb,
    float* __restrict__ Y0, float* __restrict__ Yp, float* __restrict__ Dpart)
{
    __shared__ __align__(16) char smem[24576];
    char* KsB = smem;
    char* VtB = smem + 8192;
    char* PsB = smem + 16384;

    const int wg = blockIdx.x;
    const int xcd = wg & 7;
    const int slot = wg >> 3;
    const int bh = (slot < 80) ? xcd : 8 + xcd;
    const int rem = (slot < 80) ? slot : slot - 80;
    const int rr = 79 - rem;
    int bt, sc;
    if (rr < 8)       { bt = rr; sc = 0; }
    else if (rr < 24) { const int q = rr - 8;  bt = 8 + (q >> 1);  sc = q & 1; }
    else if (rr < 48) { const int q = rr - 24; bt = 16 + q / 3;    sc = q % 3; }
    else              { const int q = rr - 48; bt = 24 + (q >> 2); sc = q & 3; }
    const int st0 = sc * SC_;
    const int st1 = min(st0 + SC_ - 1, bt);

    const int tid = threadIdx.x;
    const int wave = tid >> 6;
    const int lane = tid & 63;
    const int l15 = lane & 15;
    const int lhi = lane >> 4;
    const int b = bh >> 3, h = bh & 7;
    const int t0 = bt * 64;

    const int qrow = t0 + wave * 16 + l15;
    const unsigned short* qpp = Qsb + ((size_t)bh * T_ + qrow) * 64 + lhi * 8;
    short8 qf[2];
    qf[0] = *(const short8*)(qpp);
    qf[1] = *(const short8*)(qpp + 32);

    f32x4 accY[4];
#pragma unroll
    for (int n = 0; n < 4; ++n) accY[n] = (f32x4){0.f, 0.f, 0.f, 0.f};
    float den[4] = {0.f, 0.f, 0.f, 0.f};

    const int kchunk = lhi * 16;
    const int rsw = (l15 & 7) << 4;
    const int srow = tid >> 3;
    const int schunk = tid & 7;

    for (int st = st0; st <= st1; ++st) {
        __syncthreads();
#pragma unroll
        for (int p = 0; p < 2; ++p) {
            const int row = p * 32 + srow;
            gl2lds16(Ksb + ((size_t)bh * T_ + st * 64 + row) * 64 + schunk * 8,
                     KsB + p * 4096 + wave * 1024);
            gl2lds16(Vtb + ((size_t)bh * 64 + row) * T_ + st * 64 + schunk * 8,
                     VtB + p * 4096 + wave * 1024);
        }
        __syncthreads();

        f32x4 accS[4];
#pragma unroll
        for (int n = 0; n < 4; ++n) accS[n] = (f32x4){0.f, 0.f, 0.f, 0.f};
#pragma unroll
        for (int n = 0; n < 4; ++n) {
#pragma unroll
            for (int kk = 0; kk < 2; ++kk) {
                short8 bf = *(const short8*)(KsB + (n * 16 + l15) * 128 + ((kk * 64 + kchunk) ^ rsw));
                accS[n] = __builtin_amdgcn_mfma_f32_16x16x32_bf16(qf[kk], bf, accS[n], 0, 0, 0);
            }
        }

        const bool last = (st == bt);
        char* PsW = PsB + wave * 2048;
#pragma unroll
        for (int n = 0; n < 4; ++n) {
#pragma unroll
            for (int r = 0; r < 4; ++r) {
                const float a = accS[n][r];
                float p = a * a;
                if (last)
                    p = ((n * 16 + l15) <= wave * 16 + lhi * 4 + r) ? p : 0.f;
                den[r] += p;
                const int prow = lhi * 4 + r;
                *(unsigned short*)(PsW + prow * 128 + ((2 * (n * 16 + l15)) ^ ((prow & 7) << 4))) = f2b(p);
            }
        }

        short8 pa[2];
#pragma unroll
        for (int kk = 0; kk < 2; ++kk)
            pa[kk] = *(const short8*)(PsW + l15 * 128 + ((kk * 64 + kchunk) ^ rsw));
#pragma unroll
        for (int n = 0; n < 4; ++n) {
#pragma unroll
            for (int kk = 0; kk < 2; ++kk) {
                short8 vb = *(const short8*)(VtB + (n * 16 + l15) * 128 + ((kk * 64 + kchunk) ^ rsw));
                accY[n] = __builtin_amdgcn_mfma_f32_16x16x32_bf16(pa[kk], vb, accY[n], 0, 0, 0);
            }
        }
    }

#pragma unroll
    for (int r = 0; r < 4; ++r) {
        den[r] += __shfl_xor(den[r], 1, 64);
        den[r] += __shfl_xor(den[r], 2, 64);
        den[r] += __shfl_xor(den[r], 4, 64);
        den[r] += __shfl_xor(den[r], 8, 64);
    }

    float* Ybase = (sc == 0) ? Y0 : (Yp + (size_t)(sc - 1) * MC_);
    float* Dbase = Dpart + (size_t)sc * BHT_;
#pragma unroll
    for (int r = 0; r < 4; ++r) {
        const int t = t0 + wave * 16 + lhi * 4 + r;
        if (l15 == 0)
            Dbase[(size_t)bh * T_ + t] = den[r];
        float* yo = Ybase + (size_t)(b * T_ + t) * (H_ * D_) + h * 64 + l15;
#pragma unroll
        for (int n = 0; n < 4; ++n)
            yo[n * 16] = accY[n][r];
    }
}

// ---------------------------------------------------------------------------
// normalize: ybb = bf16((sum Y slices) / max(sum den, 1e-6)), PRE-SWIZZLED
// ---------------------------------------------------------------------------
__global__ __launch_bounds__(256) void normalize_kernel(
    const float* __restrict__ Y0, const float* __restrict__ Yp,
    const float* __restrict__ Dpart, unsigned short* __restrict__ ybb)
{
    const int gid = blockIdx.x * 256 + threadIdx.x;
    const size_t base = (size_t)gid * 8;
    const int row = (int)(base >> 9);
    const int col = (int)(base & 511);
    const int b = row >> 11, t = row & 2047, h = col >> 6;
    const int bh = b * H_ + h;
    const int nsc = ((t >> 6) >> 3) + 1;

    float d = Dpart[(size_t)bh * T_ + t];
    float4 f0 = *(const float4*)(Y0 + base);
    float4 f1 = *(const float4*)(Y0 + base + 4);
    for (int s = 1; s < nsc; ++s) {
        d += Dpart[(size_t)s * BHT_ + (size_t)bh * T_ + t];
        const float* yp = Yp + (size_t)(s - 1) * MC_ + base;
        float4 g0 = *(const float4*)(yp);
        float4 g1 = *(const float4*)(yp + 4);
        f0.x += g0.x; f0.y += g0.y; f0.z += g0.z; f0.w += g0.w;
        f1.x += g1.x; f1.y += g1.y; f1.z += g1.z; f1.w += g1.w;
    }
    const float inv = 1.0f / fmaxf(d, 1e-6f);
    f0.x *= inv; f0.y *= inv; f0.z *= inv; f0.w *= inv;
    f1.x *= inv; f1.y *= inv; f1.z *= inv; f1.w *= inv;

    const int ic = col >> 3;
    const int swc = (ic & ~7) | ((ic & 7) ^ (row & 7));
    *(short8*)(ybb + (size_t)row * 512 + swc * 8) = pack8(f0, f1);
}

// ---------------------------------------------------------------------------
extern "C" void kernel_launch(void* const* d_in, const int* in_sizes, int n_in,
                              void* d_out, int out_size, void* d_ws, size_t ws_size,
                              hipStream_t stream)
{
    const float* x      = (const float*)d_in[0];
    const float* w_attn = (const float*)d_in[1];
    const float* w_proj = (const float*)d_in[2];
    float* out = (float*)d_out;

    // workspace (~47 MB of ~256 MB), no aliasing:
    char* p = (char*)d_ws;
    float2* sincos = (float2*)p;               p += (size_t)T_ * 32 * 8;       // 512 KB
    float* g       = (float*)p;                p += (size_t)BHT_ * 4;          // 128 KB
    float* Lg      = (float*)p;                p += (size_t)BHT_ * 4;          // 128 KB
    float* Dpart   = (float*)p;                p += (size_t)4 * BHT_ * 4;      // 512 KB
    unsigned short* xb  = (unsigned short*)p;  p += (size_t)MC_ * 2;           // 4 MB
    unsigned short* Bt1 = (unsigned short*)p;  p += (size_t)N1_ * C_ * 2;      // 1.5 MB
    unsigned short* Bt2 = (unsigned short*)p;  p += (size_t)C_ * C_ * 2;       // 0.5 MB
    unsigned short* Qsb = (unsigned short*)p;  p += (size_t)BHT_ * 64 * 2;     // 4 MB
    unsigned short* Ksb = (unsigned short*)p;  p += (size_t)BHT_ * 64 * 2;     // 4 MB
    unsigned short* Vtb = (unsigned short*)p;  p += (size_t)BHT_ * 64 * 2;     // 4 MB
    float* Yp      = (float*)p;                p += (size_t)3 * MC_ * 4;       // 24 MB
    unsigned short* ybb = (unsigned short*)p;                                  // 4 MB

    const int M = B_ * T_;      // 4096

    // 0) packs + sincos table + gate GEMV
    pack_inputs<<<1416, 256, 0, stream>>>(x, w_attn, w_proj, xb, Bt1, Bt2, sincos, g);

    // 1) gate log-sigmoid + cumsum -> Lg
    gate_cumsum<<<B_ * H_, 256, 0, stream>>>(g, Lg);

    // 2) fused qkv GEMM + RoPE/prescale/transpose epilogue -> Qsb, Ksb, Vtb
    gemm_fused<<<dim3(N1_ / 128, M / 128), 256, 0, stream>>>(
        xb, Bt1, Lg, sincos, Qsb, Ksb, Vtb);

    // 3) split-s attention, non-atomic partial slices
    attn_mfma<<<NBLK_, 256, 0, stream>>>(Qsb, Ksb, Vtb, out, Yp, Dpart);

    // 4) normalize + slice-sum -> ybb (bf16, pre-swizzled)
    normalize_kernel<<<(MC_ / 8) / 256, 256, 0, stream>>>(out, Yp, Dpart, ybb);

    // 5) out = ybb @ w_proj
    gemm_bf16<<<dim3(C_ / 128, M / 128), 256, 0, stream>>>(
        ybb, Bt2, out, M, C_, H_ * D_);
}

// Round 13
// 79.807 us; speedup vs baseline: 1.6875x; 1.0555x over previous
//
#include <hip/hip_runtime.h>
#include <math.h>

// Problem constants (fixed by setup_inputs)
constexpr int B_ = 2, T_ = 2048, C_ = 512, H_ = 8, D_ = 64;
constexpr int QKVG_ = 3 * H_ * D_ + H_;   // 1544 (w_attn row stride)
constexpr float GATE_BIAS_ = 6.906768f;
constexpr int N1_ = 1536;                 // gemm1 N (Q,K,V only; gate separate)
constexpr int SC_ = 8;                    // s-tiles per attn chunk
constexpr int NBLK_ = 1280;               // attn blocks (16 bh x 80)
constexpr int MC_ = 4096 * 512;           // 2,097,152
constexpr int BHT_ = B_ * H_ * T_;        // 32,768

typedef __attribute__((ext_vector_type(8))) short short8;
typedef __attribute__((ext_vector_type(4))) float f32x4;

__device__ __forceinline__ unsigned short f2b(float f) {
    unsigned int u = __float_as_uint(f);
    unsigned int r = (u + 0x7fffu + ((u >> 16) & 1u)) >> 16;   // RNE
    return (unsigned short)r;
}
__device__ __forceinline__ short8 pack8(float4 a, float4 b) {
    short8 r;
    r[0] = (short)f2b(a.x); r[1] = (short)f2b(a.y);
    r[2] = (short)f2b(a.z); r[3] = (short)f2b(a.w);
    r[4] = (short)f2b(b.x); r[5] = (short)f2b(b.y);
    r[6] = (short)f2b(b.z); r[7] = (short)f2b(b.w);
    return r;
}

// async global->LDS, 16 B/lane
__device__ __forceinline__ void gl2lds16(const unsigned short* g, void* lds_base) {
    __builtin_amdgcn_global_load_lds(
        (const __attribute__((address_space(1))) unsigned int*)g,
        (__attribute__((address_space(3))) unsigned int*)lds_base, 16, 0, 0);
}

// ---------------------------------------------------------------------------
// pack_inputs: [0,1024) x->xb (pre-swz) | [1024,1216) w_attn->Bt1 (24x8) |
// [1216,1280) w_proj->Bt2 (8x8) | [1280,1288) sincos table | [1288,1416) gate GEMV
// ---------------------------------------------------------------------------
__device__ __forceinline__ void packT_body(
    const float* __restrict__ W, unsigned short* __restrict__ Bt,
    int K, int N, int ldW, int nt, int kt, int tid, float (*Ws)[65])
{
    {
        const int r = tid >> 2;
        const int c0 = (tid & 3) * 16;
#pragma unroll
        for (int j = 0; j < 16; ++j) {
            const int n = nt + c0 + j;
            Ws[r][c0 + j] = (n < N) ? W[(size_t)(kt + r) * ldW + n] : 0.f;
        }
    }
    __syncthreads();
    {
        const int d = tid >> 2;
        const int cc = tid & 3;
        const int kc = cc * 16;
        short8 o0, o1;
#pragma unroll
        for (int j = 0; j < 8; ++j) o0[j] = (short)f2b(Ws[kc + j][d]);
#pragma unroll
        for (int j = 0; j < 8; ++j) o1[j] = (short)f2b(Ws[kc + 8 + j][d]);
        const int row = nt + d;
        unsigned short* op = Bt + (size_t)row * K + kt;
        *(short8*)(op + ((2 * cc) ^ (row & 7)) * 8)     = o0;
        *(short8*)(op + ((2 * cc + 1) ^ (row & 7)) * 8) = o1;
    }
}

__global__ __launch_bounds__(256) void pack_inputs(
    const float* __restrict__ x, const float* __restrict__ w_attn,
    const float* __restrict__ w_proj, unsigned short* __restrict__ xb,
    unsigned short* __restrict__ Bt1, unsigned short* __restrict__ Bt2,
    float2* __restrict__ sincos, float* __restrict__ g)
{
    __shared__ float SM[64 * 65];
    float (*Ws)[65] = (float(*)[65])SM;
    const int bid = blockIdx.x;
    const int tid = threadIdx.x;
    if (bid < 1024) {
        const int i = bid * 256 + tid;
        float4 f0 = *(const float4*)(x + (size_t)i * 8);
        float4 f1 = *(const float4*)(x + (size_t)i * 8 + 4);
        const int row = i >> 6;
        const int ic = i & 63;
        const int swc = (ic & ~7) | ((ic & 7) ^ (row & 7));
        *(short8*)(xb + (size_t)row * 512 + swc * 8) = pack8(f0, f1);
    } else if (bid < 1216) {
        const int q = bid - 1024;
        packT_body(w_attn, Bt1, C_, N1_, QKVG_, (q % 24) * 64, (q / 24) * 64, tid, Ws);
    } else if (bid < 1280) {
        const int q = bid - 1216;
        packT_body(w_proj, Bt2, H_ * D_, C_, C_, (q & 7) * 64, (q >> 3) * 64, tid, Ws);
    } else if (bid < 1288) {
        const int t = (bid - 1280) * 256 + tid;
        float2* op = sincos + (size_t)t * 32;
#pragma unroll
        for (int i = 0; i < 32; ++i) {
            const float div = 6.2831853071795864f * exp2f((float)i * (-11.0f / 32.0f));
            const float ang = (float)t * div;
            op[i] = make_float2(cosf(ang), sinf(ang));
        }
    } else {
        // gate GEMV: g[bh][t] = x[m] . w_attn[:,1536+h]
        const int q = bid - 1288;
        float* LDSw = SM;                      // [512][8]
        {
            const int k = tid * 2;
#pragma unroll
            for (int kk = 0; kk < 2; ++kk) {
                const float* wp = w_attn + (size_t)(k + kk) * QKVG_ + 1536;
                float4 wa = *(const float4*)wp;
                float4 wb = *(const float4*)(wp + 4);
                float* dst = LDSw + (k + kk) * 8;
                *(float4*)dst = wa;
                *(float4*)(dst + 4) = wb;
            }
        }
        __syncthreads();
        const int m = q * 32 + (tid >> 3);
        const int h = tid & 7;
        const float* xrow = x + (size_t)m * C_;
        float s = 0.f;
#pragma unroll 4
        for (int k0 = 0; k0 < 512; k0 += 4) {
            float4 xv = *(const float4*)(xrow + k0);
            s += xv.x * LDSw[(k0 + 0) * 8 + h] + xv.y * LDSw[(k0 + 1) * 8 + h]
               + xv.z * LDSw[(k0 + 2) * 8 + h] + xv.w * LDSw[(k0 + 3) * 8 + h];
        }
        const int b = m >> 11, t = m & 2047;
        g[(size_t)(b * 8 + h) * T_ + t] = s;
    }
}

// ---------------------------------------------------------------------------
// gate_cumsum: one block per (b,h): log-sigmoid(g+bias) + block inclusive scan
// ---------------------------------------------------------------------------
__global__ __launch_bounds__(256) void gate_cumsum(
    const float* __restrict__ g, float* __restrict__ Lg)
{
    __shared__ float wsum[4];
    const int bh = blockIdx.x;
    const int tid = threadIdx.x;
    const int lane = tid & 63, wv = tid >> 6;

    const float* gp = g + (size_t)bh * T_ + tid * 8;
    float v[8];
    float s = 0.f;
#pragma unroll
    for (int j = 0; j < 8; ++j) {
        const float z = gp[j] + GATE_BIAS_;
        const float lg = (z > 0.f) ? -log1pf(expf(-z)) : (z - log1pf(expf(z)));
        s += lg;
        v[j] = s;
    }
    float ssum = s;
#pragma unroll
    for (int off = 1; off < 64; off <<= 1) {
        float n = __shfl_up(ssum, off, 64);
        if (lane >= off) ssum += n;
    }
    if (lane == 63) wsum[wv] = ssum;
    __syncthreads();
    float base = ssum - s;
#pragma unroll
    for (int w = 0; w < 3; ++w)
        base += (w < wv) ? wsum[w] : 0.f;

    float* op = Lg + (size_t)bh * T_ + tid * 8;
#pragma unroll
    for (int j = 0; j < 8; ++j) op[j] = v[j] + base;
}

// ---------------------------------------------------------------------------
// gemm_fused: qkv = xb @ Bt1^T (MFMA, N=1536), double-buffered gl2lds staging
// (prefetch k+1 under compute k; ONE barrier per k-step), fused epilogue:
//   Q -> Qsb (RoPE*e^{+L/2}/8), K -> Ksb (RoPE*e^{-L/2}, pre-swz),
//   V -> Vtb (transposed, pre-swz)
// LDS: [A0 16K][B0 16K][A1 16K][B1 16K]; epilogue overlays first 33.3KB.
// ---------------------------------------------------------------------------
__global__ __launch_bounds__(256) void gemm_fused(
    const unsigned short* __restrict__ A, const unsigned short* __restrict__ Bt,
    const float* __restrict__ Lg, const float2* __restrict__ sincos,
    unsigned short* __restrict__ Qsb, unsigned short* __restrict__ Ksb,
    unsigned short* __restrict__ Vtb)
{
    __shared__ __align__(16) char smem[65536];
    float (*epi)[65] = (float(*)[65])smem;

    const int tid = threadIdx.x;
    const int wave = tid >> 6, lane = tid & 63;
    const int l15 = lane & 15, lhi = lane >> 4;
    const int wr = wave >> 1, wc = wave & 1;
    const int bm = blockIdx.y * 128, bn = blockIdx.x * 128;

    f32x4 acc[4][4];
#pragma unroll
    for (int i = 0; i < 4; ++i)
#pragma unroll
        for (int j = 0; j < 4; ++j) acc[i][j] = (f32x4){0.f, 0.f, 0.f, 0.f};

    const unsigned short* Arow = A + (size_t)bm * C_;
    const unsigned short* Brow = Bt + (size_t)bn * C_;
    const int sw = (l15 & 7) << 4;
    const int srow = tid >> 3;
    const int schunk = tid & 7;

    // prologue: stage k-step 0 into buffer 0
#pragma unroll
    for (int p = 0; p < 4; ++p) {
        const int row = p * 32 + srow;
        const size_t goff = (size_t)row * C_ + schunk * 8;
        gl2lds16(Arow + goff, smem + p * 4096 + wave * 1024);
        gl2lds16(Brow + goff, smem + 16384 + p * 4096 + wave * 1024);
    }

    for (int ks = 0; ks < 8; ++ks) {
        __syncthreads();   // drains loads(ks); frees buffer (ks+1)&1
        if (ks < 7) {
            char* dst = smem + ((ks + 1) & 1) * 32768;
            const int k1 = (ks + 1) * 64;
#pragma unroll
            for (int p = 0; p < 4; ++p) {
                const int row = p * 32 + srow;
                const size_t goff = (size_t)row * C_ + k1 + schunk * 8;
                gl2lds16(Arow + goff, dst + p * 4096 + wave * 1024);
                gl2lds16(Brow + goff, dst + 16384 + p * 4096 + wave * 1024);
            }
        }
        const char* AsB = smem + (ks & 1) * 32768;
        const char* BsB = AsB + 16384;

        short8 af[4][2];
#pragma unroll
        for (int mi = 0; mi < 4; ++mi) {
            const int row = wr * 64 + mi * 16 + l15;
#pragma unroll
            for (int kk = 0; kk < 2; ++kk)
                af[mi][kk] = *(const short8*)(AsB + row * 128 + ((kk * 64 + lhi * 16) ^ sw));
        }
#pragma unroll
        for (int ni = 0; ni < 4; ++ni) {
            const int row = wc * 64 + ni * 16 + l15;
            short8 bf0 = *(const short8*)(BsB + row * 128 + ((lhi * 16) ^ sw));
            short8 bf1 = *(const short8*)(BsB + row * 128 + ((64 + lhi * 16) ^ sw));
#pragma unroll
            for (int mi = 0; mi < 4; ++mi) {
                acc[mi][ni] = __builtin_amdgcn_mfma_f32_16x16x32_bf16(af[mi][0], bf0, acc[mi][ni], 0, 0, 0);
                acc[mi][ni] = __builtin_amdgcn_mfma_f32_16x16x32_bf16(af[mi][1], bf1, acc[mi][ni], 0, 0, 0);
            }
        }
    }

    // -------- fused epilogue --------
    const int rid = bn >> 9;              // 0 Q, 1 K, 2 V
    const int b = bm >> 11;
    const int tloc0 = bm & 2047;

#pragma unroll
    for (int hc = 0; hc < 2; ++hc) {
        __syncthreads();
        if (wc == hc) {
#pragma unroll
            for (int mi = 0; mi < 4; ++mi)
#pragma unroll
                for (int ni = 0; ni < 4; ++ni)
#pragma unroll
                    for (int r = 0; r < 4; ++r)
                        epi[wr * 64 + mi * 16 + lhi * 4 + r][ni * 16 + l15] = acc[mi][ni][r];
        }
        __syncthreads();
        const int h = ((bn & 511) >> 6) + hc;
        const int bh = b * 8 + h;
        if (rid < 2) {
            const int row = tid >> 1;
            const int c0 = (tid & 1) * 32;
            const int t = tloc0 + row;
            const float Lt = Lg[(size_t)bh * T_ + t];
            const float scl = (rid == 0) ? (__expf(0.5f * Lt) * 0.125f)
                                         : __expf(-0.5f * Lt);
            float vb[32];
#pragma unroll
            for (int j = 0; j < 32; ++j) vb[j] = epi[row][c0 + j];
            const float2* sct = sincos + (size_t)t * 32 + (c0 >> 1);
#pragma unroll
            for (int p = 0; p < 16; ++p) {
                const float2 cssn = sct[p];
                const float x1 = vb[2 * p], x2 = vb[2 * p + 1];
                vb[2 * p]     = (x1 * cssn.x - x2 * cssn.y) * scl;
                vb[2 * p + 1] = (x2 * cssn.x + x1 * cssn.y) * scl;
            }
            unsigned short* op = ((rid == 0) ? Qsb : Ksb) + ((size_t)bh * T_ + t) * 64;
#pragma unroll
            for (int j = 0; j < 4; ++j) {
                short8 o = pack8(*(float4*)&vb[j * 8], *(float4*)&vb[j * 8 + 4]);
                const int chunk = (c0 >> 3) + j;
                const int pos = (rid == 0) ? chunk : (chunk ^ (t & 7));
                *(short8*)(op + pos * 8) = o;
            }
        } else {
            const int d = tid >> 2;
            const int tq = tid & 3;
            unsigned short* op = Vtb + ((size_t)(bh * 64 + d)) * T_;
#pragma unroll
            for (int j = 0; j < 4; ++j) {
                const int tl = tq * 32 + j * 8;
                short8 o;
#pragma unroll
                for (int e = 0; e < 8; ++e)
                    o[e] = (short)f2b(epi[tl + e][d]);
                const int chunkidx = (tloc0 + tl) >> 3;
                const int pos = (chunkidx & ~7) | ((chunkidx & 7) ^ (d & 7));
                *(short8*)(op + pos * 8) = o;
            }
        }
    }
}

// ---------------------------------------------------------------------------
// gemm_bf16 (gemm2): C = A @ Bt^T, pre-swizzled operands, double-buffered
// gl2lds staging with prefetch-under-compute.
// ---------------------------------------------------------------------------
__global__ __launch_bounds__(256) void gemm_bf16(
    const unsigned short* __restrict__ A, const unsigned short* __restrict__ Bt,
    float* __restrict__ C, int M, int N, int K)
{
    __shared__ __align__(16) char smem[65536];

    const int tid = threadIdx.x;
    const int wave = tid >> 6, lane = tid & 63;
    const int l15 = lane & 15, lhi = lane >> 4;
    const int wr = wave >> 1, wc = wave & 1;
    const int bm = blockIdx.y * 128, bn = blockIdx.x * 128;

    f32x4 acc[4][4];
#pragma unroll
    for (int i = 0; i < 4; ++i)
#pragma unroll
        for (int j = 0; j < 4; ++j) acc[i][j] = (f32x4){0.f, 0.f, 0.f, 0.f};

    const unsigned short* Arow = A + (size_t)bm * K;
    const unsigned short* Brow = Bt + (size_t)bn * K;
    const int sw = (l15 & 7) << 4;
    const int srow = tid >> 3;
    const int schunk = tid & 7;
    const int nks = K >> 6;

    // prologue
#pragma unroll
    for (int p = 0; p < 4; ++p) {
        const int row = p * 32 + srow;
        const size_t goff = (size_t)row * K + schunk * 8;
        gl2lds16(Arow + goff, smem + p * 4096 + wave * 1024);
        gl2lds16(Brow + goff, smem + 16384 + p * 4096 + wave * 1024);
    }

    for (int ks = 0; ks < nks; ++ks) {
        __syncthreads();
        if (ks + 1 < nks) {
            char* dst = smem + ((ks + 1) & 1) * 32768;
            const int k1 = (ks + 1) * 64;
#pragma unroll
            for (int p = 0; p < 4; ++p) {
                const int row = p * 32 + srow;
                const size_t goff = (size_t)row * K + k1 + schunk * 8;
                gl2lds16(Arow + goff, dst + p * 4096 + wave * 1024);
                gl2lds16(Brow + goff, dst + 16384 + p * 4096 + wave * 1024);
            }
        }
        const char* AsB = smem + (ks & 1) * 32768;
        const char* BsB = AsB + 16384;

        short8 af[4][2];
#pragma unroll
        for (int mi = 0; mi < 4; ++mi) {
            const int row = wr * 64 + mi * 16 + l15;
#pragma unroll
            for (int kk = 0; kk < 2; ++kk)
                af[mi][kk] = *(const short8*)(AsB + row * 128 + ((kk * 64 + lhi * 16) ^ sw));
        }
#pragma unroll
        for (int ni = 0; ni < 4; ++ni) {
            const int row = wc * 64 + ni * 16 + l15;
            short8 bf0 = *(const short8*)(BsB + row * 128 + ((lhi * 16) ^ sw));
            short8 bf1 = *(const short8*)(BsB + row * 128 + ((64 + lhi * 16) ^ sw));
#pragma unroll
            for (int mi = 0; mi < 4; ++mi) {
                acc[mi][ni] = __builtin_amdgcn_mfma_f32_16x16x32_bf16(af[mi][0], bf0, acc[mi][ni], 0, 0, 0);
                acc[mi][ni] = __builtin_amdgcn_mfma_f32_16x16x32_bf16(af[mi][1], bf1, acc[mi][ni], 0, 0, 0);
            }
        }
    }

#pragma unroll
    for (int mi = 0; mi < 4; ++mi) {
        const int gm = bm + wr * 64 + mi * 16 + lhi * 4;
#pragma unroll
        for (int r = 0; r < 4; ++r) {
            float* crow = C + (size_t)(gm + r) * N;
#pragma unroll
            for (int ni = 0; ni < 4; ++ni) {
                const int gn = bn + wc * 64 + ni * 16 + l15;
                if (gn < N) crow[gn] = acc[mi][ni][r];
            }
        }
    }
}

// ---------------------------------------------------------------------------
// attn_mfma: scores p = (q'.k')^2; XCD-pinned grid; K/V double-buffered
// gl2lds staging (prefetch tile st+1 under compute of st), one barrier/tile.
// LDS: [K0 8K][V0 8K][K1 8K][V1 8K][PsB 8K] = 40KB.
// ---------------------------------------------------------------------------
__global__ __launch_bounds__(256) void attn_mfma(
    const unsigned short* __restrict__ Qsb, const unsigned short* __restrict__ Ksb,
    const unsigned short* __restrict__ Vtb,
    float* __restrict__ Y0, float* __restrict__ Yp, float* __restrict__ Dpart)
{
    __shared__ __align__(16) char smem[40960];
    char* PsB = smem + 32768;

    const int wg = blockIdx.x;
    const int xcd = wg & 7;
    const int slot = wg >> 3;
    const int bh = (slot < 80) ? xcd : 8 + xcd;
    const int rem = (slot < 80) ? slot : slot - 80;
    const int rr = 79 - rem;
    int bt, sc;
    if (rr < 8)       { bt = rr; sc = 0; }
    else if (rr < 24) { const int q = rr - 8;  bt = 8 + (q >> 1);  sc = q & 1; }
    else if (rr < 48) { const int q = rr - 24; bt = 16 + q / 3;    sc = q % 3; }
    else              { const int q = rr - 48; bt = 24 + (q >> 2); sc = q & 3; }
    const int st0 = sc * SC_;
    const int st1 = min(st0 + SC_ - 1, bt);

    const int tid = threadIdx.x;
    const int wave = tid >> 6;
    const int lane = tid & 63;
    const int l15 = lane & 15;
    const int lhi = lane >> 4;
    const int b = bh >> 3, h = bh & 7;
    const int t0 = bt * 64;

    const int qrow = t0 + wave * 16 + l15;
    const unsigned short* qpp = Qsb + ((size_t)bh * T_ + qrow) * 64 + lhi * 8;
    short8 qf[2];
    qf[0] = *(const short8*)(qpp);
    qf[1] = *(const short8*)(qpp + 32);

    f32x4 accY[4];
#pragma unroll
    for (int n = 0; n < 4; ++n) accY[n] = (f32x4){0.f, 0.f, 0.f, 0.f};
    float den[4] = {0.f, 0.f, 0.f, 0.f};

    const int kchunk = lhi * 16;
    const int rsw = (l15 & 7) << 4;
    const int srow = tid >> 3;
    const int schunk = tid & 7;

    // prologue: stage tile st0 into buffer 0
#pragma unroll
    for (int p = 0; p < 2; ++p) {
        const int row = p * 32 + srow;
        gl2lds16(Ksb + ((size_t)bh * T_ + st0 * 64 + row) * 64 + schunk * 8,
                 smem + p * 4096 + wave * 1024);
        gl2lds16(Vtb + ((size_t)bh * 64 + row) * T_ + st0 * 64 + schunk * 8,
                 smem + 8192 + p * 4096 + wave * 1024);
    }

    for (int st = st0; st <= st1; ++st) {
        __syncthreads();   // drains loads(st); frees other buffer
        if (st < st1) {
            char* dst = smem + (((st - st0) + 1) & 1) * 16384;
            const int s1 = (st + 1) * 64;
#pragma unroll
            for (int p = 0; p < 2; ++p) {
                const int row = p * 32 + srow;
                gl2lds16(Ksb + ((size_t)bh * T_ + s1 + row) * 64 + schunk * 8,
                         dst + p * 4096 + wave * 1024);
                gl2lds16(Vtb + ((size_t)bh * 64 + row) * T_ + s1 + schunk * 8,
                         dst + 8192 + p * 4096 + wave * 1024);
            }
        }
        const char* KsB = smem + ((st - st0) & 1) * 16384;
        const char* VtB = KsB + 8192;

        f32x4 accS[4];
#pragma unroll
        for (int n = 0; n < 4; ++n) accS[n] = (f32x4){0.f, 0.f, 0.f, 0.f};
#pragma unroll
        for (int n = 0; n < 4; ++n) {
#pragma unroll
            for (int kk = 0; kk < 2; ++kk) {
                short8 bf = *(const short8*)(KsB + (n * 16 + l15) * 128 + ((kk * 64 + kchunk) ^ rsw));
                accS[n] = __builtin_amdgcn_mfma_f32_16x16x32_bf16(qf[kk], bf, accS[n], 0, 0, 0);
            }
        }

        const bool last = (st == bt);
        char* PsW = PsB + wave * 2048;
#pragma unroll
        for (int n = 0; n < 4; ++n) {
#pragma unroll
            for (int r = 0; r < 4; ++r) {
                const float a = accS[n][r];
                float p = a * a;
                if (last)
                    p = ((n * 16 + l15) <= wave * 16 + lhi * 4 + r) ? p : 0.f;
                den[r] += p;
                const int prow = lhi * 4 + r;
                *(unsigned short*)(PsW + prow * 128 + ((2 * (n * 16 + l15)) ^ ((prow & 7) << 4))) = f2b(p);
            }
        }

        short8 pa[2];
#pragma unroll
        for (int kk = 0; kk < 2; ++kk)
            pa[kk] = *(const short8*)(PsW + l15 * 128 + ((kk * 64 + kchunk) ^ rsw));
#pragma unroll
        for (int n = 0; n < 4; ++n) {
#pragma unroll
            for (int kk = 0; kk < 2; ++kk) {
                short8 vb = *(const short8*)(VtB + (n * 16 + l15) * 128 + ((kk * 64 + kchunk) ^ rsw));
                accY[n] = __builtin_amdgcn_mfma_f32_16x16x32_bf16(pa[kk], vb, accY[n], 0, 0, 0);
            }
        }
    }

#pragma unroll
    for (int r = 0; r < 4; ++r) {
        den[r] += __shfl_xor(den[r], 1, 64);
        den[r] += __shfl_xor(den[r], 2, 64);
        den[r] += __shfl_xor(den[r], 4, 64);
        den[r] += __shfl_xor(den[r], 8, 64);
    }

    float* Ybase = (sc == 0) ? Y0 : (Yp + (size_t)(sc - 1) * MC_);
    float* Dbase = Dpart + (size_t)sc * BHT_;
#pragma unroll
    for (int r = 0; r < 4; ++r) {
        const int t = t0 + wave * 16 + lhi * 4 + r;
        if (l15 == 0)
            Dbase[(size_t)bh * T_ + t] = den[r];
        float* yo = Ybase + (size_t)(b * T_ + t) * (H_ * D_) + h * 64 + l15;
#pragma unroll
        for (int n = 0; n < 4; ++n)
            yo[n * 16] = accY[n][r];
    }
}

// ---------------------------------------------------------------------------
// normalize: ybb = bf16((sum Y slices) / max(sum den, 1e-6)), PRE-SWIZZLED
// ---------------------------------------------------------------------------
__global__ __launch_bounds__(256) void normalize_kernel(
    const float* __restrict__ Y0, const float* __restrict__ Yp,
    const float* __restrict__ Dpart, unsigned short* __restrict__ ybb)
{
    const int gid = blockIdx.x * 256 + threadIdx.x;
    const size_t base = (size_t)gid * 8;
    const int row = (int)(base >> 9);
    const int col = (int)(base & 511);
    const int b = row >> 11, t = row & 2047, h = col >> 6;
    const int bh = b * H_ + h;
    const int nsc = ((t >> 6) >> 3) + 1;

    float d = Dpart[(size_t)bh * T_ + t];
    float4 f0 = *(const float4*)(Y0 + base);
    float4 f1 = *(const float4*)(Y0 + base + 4);
    for (int s = 1; s < nsc; ++s) {
        d += Dpart[(size_t)s * BHT_ + (size_t)bh * T_ + t];
        const float* yp = Yp + (size_t)(s - 1) * MC_ + base;
        float4 g0 = *(const float4*)(yp);
        float4 g1 = *(const float4*)(yp + 4);
        f0.x += g0.x; f0.y += g0.y; f0.z += g0.z; f0.w += g0.w;
        f1.x += g1.x; f1.y += g1.y; f1.z += g1.z; f1.w += g1.w;
    }
    const float inv = 1.0f / fmaxf(d, 1e-6f);
    f0.x *= inv; f0.y *= inv; f0.z *= inv; f0.w *= inv;
    f1.x *= inv; f1.y *= inv; f1.z *= inv; f1.w *= inv;

    const int ic = col >> 3;
    const int swc = (ic & ~7) | ((ic & 7) ^ (row & 7));
    *(short8*)(ybb + (size_t)row * 512 + swc * 8) = pack8(f0, f1);
}

// ---------------------------------------------------------------------------
extern "C" void kernel_launch(void* const* d_in, const int* in_sizes, int n_in,
                              void* d_out, int out_size, void* d_ws, size_t ws_size,
                              hipStream_t stream)
{
    const float* x      = (const float*)d_in[0];
    const float* w_attn = (const float*)d_in[1];
    const float* w_proj = (const float*)d_in[2];
    float* out = (float*)d_out;

    // workspace (~47 MB of ~256 MB), no aliasing:
    char* p = (char*)d_ws;
    float2* sincos = (float2*)p;               p += (size_t)T_ * 32 * 8;       // 512 KB
    float* g       = (float*)p;                p += (size_t)BHT_ * 4;          // 128 KB
    float* Lg      = (float*)p;                p += (size_t)BHT_ * 4;          // 128 KB
    float* Dpart   = (float*)p;                p += (size_t)4 * BHT_ * 4;      // 512 KB
    unsigned short* xb  = (unsigned short*)p;  p += (size_t)MC_ * 2;           // 4 MB
    unsigned short* Bt1 = (unsigned short*)p;  p += (size_t)N1_ * C_ * 2;      // 1.5 MB
    unsigned short* Bt2 = (unsigned short*)p;  p += (size_t)C_ * C_ * 2;       // 0.5 MB
    unsigned short* Qsb = (unsigned short*)p;  p += (size_t)BHT_ * 64 * 2;     // 4 MB
    unsigned short* Ksb = (unsigned short*)p;  p += (size_t)BHT_ * 64 * 2;     // 4 MB
    unsigned short* Vtb = (unsigned short*)p;  p += (size_t)BHT_ * 64 * 2;     // 4 MB
    float* Yp      = (float*)p;                p += (size_t)3 * MC_ * 4;       // 24 MB
    unsigned short* ybb = (unsigned short*)p;                                  // 4 MB

    const int M = B_ * T_;      // 4096

    // 0) packs + sincos table + gate GEMV
    pack_inputs<<<1416, 256, 0, stream>>>(x, w_attn, w_proj, xb, Bt1, Bt2, sincos, g);

    // 1) gate log-sigmoid + cumsum -> Lg
    gate_cumsum<<<B_ * H_, 256, 0, stream>>>(g, Lg);

    // 2) fused qkv GEMM + RoPE/prescale/transpose epilogue -> Qsb, Ksb, Vtb
    gemm_fused<<<dim3(N1_ / 128, M / 128), 256, 0, stream>>>(
        xb, Bt1, Lg, sincos, Qsb, Ksb, Vtb);

    // 3) split-s attention, non-atomic partial slices
    attn_mfma<<<NBLK_, 256, 0, stream>>>(Qsb, Ksb, Vtb, out, Yp, Dpart);

    // 4) normalize + slice-sum -> ybb (bf16, pre-swizzled)
    normalize_kernel<<<(MC_ / 8) / 256, 256, 0, stream>>>(out, Yp, Dpart, ybb);

    // 5) out = ybb @ w_proj
    gemm_bf16<<<dim3(C_ / 128, M / 128), 256, 0, stream>>>(
        ybb, Bt2, out, M, C_, H_ * D_);
}

// Round 14
// 79.148 us; speedup vs baseline: 1.7016x; 1.0083x over previous
//
#include <hip/hip_runtime.h>
#include <hip/hip_bf16.h>
#include <math.h>

// Problem constants (fixed by setup_inputs)
constexpr int B_ = 2, T_ = 2048, C_ = 512, H_ = 8, D_ = 64;
constexpr int QKVG_ = 3 * H_ * D_ + H_;   // 1544 (w_attn row stride)
constexpr float GATE_BIAS_ = 6.906768f;
constexpr int N1_ = 1536;                 // gemm1 N (Q,K,V only; gate separate)
constexpr int SC_ = 8;                    // s-tiles per attn chunk
constexpr int NBLK_ = 1280;               // attn blocks (16 bh x 80)
constexpr int MC_ = 4096 * 512;           // 2,097,152
constexpr int BHT_ = B_ * H_ * T_;        // 32,768

typedef __attribute__((ext_vector_type(8))) short short8;
typedef __attribute__((ext_vector_type(4))) float f32x4;

// hardware RNE f32->bf16 (compiler fuses pairs into v_cvt_pk_bf16_f32)
__device__ __forceinline__ unsigned short f2b(float f) {
    union { __hip_bfloat16 h; unsigned short u; } cv;
    cv.h = __float2bfloat16(f);
    return cv.u;
}
__device__ __forceinline__ short8 pack8(float4 a, float4 b) {
    short8 r;
    r[0] = (short)f2b(a.x); r[1] = (short)f2b(a.y);
    r[2] = (short)f2b(a.z); r[3] = (short)f2b(a.w);
    r[4] = (short)f2b(b.x); r[5] = (short)f2b(b.y);
    r[6] = (short)f2b(b.z); r[7] = (short)f2b(b.w);
    return r;
}

// async global->LDS, 16 B/lane
__device__ __forceinline__ void gl2lds16(const unsigned short* g, void* lds_base) {
    __builtin_amdgcn_global_load_lds(
        (const __attribute__((address_space(1))) unsigned int*)g,
        (__attribute__((address_space(3))) unsigned int*)lds_base, 16, 0, 0);
}

// ---------------------------------------------------------------------------
// pack_inputs: [0,1024) x->xb (pre-swz) | [1024,1216) w_attn->Bt1 (24x8) |
// [1216,1280) w_proj->Bt2 (8x8) | [1280,1288) sincos table | [1288,1416) gate GEMV
// ---------------------------------------------------------------------------
__device__ __forceinline__ void packT_body(
    const float* __restrict__ W, unsigned short* __restrict__ Bt,
    int K, int N, int ldW, int nt, int kt, int tid, float (*Ws)[65])
{
    {
        const int r = tid >> 2;
        const int c0 = (tid & 3) * 16;
#pragma unroll
        for (int j = 0; j < 16; ++j) {
            const int n = nt + c0 + j;
            Ws[r][c0 + j] = (n < N) ? W[(size_t)(kt + r) * ldW + n] : 0.f;
        }
    }
    __syncthreads();
    {
        const int d = tid >> 2;
        const int cc = tid & 3;
        const int kc = cc * 16;
        short8 o0, o1;
#pragma unroll
        for (int j = 0; j < 8; ++j) o0[j] = (short)f2b(Ws[kc + j][d]);
#pragma unroll
        for (int j = 0; j < 8; ++j) o1[j] = (short)f2b(Ws[kc + 8 + j][d]);
        const int row = nt + d;
        unsigned short* op = Bt + (size_t)row * K + kt;
        *(short8*)(op + ((2 * cc) ^ (row & 7)) * 8)     = o0;
        *(short8*)(op + ((2 * cc + 1) ^ (row & 7)) * 8) = o1;
    }
}

__global__ __launch_bounds__(256) void pack_inputs(
    const float* __restrict__ x, const float* __restrict__ w_attn,
    const float* __restrict__ w_proj, unsigned short* __restrict__ xb,
    unsigned short* __restrict__ Bt1, unsigned short* __restrict__ Bt2,
    float2* __restrict__ sincos, float* __restrict__ g)
{
    __shared__ float SM[64 * 65];
    float (*Ws)[65] = (float(*)[65])SM;
    const int bid = blockIdx.x;
    const int tid = threadIdx.x;
    if (bid < 1024) {
        const int i = bid * 256 + tid;
        float4 f0 = *(const float4*)(x + (size_t)i * 8);
        float4 f1 = *(const float4*)(x + (size_t)i * 8 + 4);
        const int row = i >> 6;
        const int ic = i & 63;
        const int swc = (ic & ~7) | ((ic & 7) ^ (row & 7));
        *(short8*)(xb + (size_t)row * 512 + swc * 8) = pack8(f0, f1);
    } else if (bid < 1216) {
        const int q = bid - 1024;
        packT_body(w_attn, Bt1, C_, N1_, QKVG_, (q % 24) * 64, (q / 24) * 64, tid, Ws);
    } else if (bid < 1280) {
        const int q = bid - 1216;
        packT_body(w_proj, Bt2, H_ * D_, C_, C_, (q & 7) * 64, (q >> 3) * 64, tid, Ws);
    } else if (bid < 1288) {
        const int t = (bid - 1280) * 256 + tid;
        float2* op = sincos + (size_t)t * 32;
#pragma unroll
        for (int i = 0; i < 32; ++i) {
            const float div = 6.2831853071795864f * exp2f((float)i * (-11.0f / 32.0f));
            const float ang = (float)t * div;
            op[i] = make_float2(cosf(ang), sinf(ang));
        }
    } else {
        // gate GEMV: g[bh][t] = x[m] . w_attn[:,1536+h]
        const int q = bid - 1288;
        float* LDSw = SM;                      // [512][8]
        {
            const int k = tid * 2;
#pragma unroll
            for (int kk = 0; kk < 2; ++kk) {
                const float* wp = w_attn + (size_t)(k + kk) * QKVG_ + 1536;
                float4 wa = *(const float4*)wp;
                float4 wb = *(const float4*)(wp + 4);
                float* dst = LDSw + (k + kk) * 8;
                *(float4*)dst = wa;
                *(float4*)(dst + 4) = wb;
            }
        }
        __syncthreads();
        const int m = q * 32 + (tid >> 3);
        const int h = tid & 7;
        const float* xrow = x + (size_t)m * C_;
        float s = 0.f;
#pragma unroll 4
        for (int k0 = 0; k0 < 512; k0 += 4) {
            float4 xv = *(const float4*)(xrow + k0);
            s += xv.x * LDSw[(k0 + 0) * 8 + h] + xv.y * LDSw[(k0 + 1) * 8 + h]
               + xv.z * LDSw[(k0 + 2) * 8 + h] + xv.w * LDSw[(k0 + 3) * 8 + h];
        }
        const int b = m >> 11, t = m & 2047;
        g[(size_t)(b * 8 + h) * T_ + t] = s;
    }
}

// ---------------------------------------------------------------------------
// gate_cumsum: one block per (b,h): log-sigmoid(g+bias) + block inclusive scan
// ---------------------------------------------------------------------------
__global__ __launch_bounds__(256) void gate_cumsum(
    const float* __restrict__ g, float* __restrict__ Lg)
{
    __shared__ float wsum[4];
    const int bh = blockIdx.x;
    const int tid = threadIdx.x;
    const int lane = tid & 63, wv = tid >> 6;

    const float* gp = g + (size_t)bh * T_ + tid * 8;
    float v[8];
    float s = 0.f;
#pragma unroll
    for (int j = 0; j < 8; ++j) {
        const float z = gp[j] + GATE_BIAS_;
        const float lg = (z > 0.f) ? -log1pf(expf(-z)) : (z - log1pf(expf(z)));
        s += lg;
        v[j] = s;
    }
    float ssum = s;
#pragma unroll
    for (int off = 1; off < 64; off <<= 1) {
        float n = __shfl_up(ssum, off, 64);
        if (lane >= off) ssum += n;
    }
    if (lane == 63) wsum[wv] = ssum;
    __syncthreads();
    float base = ssum - s;
#pragma unroll
    for (int w = 0; w < 3; ++w)
        base += (w < wv) ? wsum[w] : 0.f;

    float* op = Lg + (size_t)bh * T_ + tid * 8;
#pragma unroll
    for (int j = 0; j < 8; ++j) op[j] = v[j] + base;
}

// ---------------------------------------------------------------------------
// gemm_fused: qkv = xb @ Bt1^T (MFMA, N=1536), double-buffered gl2lds staging,
// fused epilogue -> Qsb / Ksb(swz) / Vtb(transposed, swz)
// ---------------------------------------------------------------------------
__global__ __launch_bounds__(256) void gemm_fused(
    const unsigned short* __restrict__ A, const unsigned short* __restrict__ Bt,
    const float* __restrict__ Lg, const float2* __restrict__ sincos,
    unsigned short* __restrict__ Qsb, unsigned short* __restrict__ Ksb,
    unsigned short* __restrict__ Vtb)
{
    __shared__ __align__(16) char smem[65536];
    float (*epi)[65] = (float(*)[65])smem;

    const int tid = threadIdx.x;
    const int wave = tid >> 6, lane = tid & 63;
    const int l15 = lane & 15, lhi = lane >> 4;
    const int wr = wave >> 1, wc = wave & 1;
    const int bm = blockIdx.y * 128, bn = blockIdx.x * 128;

    f32x4 acc[4][4];
#pragma unroll
    for (int i = 0; i < 4; ++i)
#pragma unroll
        for (int j = 0; j < 4; ++j) acc[i][j] = (f32x4){0.f, 0.f, 0.f, 0.f};

    const unsigned short* Arow = A + (size_t)bm * C_;
    const unsigned short* Brow = Bt + (size_t)bn * C_;
    const int sw = (l15 & 7) << 4;
    const int srow = tid >> 3;
    const int schunk = tid & 7;

    // prologue: stage k-step 0 into buffer 0
#pragma unroll
    for (int p = 0; p < 4; ++p) {
        const int row = p * 32 + srow;
        const size_t goff = (size_t)row * C_ + schunk * 8;
        gl2lds16(Arow + goff, smem + p * 4096 + wave * 1024);
        gl2lds16(Brow + goff, smem + 16384 + p * 4096 + wave * 1024);
    }

    for (int ks = 0; ks < 8; ++ks) {
        __syncthreads();
        if (ks < 7) {
            char* dst = smem + ((ks + 1) & 1) * 32768;
            const int k1 = (ks + 1) * 64;
#pragma unroll
            for (int p = 0; p < 4; ++p) {
                const int row = p * 32 + srow;
                const size_t goff = (size_t)row * C_ + k1 + schunk * 8;
                gl2lds16(Arow + goff, dst + p * 4096 + wave * 1024);
                gl2lds16(Brow + goff, dst + 16384 + p * 4096 + wave * 1024);
            }
        }
        const char* AsB = smem + (ks & 1) * 32768;
        const char* BsB = AsB + 16384;

        short8 af[4][2];
#pragma unroll
        for (int mi = 0; mi < 4; ++mi) {
            const int row = wr * 64 + mi * 16 + l15;
#pragma unroll
            for (int kk = 0; kk < 2; ++kk)
                af[mi][kk] = *(const short8*)(AsB + row * 128 + ((kk * 64 + lhi * 16) ^ sw));
        }
#pragma unroll
        for (int ni = 0; ni < 4; ++ni) {
            const int row = wc * 64 + ni * 16 + l15;
            short8 bf0 = *(const short8*)(BsB + row * 128 + ((lhi * 16) ^ sw));
            short8 bf1 = *(const short8*)(BsB + row * 128 + ((64 + lhi * 16) ^ sw));
#pragma unroll
            for (int mi = 0; mi < 4; ++mi) {
                acc[mi][ni] = __builtin_amdgcn_mfma_f32_16x16x32_bf16(af[mi][0], bf0, acc[mi][ni], 0, 0, 0);
                acc[mi][ni] = __builtin_amdgcn_mfma_f32_16x16x32_bf16(af[mi][1], bf1, acc[mi][ni], 0, 0, 0);
            }
        }
    }

    // -------- fused epilogue --------
    const int rid = bn >> 9;              // 0 Q, 1 K, 2 V
    const int b = bm >> 11;
    const int tloc0 = bm & 2047;

#pragma unroll
    for (int hc = 0; hc < 2; ++hc) {
        __syncthreads();
        if (wc == hc) {
#pragma unroll
            for (int mi = 0; mi < 4; ++mi)
#pragma unroll
                for (int ni = 0; ni < 4; ++ni)
#pragma unroll
                    for (int r = 0; r < 4; ++r)
                        epi[wr * 64 + mi * 16 + lhi * 4 + r][ni * 16 + l15] = acc[mi][ni][r];
        }
        __syncthreads();
        const int h = ((bn & 511) >> 6) + hc;
        const int bh = b * 8 + h;
        if (rid < 2) {
            const int row = tid >> 1;
            const int c0 = (tid & 1) * 32;
            const int t = tloc0 + row;
            const float Lt = Lg[(size_t)bh * T_ + t];
            const float scl = (rid == 0) ? (__expf(0.5f * Lt) * 0.125f)
                                         : __expf(-0.5f * Lt);
            float vb[32];
#pragma unroll
            for (int j = 0; j < 32; ++j) vb[j] = epi[row][c0 + j];
            const float2* sct = sincos + (size_t)t * 32 + (c0 >> 1);
#pragma unroll
            for (int p = 0; p < 16; ++p) {
                const float2 cssn = sct[p];
                const float x1 = vb[2 * p], x2 = vb[2 * p + 1];
                vb[2 * p]     = (x1 * cssn.x - x2 * cssn.y) * scl;
                vb[2 * p + 1] = (x2 * cssn.x + x1 * cssn.y) * scl;
            }
            unsigned short* op = ((rid == 0) ? Qsb : Ksb) + ((size_t)bh * T_ + t) * 64;
#pragma unroll
            for (int j = 0; j < 4; ++j) {
                short8 o = pack8(*(float4*)&vb[j * 8], *(float4*)&vb[j * 8 + 4]);
                const int chunk = (c0 >> 3) + j;
                const int pos = (rid == 0) ? chunk : (chunk ^ (t & 7));
                *(short8*)(op + pos * 8) = o;
            }
        } else {
            const int d = tid >> 2;
            const int tq = tid & 3;
            unsigned short* op = Vtb + ((size_t)(bh * 64 + d)) * T_;
#pragma unroll
            for (int j = 0; j < 4; ++j) {
                const int tl = tq * 32 + j * 8;
                short8 o;
#pragma unroll
                for (int e = 0; e < 8; ++e)
                    o[e] = (short)f2b(epi[tl + e][d]);
                const int chunkidx = (tloc0 + tl) >> 3;
                const int pos = (chunkidx & ~7) | ((chunkidx & 7) ^ (d & 7));
                *(short8*)(op + pos * 8) = o;
            }
        }
    }
}

// ---------------------------------------------------------------------------
// gemm_bf16 (gemm2): C = A @ Bt^T, tile 64x128 (grid 256 blocks = 1/CU),
// pre-swizzled operands, double-buffered gl2lds staging.
// LDS: [A0 8K][B0 16K][A1 8K][B1 16K] = 48KB.
// ---------------------------------------------------------------------------
__global__ __launch_bounds__(256) void gemm_bf16(
    const unsigned short* __restrict__ A, const unsigned short* __restrict__ Bt,
    float* __restrict__ C, int M, int N, int K)
{
    __shared__ __align__(16) char smem[49152];

    const int tid = threadIdx.x;
    const int wave = tid >> 6, lane = tid & 63;
    const int l15 = lane & 15, lhi = lane >> 4;
    const int wr = wave >> 1, wc = wave & 1;
    const int bm = blockIdx.y * 64, bn = blockIdx.x * 128;

    f32x4 acc[2][4];
#pragma unroll
    for (int i = 0; i < 2; ++i)
#pragma unroll
        for (int j = 0; j < 4; ++j) acc[i][j] = (f32x4){0.f, 0.f, 0.f, 0.f};

    const unsigned short* Arow = A + (size_t)bm * K;
    const unsigned short* Brow = Bt + (size_t)bn * K;
    const int sw = (l15 & 7) << 4;
    const int srow = tid >> 3;
    const int schunk = tid & 7;
    const int nks = K >> 6;

    // prologue
#pragma unroll
    for (int p = 0; p < 2; ++p) {
        const int row = p * 32 + srow;
        gl2lds16(Arow + (size_t)row * K + schunk * 8, smem + p * 4096 + wave * 1024);
    }
#pragma unroll
    for (int p = 0; p < 4; ++p) {
        const int row = p * 32 + srow;
        gl2lds16(Brow + (size_t)row * K + schunk * 8, smem + 8192 + p * 4096 + wave * 1024);
    }

    for (int ks = 0; ks < nks; ++ks) {
        __syncthreads();
        if (ks + 1 < nks) {
            char* dst = smem + ((ks + 1) & 1) * 24576;
            const int k1 = (ks + 1) * 64;
#pragma unroll
            for (int p = 0; p < 2; ++p) {
                const int row = p * 32 + srow;
                gl2lds16(Arow + (size_t)row * K + k1 + schunk * 8, dst + p * 4096 + wave * 1024);
            }
#pragma unroll
            for (int p = 0; p < 4; ++p) {
                const int row = p * 32 + srow;
                gl2lds16(Brow + (size_t)row * K + k1 + schunk * 8, dst + 8192 + p * 4096 + wave * 1024);
            }
        }
        const char* AsB = smem + (ks & 1) * 24576;
        const char* BsB = AsB + 8192;

        short8 af[2][2];
#pragma unroll
        for (int mi = 0; mi < 2; ++mi) {
            const int row = wr * 32 + mi * 16 + l15;
#pragma unroll
            for (int kk = 0; kk < 2; ++kk)
                af[mi][kk] = *(const short8*)(AsB + row * 128 + ((kk * 64 + lhi * 16) ^ sw));
        }
#pragma unroll
        for (int ni = 0; ni < 4; ++ni) {
            const int row = wc * 64 + ni * 16 + l15;
            short8 bf0 = *(const short8*)(BsB + row * 128 + ((lhi * 16) ^ sw));
            short8 bf1 = *(const short8*)(BsB + row * 128 + ((64 + lhi * 16) ^ sw));
#pragma unroll
            for (int mi = 0; mi < 2; ++mi) {
                acc[mi][ni] = __builtin_amdgcn_mfma_f32_16x16x32_bf16(af[mi][0], bf0, acc[mi][ni], 0, 0, 0);
                acc[mi][ni] = __builtin_amdgcn_mfma_f32_16x16x32_bf16(af[mi][1], bf1, acc[mi][ni], 0, 0, 0);
            }
        }
    }

#pragma unroll
    for (int mi = 0; mi < 2; ++mi) {
        const int gm = bm + wr * 32 + mi * 16 + lhi * 4;
#pragma unroll
        for (int r = 0; r < 4; ++r) {
            float* crow = C + (size_t)(gm + r) * N;
#pragma unroll
            for (int ni = 0; ni < 4; ++ni) {
                const int gn = bn + wc * 64 + ni * 16 + l15;
                if (gn < N) crow[gn] = acc[mi][ni][r];
            }
        }
    }
}

// ---------------------------------------------------------------------------
// attn_mfma: scores p = (q'.k')^2; XCD-pinned grid; K/V double-buffered
// gl2lds staging; s_setprio(1) around MFMA clusters (T5).
// ---------------------------------------------------------------------------
__global__ __launch_bounds__(256) void attn_mfma(
    const unsigned short* __restrict__ Qsb, const unsigned short* __restrict__ Ksb,
    const unsigned short* __restrict__ Vtb,
    float* __restrict__ Y0, float* __restrict__ Yp, float* __restrict__ Dpart)
{
    __shared__ __align__(16) char smem[40960];
    char* PsB = smem + 32768;

    const int wg = blockIdx.x;
    const int xcd = wg & 7;
    const int slot = wg >> 3;
    const int bh = (slot < 80) ? xcd : 8 + xcd;
    const int rem = (slot < 80) ? slot : slot - 80;
    const int rr = 79 - rem;
    int bt, sc;
    if (rr < 8)       { bt = rr; sc = 0; }
    else if (rr < 24) { const int q = rr - 8;  bt = 8 + (q >> 1);  sc = q & 1; }
    else if (rr < 48) { const int q = rr - 24; bt = 16 + q / 3;    sc = q % 3; }
    else              { const int q = rr - 48; bt = 24 + (q >> 2); sc = q & 3; }
    const int st0 = sc * SC_;
    const int st1 = min(st0 + SC_ - 1, bt);

    const int tid = threadIdx.x;
    const int wave = tid >> 6;
    const int lane = tid & 63;
    const int l15 = lane & 15;
    const int lhi = lane >> 4;
    const int b = bh >> 3, h = bh & 7;
    const int t0 = bt * 64;

    const int qrow = t0 + wave * 16 + l15;
    const unsigned short* qpp = Qsb + ((size_t)bh * T_ + qrow) * 64 + lhi * 8;
    short8 qf[2];
    qf[0] = *(const short8*)(qpp);
    qf[1] = *(const short8*)(qpp + 32);

    f32x4 accY[4];
#pragma unroll
    for (int n = 0; n < 4; ++n) accY[n] = (f32x4){0.f, 0.f, 0.f, 0.f};
    float den[4] = {0.f, 0.f, 0.f, 0.f};

    const int kchunk = lhi * 16;
    const int rsw = (l15 & 7) << 4;
    const int srow = tid >> 3;
    const int schunk = tid & 7;

    // prologue: stage tile st0 into buffer 0
#pragma unroll
    for (int p = 0; p < 2; ++p) {
        const int row = p * 32 + srow;
        gl2lds16(Ksb + ((size_t)bh * T_ + st0 * 64 + row) * 64 + schunk * 8,
                 smem + p * 4096 + wave * 1024);
        gl2lds16(Vtb + ((size_t)bh * 64 + row) * T_ + st0 * 64 + schunk * 8,
                 smem + 8192 + p * 4096 + wave * 1024);
    }

    for (int st = st0; st <= st1; ++st) {
        __syncthreads();
        if (st < st1) {
            char* dst = smem + (((st - st0) + 1) & 1) * 16384;
            const int s1 = (st + 1) * 64;
#pragma unroll
            for (int p = 0; p < 2; ++p) {
                const int row = p * 32 + srow;
                gl2lds16(Ksb + ((size_t)bh * T_ + s1 + row) * 64 + schunk * 8,
                         dst + p * 4096 + wave * 1024);
                gl2lds16(Vtb + ((size_t)bh * 64 + row) * T_ + s1 + schunk * 8,
                         dst + 8192 + p * 4096 + wave * 1024);
            }
        }
        const char* KsB = smem + ((st - st0) & 1) * 16384;
        const char* VtB = KsB + 8192;

        f32x4 accS[4];
#pragma unroll
        for (int n = 0; n < 4; ++n) accS[n] = (f32x4){0.f, 0.f, 0.f, 0.f};
        __builtin_amdgcn_s_setprio(1);
#pragma unroll
        for (int n = 0; n < 4; ++n) {
#pragma unroll
            for (int kk = 0; kk < 2; ++kk) {
                short8 bf = *(const short8*)(KsB + (n * 16 + l15) * 128 + ((kk * 64 + kchunk) ^ rsw));
                accS[n] = __builtin_amdgcn_mfma_f32_16x16x32_bf16(qf[kk], bf, accS[n], 0, 0, 0);
            }
        }
        __builtin_amdgcn_s_setprio(0);

        const bool last = (st == bt);
        char* PsW = PsB + wave * 2048;
#pragma unroll
        for (int n = 0; n < 4; ++n) {
#pragma unroll
            for (int r = 0; r < 4; ++r) {
                const float a = accS[n][r];
                float p = a * a;
                if (last)
                    p = ((n * 16 + l15) <= wave * 16 + lhi * 4 + r) ? p : 0.f;
                den[r] += p;
                const int prow = lhi * 4 + r;
                *(unsigned short*)(PsW + prow * 128 + ((2 * (n * 16 + l15)) ^ ((prow & 7) << 4))) = f2b(p);
            }
        }

        short8 pa[2];
#pragma unroll
        for (int kk = 0; kk < 2; ++kk)
            pa[kk] = *(const short8*)(PsW + l15 * 128 + ((kk * 64 + kchunk) ^ rsw));
        __builtin_amdgcn_s_setprio(1);
#pragma unroll
        for (int n = 0; n < 4; ++n) {
#pragma unroll
            for (int kk = 0; kk < 2; ++kk) {
                short8 vb = *(const short8*)(VtB + (n * 16 + l15) * 128 + ((kk * 64 + kchunk) ^ rsw));
                accY[n] = __builtin_amdgcn_mfma_f32_16x16x32_bf16(pa[kk], vb, accY[n], 0, 0, 0);
            }
        }
        __builtin_amdgcn_s_setprio(0);
    }

#pragma unroll
    for (int r = 0; r < 4; ++r) {
        den[r] += __shfl_xor(den[r], 1, 64);
        den[r] += __shfl_xor(den[r], 2, 64);
        den[r] += __shfl_xor(den[r], 4, 64);
        den[r] += __shfl_xor(den[r], 8, 64);
    }

    float* Ybase = (sc == 0) ? Y0 : (Yp + (size_t)(sc - 1) * MC_);
    float* Dbase = Dpart + (size_t)sc * BHT_;
#pragma unroll
    for (int r = 0; r < 4; ++r) {
        const int t = t0 + wave * 16 + lhi * 4 + r;
        if (l15 == 0)
            Dbase[(size_t)bh * T_ + t] = den[r];
        float* yo = Ybase + (size_t)(b * T_ + t) * (H_ * D_) + h * 64 + l15;
#pragma unroll
        for (int n = 0; n < 4; ++n)
            yo[n * 16] = accY[n][r];
    }
}

// ---------------------------------------------------------------------------
// normalize: ybb = bf16((sum Y slices) / max(sum den, 1e-6)), PRE-SWIZZLED
// ---------------------------------------------------------------------------
__global__ __launch_bounds__(256) void normalize_kernel(
    const float* __restrict__ Y0, const float* __restrict__ Yp,
    const float* __restrict__ Dpart, unsigned short* __restrict__ ybb)
{
    const int gid = blockIdx.x * 256 + threadIdx.x;
    const size_t base = (size_t)gid * 8;
    const int row = (int)(base >> 9);
    const int col = (int)(base & 511);
    const int b = row >> 11, t = row & 2047, h = col >> 6;
    const int bh = b * H_ + h;
    const int nsc = ((t >> 6) >> 3) + 1;

    float d = Dpart[(size_t)bh * T_ + t];
    float4 f0 = *(const float4*)(Y0 + base);
    float4 f1 = *(const float4*)(Y0 + base + 4);
    for (int s = 1; s < nsc; ++s) {
        d += Dpart[(size_t)s * BHT_ + (size_t)bh * T_ + t];
        const float* yp = Yp + (size_t)(s - 1) * MC_ + base;
        float4 g0 = *(const float4*)(yp);
        float4 g1 = *(const float4*)(yp + 4);
        f0.x += g0.x; f0.y += g0.y; f0.z += g0.z; f0.w += g0.w;
        f1.x += g1.x; f1.y += g1.y; f1.z += g1.z; f1.w += g1.w;
    }
    const float inv = 1.0f / fmaxf(d, 1e-6f);
    f0.x *= inv; f0.y *= inv; f0.z *= inv; f0.w *= inv;
    f1.x *= inv; f1.y *= inv; f1.z *= inv; f1.w *= inv;

    const int ic = col >> 3;
    const int swc = (ic & ~7) | ((ic & 7) ^ (row & 7));
    *(short8*)(ybb + (size_t)row * 512 + swc * 8) = pack8(f0, f1);
}

// ---------------------------------------------------------------------------
extern "C" void kernel_launch(void* const* d_in, const int* in_sizes, int n_in,
                              void* d_out, int out_size, void* d_ws, size_t ws_size,
                              hipStream_t stream)
{
    const float* x      = (const float*)d_in[0];
    const float* w_attn = (const float*)d_in[1];
    const float* w_proj = (const float*)d_in[2];
    float* out = (float*)d_out;

    // workspace (~47 MB of ~256 MB), no aliasing:
    char* p = (char*)d_ws;
    float2* sincos = (float2*)p;               p += (size_t)T_ * 32 * 8;       // 512 KB
    float* g       = (float*)p;                p += (size_t)BHT_ * 4;          // 128 KB
    float* Lg      = (float*)p;                p += (size_t)BHT_ * 4;          // 128 KB
    float* Dpart   = (float*)p;                p += (size_t)4 * BHT_ * 4;      // 512 KB
    unsigned short* xb  = (unsigned short*)p;  p += (size_t)MC_ * 2;           // 4 MB
    unsigned short* Bt1 = (unsigned short*)p;  p += (size_t)N1_ * C_ * 2;      // 1.5 MB
    unsigned short* Bt2 = (unsigned short*)p;  p += (size_t)C_ * C_ * 2;       // 0.5 MB
    unsigned short* Qsb = (unsigned short*)p;  p += (size_t)BHT_ * 64 * 2;     // 4 MB
    unsigned short* Ksb = (unsigned short*)p;  p += (size_t)BHT_ * 64 * 2;     // 4 MB
    unsigned short* Vtb = (unsigned short*)p;  p += (size_t)BHT_ * 64 * 2;     // 4 MB
    float* Yp      = (float*)p;                p += (size_t)3 * MC_ * 4;       // 24 MB
    unsigned short* ybb = (unsigned short*)p;                                  // 4 MB

    const int M = B_ * T_;      // 4096

    // 0) packs + sincos table + gate GEMV
    pack_inputs<<<1416, 256, 0, stream>>>(x, w_attn, w_proj, xb, Bt1, Bt2, sincos, g);

    // 1) gate log-sigmoid + cumsum -> Lg
    gate_cumsum<<<B_ * H_, 256, 0, stream>>>(g, Lg);

    // 2) fused qkv GEMM + RoPE/prescale/transpose epilogue -> Qsb, Ksb, Vtb
    gemm_fused<<<dim3(N1_ / 128, M / 128), 256, 0, stream>>>(
        xb, Bt1, Lg, sincos, Qsb, Ksb, Vtb);

    // 3) split-s attention, non-atomic partial slices
    attn_mfma<<<NBLK_, 256, 0, stream>>>(Qsb, Ksb, Vtb, out, Yp, Dpart);

    // 4) normalize + slice-sum -> ybb (bf16, pre-swizzled)
    normalize_kernel<<<(MC_ / 8) / 256, 256, 0, stream>>>(out, Yp, Dpart, ybb);

    // 5) out = ybb @ w_proj  (64x128 tiles, 256 blocks)
    gemm_bf16<<<dim3(C_ / 128, M / 64), 256, 0, stream>>>(
        ybb, Bt2, out, M, C_, H_ * D_);
}